// Round 19
// baseline (454.326 us; speedup 1.0000x reference)
//
#include <hip/hip_runtime.h>

#define NB 4
#define NN 50000
#define NT 784   // 64-row tiles per batch (784*64 = 50176 >= NN)

// ---- workspace byte offsets (total ~154.9 MB, < proven 205.9 MB) ----
#define H0B    0L
#define H1B    51200000L
#define QB     102400000L
#define KKB    128000000L    // k' (unfinalized, bf16)
#define RMB    153600000L    // fp32 rm [4*50000]
#define WBFB   154400000L    // bf16 GLU weights: layer0 [256][128], layer1 at +65536B
#define V2F0B  154531072L    // fp32 v2x layer0 [4][64][128]
#define V2F1B  154662144L    // fp32 v2x layer1
#define KSB    154793216L    // fp32 ksum [4][64]
#define GMB    154794240L    // 4 uints
#define W12B   154795264L    // bf16: W1 [32][96], W2 [32][96], proj [64][32], W_regT [16][256]
#define V2TB   154819840L    // bf16 v2x^T+ksum [4][144][64]
#define NZERO  65796         // words zeroed at V2F0B (v2x0+v2x1+ksum+gmax)

typedef short short8_t __attribute__((ext_vector_type(8)));
typedef float f32x4 __attribute__((ext_vector_type(4)));

__device__ __forceinline__ unsigned short f2bf(float f){
  unsigned u = __float_as_uint(f);
  return (unsigned short)((u + 0x7FFFu + ((u>>16)&1u)) >> 16);
}
__device__ __forceinline__ float bf2f(unsigned short s){
  return __uint_as_float(((unsigned)s)<<16);
}
__device__ __forceinline__ unsigned pk2(float a, float b){
  return (unsigned)f2bf(a) | ((unsigned)f2bf(b)<<16);
}
__device__ __forceinline__ uint4 pk8(const float* f){
  uint4 o; o.x=pk2(f[0],f[1]); o.y=pk2(f[2],f[3]);
  o.z=pk2(f[4],f[5]); o.w=pk2(f[6],f[7]); return o;
}
__device__ __forceinline__ void up8(uint4 v, float* f){
  f[0]=bf2f((unsigned short)(v.x&0xFFFFu)); f[1]=bf2f((unsigned short)(v.x>>16));
  f[2]=bf2f((unsigned short)(v.y&0xFFFFu)); f[3]=bf2f((unsigned short)(v.y>>16));
  f[4]=bf2f((unsigned short)(v.z&0xFFFFu)); f[5]=bf2f((unsigned short)(v.z>>16));
  f[6]=bf2f((unsigned short)(v.w&0xFFFFu)); f[7]=bf2f((unsigned short)(v.w>>16));
}
__device__ __forceinline__ short8_t relu8(short8_t s){
  short8_t r;
  #pragma unroll
  for (int i=0;i<8;i++){ short v = s[i]; r[i] = (v & (short)0x8000) ? (short)0 : v; }
  return r;
}
__device__ __forceinline__ unsigned encOrd(float f){
  unsigned u = __float_as_uint(f);
  return (u & 0x80000000u) ? ~u : (u | 0x80000000u);
}
__device__ __forceinline__ float decOrd(unsigned u){
  return (u & 0x80000000u) ? __uint_as_float(u & 0x7fffffffu)
                           : __uint_as_float(~u);
}

// ---- zero v2x0+v2x1+ksum+gmax ----
__global__ void k_init(char* __restrict__ wsb){
  int i = blockIdx.x*256 + threadIdx.x;
  if (i < NZERO) ((unsigned*)(wsb + V2F0B))[i] = 0u;
}
// ---- GLU weights -> bf16 [n][k] ----
__global__ void k_wcvt(const float* __restrict__ wi0, const float* __restrict__ wo0,
                       const float* __restrict__ wi1, const float* __restrict__ wo1,
                       char* __restrict__ wsb){
  int idx = blockIdx.x*256 + threadIdx.x;
  if (idx >= 65536) return;
  int l = idx >> 15, r = (idx >> 7) & 255, c = idx & 127;
  const float* src = (l==0) ? ((r<128)? wi0 : wo0) : ((r<128)? wi1 : wo1);
  float v = src[(r&127)*128 + c];
  ((unsigned short*)(wsb + WBFB))[l*32768 + r*128 + c] = f2bf(v);
}
// ---- W1,W2 [32][96], proj [64][32], W_regT [16][256] -> bf16 --------------
__global__ void k_wcvt2(const float* __restrict__ W1, const float* __restrict__ W2,
                        const float* __restrict__ proj, const float* __restrict__ W_reg,
                        char* __restrict__ wsb){
  int i = blockIdx.x*256 + threadIdx.x;          // 12288 total
  if (i >= 12288) return;
  unsigned short* dst = (unsigned short*)(wsb + W12B);
  float v;
  if (i < 3072) v = W1[i];
  else if (i < 6144) v = W2[i-3072];
  else if (i < 8192) v = proj[i-6144];
  else {
    int r = (i-8192) >> 8, c = (i-8192) & 255;
    v = (r < 12) ? W_reg[r*256 + c] : 0.f;
  }
  dst[i] = f2bf(v);
}

// ---------- pass1a: h0 (W_in matmul + embeddings) --------------------------
__global__ __launch_bounds__(256) void k_pass1a(
  const float* __restrict__ x, const float* __restrict__ node_emb,
  const float* __restrict__ time_emb, const float* __restrict__ week_emb,
  const float* __restrict__ W_in, const float* __restrict__ b_in,
  char* __restrict__ wsb)
{
  const int b = blockIdx.y;
  const int n = blockIdx.x*256 + threadIdx.x;
  if (n >= NN) return;
  const long row = (long)b*NN + n;
  float xr[36];
  {
    const float4* xp = (const float4*)(x + row*36);
    #pragma unroll
    for (int i=0;i<9;i++){ float4 t=xp[i]; xr[4*i]=t.x; xr[4*i+1]=t.y; xr[4*i+2]=t.z; xr[4*i+3]=t.w; }
  }
  int tidx = (int)(xr[34]*288.0f); tidx = tidx<0?0:(tidx>287?287:tidx);
  int widx = (int)(xr[35]);        widx = widx<0?0:(widx>6?6:widx);
  uint4* h0q = (uint4*)(wsb + H0B) + row*16;
  float hh[32];
  #pragma unroll 1
  for (int jj=0;jj<8;jj++){
    #pragma unroll
    for (int jl=0;jl<4;jl++){
      const int j = jj*4+jl;
      const float* w = W_in + j*36;
      float a0=0.f,a1=0.f,a2=0.f,a3=0.f;
      #pragma unroll
      for (int i=0;i<36;i+=4){ a0+=xr[i]*w[i]; a1+=xr[i+1]*w[i+1]; a2+=xr[i+2]*w[i+2]; a3+=xr[i+3]*w[i+3]; }
      hh[j] = b_in[j] + ((a0+a1)+(a2+a3));
    }
  }
  #pragma unroll
  for (int c=0;c<4;c++) h0q[c] = pk8(hh + 8*c);
  float xg[96];
  {
    const float4* p0 = (const float4*)(node_emb + (long)n*32);
    const float4* p1 = (const float4*)(time_emb + (long)tidx*32);
    const float4* p2 = (const float4*)(week_emb + (long)widx*32);
    #pragma unroll
    for (int i=0;i<8;i++){ float4 t=p0[i]; xg[4*i]=t.x; xg[4*i+1]=t.y; xg[4*i+2]=t.z; xg[4*i+3]=t.w; }
    #pragma unroll
    for (int i=0;i<8;i++){ float4 t=p1[i]; xg[32+4*i]=t.x; xg[32+4*i+1]=t.y; xg[32+4*i+2]=t.z; xg[32+4*i+3]=t.w; }
    #pragma unroll
    for (int i=0;i<8;i++){ float4 t=p2[i]; xg[64+4*i]=t.x; xg[64+4*i+1]=t.y; xg[64+4*i+2]=t.z; xg[64+4*i+3]=t.w; }
  }
  #pragma unroll
  for (int c=0;c<12;c++) h0q[4+c] = pk8(xg + 8*c);
}

// ---------- pass1b (MFMA, persistent): q, k', rm, global key max -----------
__global__ __launch_bounds__(256) void k_pass1b(
  const float* __restrict__ b1, const float* __restrict__ b2,
  char* __restrict__ wsb)
{
  __shared__ unsigned short xgt[64][104];
  __shared__ unsigned short dt[2][64][40];
  __shared__ unsigned short ot[64][72];
  __shared__ float wred[4];
  const int b   = blockIdx.y;
  const int tid = threadIdx.x;
  const int lane= tid & 63;
  const int w   = tid >> 6;
  const int c   = lane & 15;
  const int kg  = lane >> 4;
  const int nblk = gridDim.x;
  const int srow = tid >> 2, sq3 = tid & 3;
  const unsigned short* w1bf = (const unsigned short*)(wsb + W12B);
  const unsigned short* w2bf = w1bf + 3072;
  const unsigned short* pjbf = w1bf + 6144;
  // preload tile 0 xg regs
  uint4 xv0, xv1, xv2;
  {
    const long r0 = (long)blockIdx.x*64;
    long gr = r0 + srow;
    xv0=(uint4){0,0,0,0}; xv1=xv0; xv2=xv0;
    if (gr < NN){
      const uint4* src = (const uint4*)(wsb + H0B + ((long)b*NN + gr)*256 + 64 + sq3*48);
      xv0=src[0]; xv1=src[1]; xv2=src[2];
    }
  }
  #pragma unroll 1
  for (int tile = blockIdx.x; tile < NT; tile += nblk){
    const long r0blk = (long)tile*64;
    {
      uint4* d = (uint4*)&xgt[srow][sq3*24];
      d[0]=xv0; d[1]=xv1; d[2]=xv2;
    }
    // prefetch next tile's xg (lands during MFMA phases)
    if (tile + nblk < NT){
      const long r1 = (long)(tile + nblk)*64;
      long gr = r1 + srow;
      xv0=(uint4){0,0,0,0}; xv1=xv0; xv2=xv0;
      if (gr < NN){
        const uint4* src = (const uint4*)(wsb + H0B + ((long)b*NN + gr)*256 + 64 + sq3*48);
        xv0=src[0]; xv1=src[1]; xv2=src[2];
      }
    }
    __syncthreads();
    f32x4 accd[2][2];
    #pragma unroll
    for (int s=0;s<2;s++)
      #pragma unroll
      for (int f=0;f<2;f++) accd[s][f] = (f32x4){0.f,0.f,0.f,0.f};
    #pragma unroll
    for (int ks=0;ks<3;ks++){
      short8_t a = *(const short8_t*)&xgt[w*16 + c][ks*32 + kg*8];
      #pragma unroll
      for (int f=0;f<2;f++){
        short8_t bw1 = *(const short8_t*)(w1bf + (f*16+c)*96 + ks*32 + kg*8);
        accd[0][f] = __builtin_amdgcn_mfma_f32_16x16x32_bf16(a, bw1, accd[0][f], 0,0,0);
        short8_t bw2 = *(const short8_t*)(w2bf + (f*16+c)*96 + ks*32 + kg*8);
        accd[1][f] = __builtin_amdgcn_mfma_f32_16x16x32_bf16(a, bw2, accd[1][f], 0,0,0);
      }
    }
    const float DSC = 0.42044820762685725f;   // 32^-0.25
    float dv[2][2][4];
    #pragma unroll
    for (int f=0;f<2;f++){
      float bb1 = b1[f*16+c], bb2 = b2[f*16+c];
      #pragma unroll
      for (int jj=0;jj<4;jj++){
        dv[0][f][jj] = (accd[0][f][jj] + bb1) * DSC;
        dv[1][f][jj] = (accd[1][f][jj] + bb2) * DSC;
      }
    }
    float dg[2][4];
    #pragma unroll
    for (int s=0;s<2;s++)
      #pragma unroll
      for (int jj=0;jj<4;jj++){
        float t = dv[s][0][jj]*dv[s][0][jj] + dv[s][1][jj]*dv[s][1][jj];
        #pragma unroll
        for (int off=1; off<16; off<<=1) t += __shfl_xor(t, off);
        dg[s][jj] = 0.5f * t;
      }
    #pragma unroll
    for (int s=0;s<2;s++)
      #pragma unroll
      for (int f=0;f<2;f++)
        #pragma unroll
        for (int jj=0;jj<4;jj++)
          dt[s][w*16 + kg*4 + jj][f*16 + c] = f2bf(dv[s][f][jj]);
    __syncthreads();
    f32x4 acc2[2][4];
    #pragma unroll
    for (int s=0;s<2;s++){
      short8_t ad = *(const short8_t*)&dt[s][w*16 + c][kg*8];
      #pragma unroll
      for (int f=0;f<4;f++){
        short8_t bp = *(const short8_t*)(pjbf + (f*16+c)*32 + kg*8);
        acc2[s][f] = __builtin_amdgcn_mfma_f32_16x16x32_bf16(ad, bp, (f32x4){0.f,0.f,0.f,0.f}, 0,0,0);
      }
    }
    float mx[2][4];
    #pragma unroll
    for (int s=0;s<2;s++)
      #pragma unroll
      for (int jj=0;jj<4;jj++){
        float t = fmaxf(fmaxf(acc2[s][0][jj],acc2[s][1][jj]),
                        fmaxf(acc2[s][2][jj],acc2[s][3][jj]));
        #pragma unroll
        for (int off=1; off<16; off<<=1) t = fmaxf(t, __shfl_xor(t, off));
        mx[s][jj] = t;
      }
    #pragma unroll
    for (int f=0;f<4;f++)
      #pragma unroll
      for (int jj=0;jj<4;jj++){
        float qv = 0.125f*(__expf(acc2[0][f][jj] - dg[0][jj] - mx[0][jj]) + 1e-6f);
        ot[w*16 + kg*4 + jj][f*16 + c] = f2bf(qv);
      }
    __syncthreads();
    {
      long gr = r0blk + srow;
      if (gr < NN){
        const uint4* s = (const uint4*)&ot[srow][sq3*16];
        uint4* dst = (uint4*)((unsigned short*)(wsb + QB) + ((long)b*NN + gr)*64 + sq3*16);
        dst[0] = s[0]; dst[1] = s[1];
      }
    }
    __syncthreads();
    float bmax = -3.0e38f;
    #pragma unroll
    for (int f=0;f<4;f++)
      #pragma unroll
      for (int jj=0;jj<4;jj++){
        float kv = __expf(acc2[1][f][jj] - mx[1][jj]);
        ot[w*16 + kg*4 + jj][f*16 + c] = f2bf(kv);
      }
    #pragma unroll
    for (int jj=0;jj<4;jj++){
      long gr = r0blk + w*16 + kg*4 + jj;
      bool val = (gr < NN);
      if (val && c==0)
        ((float*)(wsb + RMB))[(long)b*NN + gr] = mx[1][jj] - dg[1][jj];
      if (val) bmax = fmaxf(bmax, mx[1][jj]);
    }
    #pragma unroll
    for (int off=32; off>0; off>>=1) bmax = fmaxf(bmax, __shfl_xor(bmax, off));
    if (lane==0) wred[w] = bmax;
    __syncthreads();
    {
      long gr = r0blk + srow;
      if (gr < NN){
        const uint4* s = (const uint4*)&ot[srow][sq3*16];
        uint4* dst = (uint4*)((unsigned short*)(wsb + KKB) + ((long)b*NN + gr)*64 + sq3*16);
        dst[0] = s[0]; dst[1] = s[1];
      }
    }
    if (tid==0){
      float m2 = fmaxf(fmaxf(wred[0],wred[1]), fmaxf(wred[2],wred[3]));
      atomicMax((unsigned*)(wsb + GMB) + b, encOrd(m2));
    }
    __syncthreads();   // ot/wred WAR before next tile
  }
}

// ---------- fused GLU + k-finalize (+ksum) + MFMA reduce -------------------
// persistent tile-stride; GLU in 2 halves (gi[4]+go[4]) to cut register
// footprint below 256/wave -> 2 waves/SIMD
__global__ __launch_bounds__(256) void k_glured(
  char* __restrict__ wsb, const unsigned short* __restrict__ hsrc,
  const unsigned short* __restrict__ wbf,
  const float* __restrict__ bi, const float* __restrict__ bo,
  float* __restrict__ v2x_out, float* __restrict__ ksout)
{
  __shared__ unsigned short ht[64][132];       // 16896 B
  __shared__ unsigned short htT[128][72];      // 18432 B
  __shared__ unsigned short ktl[2][64][72];    // 2 x 9216 B
  __shared__ float red[256];
  const int b = blockIdx.y;
  const int tid = threadIdx.x;
  const int lane = tid & 63;
  const int w = tid >> 6;
  const int c = lane & 15;
  const int kg = lane >> 4;
  const int nblk = gridDim.x;
  const float gm = decOrd(((const unsigned*)(wsb + GMB))[b]);
  const float* rm = (const float*)(wsb + RMB) + (long)b*NN;
  const uint4* kbase = (const uint4*)(wsb + KKB) + (long)b*NN*8;
  f32x4 racc[8];
  #pragma unroll
  for (int f=0;f<8;f++) racc[f] = (f32x4){0.f,0.f,0.f,0.f};
  float ksacc = 0.f;
  float bi_l[8], bo_l[8];
  #pragma unroll
  for (int f=0;f<8;f++){ bi_l[f] = bi[f*16+c]; bo_l[f] = bo[f*16+c]; }
  const int krr = tid>>3, kcc = tid&7;
  const int srow = tid>>2, sq3 = tid&3;
  const int rswz = ((w*16 + c) >> 3) & 7;
  uint4 hv0,hv1,hv2,hv3, krA,krB; float rmA,rmB;
  {
    const long r0 = (long)blockIdx.x*64;
    long gr = r0 + srow;
    hv0=(uint4){0,0,0,0}; hv1=hv0; hv2=hv0; hv3=hv0;
    if (gr < NN){
      const uint4* s = (const uint4*)(hsrc + ((long)b*NN + gr)*128 + sq3*32);
      hv0=s[0]; hv1=s[1]; hv2=s[2]; hv3=s[3];
    }
    krA=(uint4){0,0,0,0}; krB=krA; rmA=0.f; rmB=0.f;
    long gA = r0 + krr;      if (gA < NN){ krA = kbase[gA*8 + kcc]; rmA = rm[gA]; }
    long gB = r0 + krr + 32; if (gB < NN){ krB = kbase[gB*8 + kcc]; rmB = rm[gB]; }
  }
  int p = 0;
  #pragma unroll 1
  for (int tile = blockIdx.x; tile < NT; tile += nblk){
    const long r0 = (long)tile*64;
    // Phase A: write ht + ktl[p] from prefetched regs; issue next prefetch
    {
      uint4* d = (uint4*)&ht[srow][sq3*32];
      d[0]=hv0; d[1]=hv1; d[2]=hv2; d[3]=hv3;
    }
    {
      bool vA = (r0 + krr) < NN;
      bool vB = (r0 + krr + 32) < NN;
      float sA = __expf(rmA - gm), sB = __expf(rmB - gm);
      float ta[8], tb[8];
      up8(krA, ta); up8(krB, tb);
      #pragma unroll
      for (int i=0;i<8;i++){
        ta[i] = vA ? 0.125f*(ta[i]*sA + 1e-6f) : 0.f;
        tb[i] = vB ? 0.125f*(tb[i]*sB + 1e-6f) : 0.f;
      }
      const int pA = (((krr>>3) ^ kcc) << 3) | (krr & 7);
      const int pB = ((((krr>>3)+4) ^ kcc) << 3) | (krr & 7);
      #pragma unroll
      for (int i=0;i<8;i++){
        ktl[p][kcc*8+i][pA] = f2bf(ta[i]);
        ktl[p][kcc*8+i][pB] = f2bf(tb[i]);
      }
    }
    if (tile + nblk < NT){
      const long r1 = (long)(tile + nblk)*64;
      long gr = r1 + srow;
      hv0=(uint4){0,0,0,0}; hv1=hv0; hv2=hv0; hv3=hv0;
      if (gr < NN){
        const uint4* s = (const uint4*)(hsrc + ((long)b*NN + gr)*128 + sq3*32);
        hv0=s[0]; hv1=s[1]; hv2=s[2]; hv3=s[3];
      }
      krA=(uint4){0,0,0,0}; krB=krA; rmA=0.f; rmB=0.f;
      long gA = r1 + krr;      if (gA < NN){ krA = kbase[gA*8 + kcc]; rmA = rm[gA]; }
      long gB = r1 + krr + 32; if (gB < NN){ krB = kbase[gB*8 + kcc]; rmB = rm[gB]; }
    }
    __syncthreads();   // barrier A: ht/ktl[p] ready (also covers prior reduce)
    // Phase B: GLU MFMA in two halves (gi[4]+go[4] live), write htT, ksum
    #pragma unroll 1
    for (int half=0; half<2; half++){
      const f32x4 z4 = (f32x4){0.f,0.f,0.f,0.f};
      f32x4 gi[4], go[4];
      #pragma unroll
      for (int ff=0;ff<4;ff++){ gi[ff]=z4; go[ff]=z4; }
      #pragma unroll
      for (int ks=0;ks<4;ks++){
        short8_t a = *(const short8_t*)&ht[w*16 + c][ks*32 + kg*8];
        #pragma unroll
        for (int ff=0;ff<4;ff++){
          const int f = half*4 + ff;
          short8_t bwi = *(const short8_t*)(wbf + (f*16 + c)*128 + ks*32 + kg*8);
          gi[ff] = __builtin_amdgcn_mfma_f32_16x16x32_bf16(a, bwi, gi[ff], 0, 0, 0);
          short8_t bwo = *(const short8_t*)(wbf + ((f+8)*16 + c)*128 + ks*32 + kg*8);
          go[ff] = __builtin_amdgcn_mfma_f32_16x16x32_bf16(a, bwo, go[ff], 0, 0, 0);
        }
      }
      #pragma unroll
      for (int ff=0;ff<4;ff++){
        const int f = half*4 + ff;
        #pragma unroll
        for (int j=0;j<4;j++){
          float aa = gi[ff][j] + bi_l[f];
          float cc2= go[ff][j] + bo_l[f];
          float o  = cc2 / (1.0f + __expf(-aa));
          bool val = (r0 + w*16 + kg*4 + j) < NN;
          htT[f*16 + c][w*16 + kg*4 + j] = val ? f2bf(o) : (unsigned short)0;
        }
      }
    }
    if (ksout){
      int m = tid & 63, n0 = (tid>>6)*16;
      int sm = (m>>3)&7;
      #pragma unroll
      for (int n=0;n<16;n++){
        int nn = n0+n;
        ksacc += bf2f(ktl[p][m][(((nn>>3)^sm)<<3)|(nn&7)]);
      }
    }
    __syncthreads();   // barrier B: htT ready
    // Phase C: reduce MFMA (reads ktl[p] + htT only)
    #pragma unroll
    for (int ks=0;ks<2;ks++){
      short8_t a = *(const short8_t*)&ktl[p][w*16 + c][((ks*4 + kg) ^ rswz) << 3];
      #pragma unroll
      for (int f=0;f<8;f++){
        short8_t bb = *(const short8_t*)&htT[f*16 + c][ks*32 + kg*8];
        racc[f] = __builtin_amdgcn_mfma_f32_16x16x32_bf16(a, bb, racc[f], 0, 0, 0);
      }
    }
    p ^= 1;
    // no barrier: next Phase A writes ht (unread in C) and ktl[p^1] (unread in C)
  }
  float* v2x = v2x_out + (long)b*8192;
  #pragma unroll
  for (int f=0;f<8;f++)
    #pragma unroll
    for (int j=0;j<4;j++)
      atomicAdd(&v2x[(w*16 + kg*4 + j)*128 + f*16 + c], racc[f][j]);
  if (ksout){
    red[tid] = ksacc;
    __syncthreads();
    if (tid < 64)
      atomicAdd(ksout + b*64 + tid,
                red[tid]+red[64+tid]+red[128+tid]+red[192+tid]);
  }
}

// ---------- v2t[b][n][m]: n<128: v2x[m][n]; n=128: ksum[m]; n>128: 0 -------
__global__ void k_v2cvt(char* __restrict__ wsb, const float* __restrict__ v2f){
  int idx = blockIdx.x*256 + threadIdx.x;          // 36864
  if (idx >= 36864) return;
  int b = idx / 9216, rem = idx % 9216;
  int n = rem / 64, m = rem % 64;
  const float* ks = (const float*)(wsb + KSB);
  float v = (n < 128) ? v2f[b*8192 + m*128 + n] : ((n==128) ? ks[b*64+m] : 0.f);
  ((unsigned short*)(wsb + V2TB))[b*9216 + n*64 + m] = f2bf(v);
}

// ---------- attn0 + residual(h0) + LN0 -> h1 (persistent) ------------------
__global__ __launch_bounds__(256) void k_attnln(
  char* __restrict__ wsb, const float* __restrict__ g0,
  const float* __restrict__ bt0)
{
  __shared__ unsigned short ht[64][132];    // 16896 B
  __shared__ unsigned short v2s[144*72];    // 20736 B (persistent across tiles)
  const int b = blockIdx.y;
  const int tid = threadIdx.x;
  const int lane = tid & 63;
  const int w  = tid >> 6;
  const int c  = lane & 15;
  const int kg = lane >> 4;
  const int nblk = gridDim.x;
  const int rrow = tid>>2, rq3 = tid&3;
  const unsigned short* qb = (const unsigned short*)(wsb + QB) + (long)b*NN*64;
  const unsigned short* h0g = (const unsigned short*)(wsb + H0B) + (long)b*NN*128;
  unsigned short* h1g = (unsigned short*)(wsb + H1B) + (long)b*NN*128;
  {
    const uint4* v2g = (const uint4*)((const unsigned short*)(wsb + V2TB) + b*9216);
    #pragma unroll
    for (int e=0;e<5;e++){
      int j = tid + 256*e;
      if (j < 1152){
        int row = j >> 3, cc = j & 7;
        *(uint4*)&v2s[row*72 + cc*8] = v2g[j];
      }
    }
  }
  short8_t aq0, aq1;
  uint4 rh0, rh1, rh2, rh3;
  {
    const long r0 = (long)blockIdx.x*64;
    if (r0 + w*16 + c < NN){
      const unsigned short* qrow = qb + (r0 + w*16 + c)*64 + kg*8;
      aq0 = *(const short8_t*)qrow; aq1 = *(const short8_t*)(qrow + 32);
    } else { aq0 = (short8_t){0,0,0,0,0,0,0,0}; aq1 = aq0; }
    rh0=(uint4){0,0,0,0}; rh1=rh0; rh2=rh0; rh3=rh0;
    if (r0 + rrow < NN){
      const uint4* hs = (const uint4*)(h0g + (r0 + rrow)*128 + rq3*32);
      rh0=hs[0]; rh1=hs[1]; rh2=hs[2]; rh3=hs[3];
    }
  }
  __syncthreads();   // v2s ready
  #pragma unroll 1
  for (int tile = blockIdx.x; tile < NT; tile += nblk){
    const long r0blk = (long)tile*64;
    const long rgr = r0blk + rrow;
    f32x4 acc[9];
    #pragma unroll
    for (int f=0;f<9;f++) acc[f] = (f32x4){0.f,0.f,0.f,0.f};
    #pragma unroll
    for (int f=0;f<9;f++){
      short8_t b0 = *(const short8_t*)&v2s[(f*16 + c)*72 + kg*8];
      acc[f] = __builtin_amdgcn_mfma_f32_16x16x32_bf16(aq0, b0, acc[f], 0, 0, 0);
      short8_t b1v = *(const short8_t*)&v2s[(f*16 + c)*72 + 32 + kg*8];
      acc[f] = __builtin_amdgcn_mfma_f32_16x16x32_bf16(aq1, b1v, acc[f], 0, 0, 0);
    }
    float inv[4];
    #pragma unroll
    for (int j=0;j<4;j++) inv[j] = 1.0f / __shfl(acc[8][j], (lane & 48));
    #pragma unroll
    for (int f=0;f<8;f++)
      #pragma unroll
      for (int j=0;j<4;j++)
        ht[w*16 + kg*4 + j][f*16 + c] = f2bf(acc[f][j]*inv[j]);
    __syncthreads();
    short8_t aq0n, aq1n;
    uint4 nh0, nh1, nh2, nh3;
    {
      aq0n = (short8_t){0,0,0,0,0,0,0,0}; aq1n = aq0n;
      nh0=(uint4){0,0,0,0}; nh1=nh0; nh2=nh0; nh3=nh0;
      if (tile + nblk < NT){
        const long r1 = (long)(tile + nblk)*64;
        if (r1 + w*16 + c < NN){
          const unsigned short* qrow = qb + (r1 + w*16 + c)*64 + kg*8;
          aq0n = *(const short8_t*)qrow; aq1n = *(const short8_t*)(qrow + 32);
        }
        if (r1 + rrow < NN){
          const uint4* hs = (const uint4*)(h0g + (r1 + rrow)*128 + rq3*32);
          nh0=hs[0]; nh1=hs[1]; nh2=hs[2]; nh3=hs[3];
        }
      }
    }
    {
      float tv[32];
      {
        const uint4* os = (const uint4*)&ht[rrow][rq3*32];
        uint4 o0=os[0],o1=os[1],o2=os[2],o3=os[3];
        up8(o0,tv); up8(o1,tv+8); up8(o2,tv+16); up8(o3,tv+24);
      }
      {
        float hv[32];
        up8(rh0,hv); up8(rh1,hv+8); up8(rh2,hv+16); up8(rh3,hv+24);
        #pragma unroll
        for (int i=0;i<32;i++) tv[i] += hv[i];
      }
      float s = 0.f;
      #pragma unroll
      for (int i=0;i<32;i++) s += tv[i];
      s += __shfl_xor(s, 1); s += __shfl_xor(s, 2);
      float mu = s * (1.0f/128.0f);
      float vv = 0.f;
      #pragma unroll
      for (int i=0;i<32;i++){ float e = tv[i]-mu; vv += e*e; }
      vv += __shfl_xor(vv, 1); vv += __shfl_xor(vv, 2);
      float rs = rsqrtf(vv * (1.0f/128.0f) + 1e-5f);
      const float4* gp = (const float4*)(g0 + rq3*32);
      const float4* bp = (const float4*)(bt0 + rq3*32);
      float h1v[32];
      #pragma unroll
      for (int i8=0;i8<8;i8++){
        float4 g4 = gp[i8], b4 = bp[i8];
        h1v[i8*4  ] = (tv[i8*4  ]-mu)*rs*g4.x + b4.x;
        h1v[i8*4+1] = (tv[i8*4+1]-mu)*rs*g4.y + b4.y;
        h1v[i8*4+2] = (tv[i8*4+2]-mu)*rs*g4.z + b4.z;
        h1v[i8*4+3] = (tv[i8*4+3]-mu)*rs*g4.w + b4.w;
      }
      if (rgr < NN){
        uint4 p0=pk8(h1v), p1=pk8(h1v+8), p2=pk8(h1v+16), p3=pk8(h1v+24);
        uint4* dst = (uint4*)(h1g + rgr*128 + rq3*32);
        dst[0]=p0; dst[1]=p1; dst[2]=p2; dst[3]=p3;
      }
    }
    __syncthreads();   // ht WAR for next tile
    aq0=aq0n; aq1=aq1n; rh0=nh0; rh1=nh1; rh2=nh2; rh3=nh3;
  }
}

// ---------- attn1 + residual(h1) + LN1 + MFMA head (persistent) ------------
__global__ __launch_bounds__(256) void k_attnhead(
  char* __restrict__ wsb, const float* __restrict__ g1,
  const float* __restrict__ bt1, const float* __restrict__ b_reg,
  float* __restrict__ out)
{
  __shared__ unsigned short ht[64][132];    // 16896 B
  __shared__ unsigned short v2s[144*72];    // 20736 B (persistent)
  __shared__ unsigned short h0t[64][136];   // 17408 B
  const int b = blockIdx.y;
  const int tid = threadIdx.x;
  const int lane = tid & 63;
  const int w  = tid >> 6;
  const int c  = lane & 15;
  const int kg = lane >> 4;
  const int nblk = gridDim.x;
  const int rrow = tid>>2, rq3 = tid&3;
  const unsigned short* qb  = (const unsigned short*)(wsb + QB) + (long)b*NN*64;
  const unsigned short* h0g = (const unsigned short*)(wsb + H0B) + (long)b*NN*128;
  const unsigned short* h1g = (const unsigned short*)(wsb + H1B) + (long)b*NN*128;
  {
    const uint4* v2g = (const uint4*)((const unsigned short*)(wsb + V2TB) + b*9216);
    #pragma unroll
    for (int e=0;e<5;e++){
      int j = tid + 256*e;
      if (j < 1152){
        int row = j >> 3, cc = j & 7;
        *(uint4*)&v2s[row*72 + cc*8] = v2g[j];
      }
    }
  }
  short8_t aq0, aq1;
  uint4 rh0, rh1, rh2, rh3, ah0, ah1, ah2, ah3;
  {
    const long r0 = (long)blockIdx.x*64;
    if (r0 + w*16 + c < NN){
      const unsigned short* qrow = qb + (r0 + w*16 + c)*64 + kg*8;
      aq0 = *(const short8_t*)qrow; aq1 = *(const short8_t*)(qrow + 32);
    } else { aq0 = (short8_t){0,0,0,0,0,0,0,0}; aq1 = aq0; }
    rh0=(uint4){0,0,0,0}; rh1=rh0; rh2=rh0; rh3=rh0;
    ah0=rh0; ah1=rh0; ah2=rh0; ah3=rh0;
    if (r0 + rrow < NN){
      const uint4* hs = (const uint4*)(h1g + (r0 + rrow)*128 + rq3*32);
      rh0=hs[0]; rh1=hs[1]; rh2=hs[2]; rh3=hs[3];
      const uint4* h0s = (const uint4*)(h0g + (r0 + rrow)*128 + rq3*32);
      ah0=h0s[0]; ah1=h0s[1]; ah2=h0s[2]; ah3=h0s[3];
    }
  }
  __syncthreads();   // v2s ready
  #pragma unroll 1
  for (int tile = blockIdx.x; tile < NT; tile += nblk){
    const long r0blk = (long)tile*64;
    const long r0w = r0blk + w*16;
    const long rgr = r0blk + rrow;
    f32x4 acc[9];
    #pragma unroll
    for (int f=0;f<9;f++) acc[f] = (f32x4){0.f,0.f,0.f,0.f};
    #pragma unroll
    for (int f=0;f<9;f++){
      short8_t b0 = *(const short8_t*)&v2s[(f*16 + c)*72 + kg*8];
      acc[f] = __builtin_amdgcn_mfma_f32_16x16x32_bf16(aq0, b0, acc[f], 0, 0, 0);
      short8_t b1v = *(const short8_t*)&v2s[(f*16 + c)*72 + 32 + kg*8];
      acc[f] = __builtin_amdgcn_mfma_f32_16x16x32_bf16(aq1, b1v, acc[f], 0, 0, 0);
    }
    float inv[4];
    #pragma unroll
    for (int j=0;j<4;j++) inv[j] = 1.0f / __shfl(acc[8][j], (lane & 48));
    #pragma unroll
    for (int f=0;f<8;f++)
      #pragma unroll
      for (int j=0;j<4;j++)
        ht[w*16 + kg*4 + j][f*16 + c] = f2bf(acc[f][j]*inv[j]);
    __syncthreads();
    short8_t aq0n, aq1n;
    uint4 nh0, nh1, nh2, nh3, na0, na1, na2, na3;
    {
      aq0n = (short8_t){0,0,0,0,0,0,0,0}; aq1n = aq0n;
      nh0=(uint4){0,0,0,0}; nh1=nh0; nh2=nh0; nh3=nh0;
      na0=nh0; na1=nh0; na2=nh0; na3=nh0;
      if (tile + nblk < NT){
        const long r1 = (long)(tile + nblk)*64;
        if (r1 + w*16 + c < NN){
          const unsigned short* qrow = qb + (r1 + w*16 + c)*64 + kg*8;
          aq0n = *(const short8_t*)qrow; aq1n = *(const short8_t*)(qrow + 32);
        }
        if (r1 + rrow < NN){
          const uint4* hs = (const uint4*)(h1g + (r1 + rrow)*128 + rq3*32);
          nh0=hs[0]; nh1=hs[1]; nh2=hs[2]; nh3=hs[3];
          const uint4* h0s = (const uint4*)(h0g + (r1 + rrow)*128 + rq3*32);
          na0=h0s[0]; na1=h0s[1]; na2=h0s[2]; na3=h0s[3];
        }
      }
    }
    {
      uint4* hd = (uint4*)&h0t[rrow][rq3*32];
      hd[0]=ah0; hd[1]=ah1; hd[2]=ah2; hd[3]=ah3;
      float tv[32];
      {
        const uint4* os = (const uint4*)&ht[rrow][rq3*32];
        uint4 o0=os[0],o1=os[1],o2=os[2],o3=os[3];
        up8(o0,tv); up8(o1,tv+8); up8(o2,tv+16); up8(o3,tv+24);
      }
      {
        float hv[32];
        up8(rh0,hv); up8(rh1,hv+8); up8(rh2,hv+16); up8(rh3,hv+24);
        #pragma unroll
        for (int i=0;i<32;i++) tv[i] += hv[i];
      }
      float s = 0.f;
      #pragma unroll
      for (int i=0;i<32;i++) s += tv[i];
      s += __shfl_xor(s, 1); s += __shfl_xor(s, 2);
      float mu = s * (1.0f/128.0f);
      float vv = 0.f;
      #pragma unroll
      for (int i=0;i<32;i++){ float e = tv[i]-mu; vv += e*e; }
      vv += __shfl_xor(vv, 1); vv += __shfl_xor(vv, 2);
      float rs = rsqrtf(vv * (1.0f/128.0f) + 1e-5f);
      const float4* gp = (const float4*)(g1 + rq3*32);
      const float4* bp = (const float4*)(bt1 + rq3*32);
      float h2v[32];
      #pragma unroll
      for (int i8=0;i8<8;i8++){
        float4 g4 = gp[i8], b4 = bp[i8];
        h2v[i8*4  ] = fmaxf((tv[i8*4  ]-mu)*rs*g4.x + b4.x, 0.f);
        h2v[i8*4+1] = fmaxf((tv[i8*4+1]-mu)*rs*g4.y + b4.y, 0.f);
        h2v[i8*4+2] = fmaxf((tv[i8*4+2]-mu)*rs*g4.z + b4.z, 0.f);
        h2v[i8*4+3] = fmaxf((tv[i8*4+3]-mu)*rs*g4.w + b4.w, 0.f);
      }
      uint4 p0=pk8(h2v), p1=pk8(h2v+8), p2=pk8(h2v+16), p3=pk8(h2v+24);
      uint4* d = (uint4*)&ht[rrow][rq3*32];
      d[0]=p0; d[1]=p1; d[2]=p2; d[3]=p3;
    }
    __syncthreads();
    const unsigned short* wregT = (const unsigned short*)(wsb + W12B) + 8192;
    f32x4 hacc = (f32x4){0.f,0.f,0.f,0.f};
    #pragma unroll
    for (int ks=0;ks<8;ks++){
      short8_t a;
      if (ks < 4)
        a = relu8(*(const short8_t*)&h0t[w*16 + c][ks*32 + kg*8]);
      else
        a = *(const short8_t*)&ht[w*16 + c][(ks-4)*32 + kg*8];
      short8_t bb = *(const short8_t*)(wregT + c*256 + ks*32 + kg*8);
      hacc = __builtin_amdgcn_mfma_f32_16x16x32_bf16(a, bb, hacc, 0, 0, 0);
    }
    if (c < 12){
      float br = b_reg[c];
      #pragma unroll
      for (int j=0;j<4;j++){
        long gr = r0w + kg*4 + j;
        if (gr < NN)
          out[((long)b*12 + c)*NN + gr] = hacc[j] + br;
      }
    }
    __syncthreads();   // ht/h0t WAR for next tile
    aq0=aq0n; aq1=aq1n;
    rh0=nh0; rh1=nh1; rh2=nh2; rh3=nh3;
    ah0=na0; ah1=na1; ah2=na2; ah3=na3;
  }
}

extern "C" void kernel_launch(void* const* d_in, const int* in_sizes, int n_in,
                              void* d_out, int out_size, void* d_ws, size_t ws_size,
                              hipStream_t stream)
{
  const float* x        = (const float*)d_in[0];
  const float* node_emb = (const float*)d_in[1];
  const float* time_emb = (const float*)d_in[2];
  const float* week_emb = (const float*)d_in[3];
  const float* W_in     = (const float*)d_in[4];
  const float* b_in     = (const float*)d_in[5];
  const float* W1       = (const float*)d_in[6];
  const float* b1       = (const float*)d_in[7];
  const float* W2       = (const float*)d_in[8];
  const float* b2       = (const float*)d_in[9];
  const float* W_reg    = (const float*)d_in[10];
  const float* b_reg    = (const float*)d_in[11];
  const float* proj     = (const float*)d_in[12];
  const float* fc_in0_w = (const float*)d_in[13];
  const float* fc_in0_b = (const float*)d_in[14];
  const float* fc_out0_w= (const float*)d_in[15];
  const float* fc_out0_b= (const float*)d_in[16];
  const float* ln0_g    = (const float*)d_in[17];
  const float* ln0_b    = (const float*)d_in[18];
  const float* fc_in1_w = (const float*)d_in[19];
  const float* fc_in1_b = (const float*)d_in[20];
  const float* fc_out1_w= (const float*)d_in[21];
  const float* fc_out1_b= (const float*)d_in[22];
  const float* ln1_g    = (const float*)d_in[23];
  const float* ln1_b    = (const float*)d_in[24];
  char* wsb  = (char*)d_ws;
  float* out = (float*)d_out;

  dim3 rowgrid((NN+255)/256, NB);     // (196, 4)
  dim3 pgrid(128, NB);                // persistent: 512 blocks, tile-stride
  dim3 cvtgrid(144);

  k_init  <<<258, 256, 0, stream>>>(wsb);
  k_wcvt  <<<256, 256, 0, stream>>>(fc_in0_w, fc_out0_w, fc_in1_w, fc_out1_w, wsb);
  k_wcvt2 <<<48, 256, 0, stream>>>(W1, W2, proj, W_reg, wsb);
  k_pass1a<<<rowgrid, 256, 0, stream>>>(x, node_emb, time_emb, week_emb,
                                        W_in, b_in, wsb);
  k_pass1b<<<pgrid, 256, 0, stream>>>(b1, b2, wsb);
  k_glured<<<pgrid, 256, 0, stream>>>(wsb, (const unsigned short*)(wsb + H0B),
                                      (const unsigned short*)(wsb + WBFB),
                                      fc_in0_b, fc_out0_b,
                                      (float*)(wsb + V2F0B), (float*)(wsb + KSB));
  k_v2cvt <<<cvtgrid, 256, 0, stream>>>(wsb, (const float*)(wsb + V2F0B));
  k_attnln<<<pgrid, 256, 0, stream>>>(wsb, ln0_g, ln0_b);
  k_glured<<<pgrid, 256, 0, stream>>>(wsb, (const unsigned short*)(wsb + H1B),
                                      (const unsigned short*)(wsb + WBFB) + 32768,
                                      fc_in1_b, fc_out1_b,
                                      (float*)(wsb + V2F1B), (float*)nullptr);
  k_v2cvt <<<cvtgrid, 256, 0, stream>>>(wsb, (const float*)(wsb + V2F1B));
  k_attnhead<<<pgrid, 256, 0, stream>>>(wsb, ln1_g, ln1_b, b_reg, out);
}

// Round 20
// 394.173 us; speedup vs baseline: 1.1526x; 1.1526x over previous
//
#include <hip/hip_runtime.h>

#define NB 4
#define NN 50000
#define NT 784   // 64-row tiles per batch (784*64 = 50176 >= NN)

// ---- workspace byte offsets (total ~154.9 MB, < proven 205.9 MB) ----
#define H0B    0L
#define H1B    51200000L
#define QB     102400000L
#define KKB    128000000L    // k' (unfinalized, bf16)
#define RMB    153600000L    // fp32 rm [4*50000]
#define WBFB   154400000L    // bf16 GLU weights: layer0 [256][128], layer1 at +65536B
#define V2F0B  154531072L    // fp32 v2x layer0 [4][64][128]
#define V2F1B  154662144L    // fp32 v2x layer1
#define KSB    154793216L    // fp32 ksum [4][64]
#define GMB    154794240L    // 4 uints
#define W12B   154795264L    // bf16: W1 [32][96], W2 [32][96], proj [64][32], W_regT [16][256]
#define NZERO  65796         // words zeroed at V2F0B (v2x0+v2x1+ksum+gmax)

typedef short short8_t __attribute__((ext_vector_type(8)));
typedef float f32x4 __attribute__((ext_vector_type(4)));

__device__ __forceinline__ unsigned short f2bf(float f){
  unsigned u = __float_as_uint(f);
  return (unsigned short)((u + 0x7FFFu + ((u>>16)&1u)) >> 16);
}
__device__ __forceinline__ float bf2f(unsigned short s){
  return __uint_as_float(((unsigned)s)<<16);
}
__device__ __forceinline__ unsigned pk2(float a, float b){
  return (unsigned)f2bf(a) | ((unsigned)f2bf(b)<<16);
}
__device__ __forceinline__ uint4 pk8(const float* f){
  uint4 o; o.x=pk2(f[0],f[1]); o.y=pk2(f[2],f[3]);
  o.z=pk2(f[4],f[5]); o.w=pk2(f[6],f[7]); return o;
}
__device__ __forceinline__ void up8(uint4 v, float* f){
  f[0]=bf2f((unsigned short)(v.x&0xFFFFu)); f[1]=bf2f((unsigned short)(v.x>>16));
  f[2]=bf2f((unsigned short)(v.y&0xFFFFu)); f[3]=bf2f((unsigned short)(v.y>>16));
  f[4]=bf2f((unsigned short)(v.z&0xFFFFu)); f[5]=bf2f((unsigned short)(v.z>>16));
  f[6]=bf2f((unsigned short)(v.w&0xFFFFu)); f[7]=bf2f((unsigned short)(v.w>>16));
}
__device__ __forceinline__ short8_t relu8(short8_t s){
  short8_t r;
  #pragma unroll
  for (int i=0;i<8;i++){ short v = s[i]; r[i] = (v & (short)0x8000) ? (short)0 : v; }
  return r;
}
__device__ __forceinline__ unsigned encOrd(float f){
  unsigned u = __float_as_uint(f);
  return (u & 0x80000000u) ? ~u : (u | 0x80000000u);
}
__device__ __forceinline__ float decOrd(unsigned u){
  return (u & 0x80000000u) ? __uint_as_float(u & 0x7fffffffu)
                           : __uint_as_float(~u);
}

// ---- zero v2x0+v2x1+ksum+gmax ----
__global__ void k_init(char* __restrict__ wsb){
  int i = blockIdx.x*256 + threadIdx.x;
  if (i < NZERO) ((unsigned*)(wsb + V2F0B))[i] = 0u;
}
// ---- GLU weights -> bf16 [n][k] ----
__global__ void k_wcvt(const float* __restrict__ wi0, const float* __restrict__ wo0,
                       const float* __restrict__ wi1, const float* __restrict__ wo1,
                       char* __restrict__ wsb){
  int idx = blockIdx.x*256 + threadIdx.x;
  if (idx >= 65536) return;
  int l = idx >> 15, r = (idx >> 7) & 255, c = idx & 127;
  const float* src = (l==0) ? ((r<128)? wi0 : wo0) : ((r<128)? wi1 : wo1);
  float v = src[(r&127)*128 + c];
  ((unsigned short*)(wsb + WBFB))[l*32768 + r*128 + c] = f2bf(v);
}
// ---- W1,W2 [32][96], proj [64][32], W_regT [16][256] -> bf16 --------------
__global__ void k_wcvt2(const float* __restrict__ W1, const float* __restrict__ W2,
                        const float* __restrict__ proj, const float* __restrict__ W_reg,
                        char* __restrict__ wsb){
  int i = blockIdx.x*256 + threadIdx.x;          // 12288 total
  if (i >= 12288) return;
  unsigned short* dst = (unsigned short*)(wsb + W12B);
  float v;
  if (i < 3072) v = W1[i];
  else if (i < 6144) v = W2[i-3072];
  else if (i < 8192) v = proj[i-6144];
  else {
    int r = (i-8192) >> 8, c = (i-8192) & 255;
    v = (r < 12) ? W_reg[r*256 + c] : 0.f;
  }
  dst[i] = f2bf(v);
}

// ---------- pass1a: h0 (W_in matmul + embeddings) --------------------------
__global__ __launch_bounds__(256) void k_pass1a(
  const float* __restrict__ x, const float* __restrict__ node_emb,
  const float* __restrict__ time_emb, const float* __restrict__ week_emb,
  const float* __restrict__ W_in, const float* __restrict__ b_in,
  char* __restrict__ wsb)
{
  const int b = blockIdx.y;
  const int n = blockIdx.x*256 + threadIdx.x;
  if (n >= NN) return;
  const long row = (long)b*NN + n;
  float xr[36];
  {
    const float4* xp = (const float4*)(x + row*36);
    #pragma unroll
    for (int i=0;i<9;i++){ float4 t=xp[i]; xr[4*i]=t.x; xr[4*i+1]=t.y; xr[4*i+2]=t.z; xr[4*i+3]=t.w; }
  }
  int tidx = (int)(xr[34]*288.0f); tidx = tidx<0?0:(tidx>287?287:tidx);
  int widx = (int)(xr[35]);        widx = widx<0?0:(widx>6?6:widx);
  uint4* h0q = (uint4*)(wsb + H0B) + row*16;
  float hh[32];
  #pragma unroll 1
  for (int jj=0;jj<8;jj++){
    #pragma unroll
    for (int jl=0;jl<4;jl++){
      const int j = jj*4+jl;
      const float* w = W_in + j*36;
      float a0=0.f,a1=0.f,a2=0.f,a3=0.f;
      #pragma unroll
      for (int i=0;i<36;i+=4){ a0+=xr[i]*w[i]; a1+=xr[i+1]*w[i+1]; a2+=xr[i+2]*w[i+2]; a3+=xr[i+3]*w[i+3]; }
      hh[j] = b_in[j] + ((a0+a1)+(a2+a3));
    }
  }
  #pragma unroll
  for (int c=0;c<4;c++) h0q[c] = pk8(hh + 8*c);
  float xg[96];
  {
    const float4* p0 = (const float4*)(node_emb + (long)n*32);
    const float4* p1 = (const float4*)(time_emb + (long)tidx*32);
    const float4* p2 = (const float4*)(week_emb + (long)widx*32);
    #pragma unroll
    for (int i=0;i<8;i++){ float4 t=p0[i]; xg[4*i]=t.x; xg[4*i+1]=t.y; xg[4*i+2]=t.z; xg[4*i+3]=t.w; }
    #pragma unroll
    for (int i=0;i<8;i++){ float4 t=p1[i]; xg[32+4*i]=t.x; xg[32+4*i+1]=t.y; xg[32+4*i+2]=t.z; xg[32+4*i+3]=t.w; }
    #pragma unroll
    for (int i=0;i<8;i++){ float4 t=p2[i]; xg[64+4*i]=t.x; xg[64+4*i+1]=t.y; xg[64+4*i+2]=t.z; xg[64+4*i+3]=t.w; }
  }
  #pragma unroll
  for (int c=0;c<12;c++) h0q[4+c] = pk8(xg + 8*c);
}

// ---------- pass1b (MFMA, persistent): q, k', rm, global key max -----------
__global__ __launch_bounds__(256) void k_pass1b(
  const float* __restrict__ b1, const float* __restrict__ b2,
  char* __restrict__ wsb)
{
  __shared__ unsigned short xgt[64][104];
  __shared__ unsigned short dt[2][64][40];
  __shared__ unsigned short ot[64][72];
  __shared__ float wred[4];
  const int b   = blockIdx.y;
  const int tid = threadIdx.x;
  const int lane= tid & 63;
  const int w   = tid >> 6;
  const int c   = lane & 15;
  const int kg  = lane >> 4;
  const int nblk = gridDim.x;
  const int srow = tid >> 2, sq3 = tid & 3;
  const unsigned short* w1bf = (const unsigned short*)(wsb + W12B);
  const unsigned short* w2bf = w1bf + 3072;
  const unsigned short* pjbf = w1bf + 6144;
  uint4 xv0, xv1, xv2;
  {
    const long r0 = (long)blockIdx.x*64;
    long gr = r0 + srow;
    xv0=(uint4){0,0,0,0}; xv1=xv0; xv2=xv0;
    if (gr < NN){
      const uint4* src = (const uint4*)(wsb + H0B + ((long)b*NN + gr)*256 + 64 + sq3*48);
      xv0=src[0]; xv1=src[1]; xv2=src[2];
    }
  }
  #pragma unroll 1
  for (int tile = blockIdx.x; tile < NT; tile += nblk){
    const long r0blk = (long)tile*64;
    {
      uint4* d = (uint4*)&xgt[srow][sq3*24];
      d[0]=xv0; d[1]=xv1; d[2]=xv2;
    }
    if (tile + nblk < NT){
      const long r1 = (long)(tile + nblk)*64;
      long gr = r1 + srow;
      xv0=(uint4){0,0,0,0}; xv1=xv0; xv2=xv0;
      if (gr < NN){
        const uint4* src = (const uint4*)(wsb + H0B + ((long)b*NN + gr)*256 + 64 + sq3*48);
        xv0=src[0]; xv1=src[1]; xv2=src[2];
      }
    }
    __syncthreads();
    f32x4 accd[2][2];
    #pragma unroll
    for (int s=0;s<2;s++)
      #pragma unroll
      for (int f=0;f<2;f++) accd[s][f] = (f32x4){0.f,0.f,0.f,0.f};
    #pragma unroll
    for (int ks=0;ks<3;ks++){
      short8_t a = *(const short8_t*)&xgt[w*16 + c][ks*32 + kg*8];
      #pragma unroll
      for (int f=0;f<2;f++){
        short8_t bw1 = *(const short8_t*)(w1bf + (f*16+c)*96 + ks*32 + kg*8);
        accd[0][f] = __builtin_amdgcn_mfma_f32_16x16x32_bf16(a, bw1, accd[0][f], 0,0,0);
        short8_t bw2 = *(const short8_t*)(w2bf + (f*16+c)*96 + ks*32 + kg*8);
        accd[1][f] = __builtin_amdgcn_mfma_f32_16x16x32_bf16(a, bw2, accd[1][f], 0,0,0);
      }
    }
    const float DSC = 0.42044820762685725f;   // 32^-0.25
    float dv[2][2][4];
    #pragma unroll
    for (int f=0;f<2;f++){
      float bb1 = b1[f*16+c], bb2 = b2[f*16+c];
      #pragma unroll
      for (int jj=0;jj<4;jj++){
        dv[0][f][jj] = (accd[0][f][jj] + bb1) * DSC;
        dv[1][f][jj] = (accd[1][f][jj] + bb2) * DSC;
      }
    }
    float dg[2][4];
    #pragma unroll
    for (int s=0;s<2;s++)
      #pragma unroll
      for (int jj=0;jj<4;jj++){
        float t = dv[s][0][jj]*dv[s][0][jj] + dv[s][1][jj]*dv[s][1][jj];
        #pragma unroll
        for (int off=1; off<16; off<<=1) t += __shfl_xor(t, off);
        dg[s][jj] = 0.5f * t;
      }
    #pragma unroll
    for (int s=0;s<2;s++)
      #pragma unroll
      for (int f=0;f<2;f++)
        #pragma unroll
        for (int jj=0;jj<4;jj++)
          dt[s][w*16 + kg*4 + jj][f*16 + c] = f2bf(dv[s][f][jj]);
    __syncthreads();
    f32x4 acc2[2][4];
    #pragma unroll
    for (int s=0;s<2;s++){
      short8_t ad = *(const short8_t*)&dt[s][w*16 + c][kg*8];
      #pragma unroll
      for (int f=0;f<4;f++){
        short8_t bp = *(const short8_t*)(pjbf + (f*16+c)*32 + kg*8);
        acc2[s][f] = __builtin_amdgcn_mfma_f32_16x16x32_bf16(ad, bp, (f32x4){0.f,0.f,0.f,0.f}, 0,0,0);
      }
    }
    float mx[2][4];
    #pragma unroll
    for (int s=0;s<2;s++)
      #pragma unroll
      for (int jj=0;jj<4;jj++){
        float t = fmaxf(fmaxf(acc2[s][0][jj],acc2[s][1][jj]),
                        fmaxf(acc2[s][2][jj],acc2[s][3][jj]));
        #pragma unroll
        for (int off=1; off<16; off<<=1) t = fmaxf(t, __shfl_xor(t, off));
        mx[s][jj] = t;
      }
    #pragma unroll
    for (int f=0;f<4;f++)
      #pragma unroll
      for (int jj=0;jj<4;jj++){
        float qv = 0.125f*(__expf(acc2[0][f][jj] - dg[0][jj] - mx[0][jj]) + 1e-6f);
        ot[w*16 + kg*4 + jj][f*16 + c] = f2bf(qv);
      }
    __syncthreads();
    {
      long gr = r0blk + srow;
      if (gr < NN){
        const uint4* s = (const uint4*)&ot[srow][sq3*16];
        uint4* dst = (uint4*)((unsigned short*)(wsb + QB) + ((long)b*NN + gr)*64 + sq3*16);
        dst[0] = s[0]; dst[1] = s[1];
      }
    }
    __syncthreads();
    float bmax = -3.0e38f;
    #pragma unroll
    for (int f=0;f<4;f++)
      #pragma unroll
      for (int jj=0;jj<4;jj++){
        float kv = __expf(acc2[1][f][jj] - mx[1][jj]);
        ot[w*16 + kg*4 + jj][f*16 + c] = f2bf(kv);
      }
    #pragma unroll
    for (int jj=0;jj<4;jj++){
      long gr = r0blk + w*16 + kg*4 + jj;
      bool val = (gr < NN);
      if (val && c==0)
        ((float*)(wsb + RMB))[(long)b*NN + gr] = mx[1][jj] - dg[1][jj];
      if (val) bmax = fmaxf(bmax, mx[1][jj]);
    }
    #pragma unroll
    for (int off=32; off>0; off>>=1) bmax = fmaxf(bmax, __shfl_xor(bmax, off));
    if (lane==0) wred[w] = bmax;
    __syncthreads();
    {
      long gr = r0blk + srow;
      if (gr < NN){
        const uint4* s = (const uint4*)&ot[srow][sq3*16];
        uint4* dst = (uint4*)((unsigned short*)(wsb + KKB) + ((long)b*NN + gr)*64 + sq3*16);
        dst[0] = s[0]; dst[1] = s[1];
      }
    }
    if (tid==0){
      float m2 = fmaxf(fmaxf(wred[0],wred[1]), fmaxf(wred[2],wred[3]));
      atomicMax((unsigned*)(wsb + GMB) + b, encOrd(m2));
    }
    __syncthreads();   // ot/wred WAR before next tile
  }
}

// ---------- fused GLU + k-finalize (+ksum) + MFMA reduce -------------------
// persistent tile-stride; gacc[16] GLU (ILP-optimal); 2 barriers/tile
__global__ __launch_bounds__(256) void k_glured(
  char* __restrict__ wsb, const unsigned short* __restrict__ hsrc,
  const unsigned short* __restrict__ wbf,
  const float* __restrict__ bi, const float* __restrict__ bo,
  float* __restrict__ v2x_out, float* __restrict__ ksout)
{
  __shared__ unsigned short ht[64][132];       // 16896 B
  __shared__ unsigned short htT[128][72];      // 18432 B
  __shared__ unsigned short ktl[2][64][72];    // 2 x 9216 B
  __shared__ float red[256];
  const int b = blockIdx.y;
  const int tid = threadIdx.x;
  const int lane = tid & 63;
  const int w = tid >> 6;
  const int c = lane & 15;
  const int kg = lane >> 4;
  const int nblk = gridDim.x;
  const float gm = decOrd(((const unsigned*)(wsb + GMB))[b]);
  const float* rm = (const float*)(wsb + RMB) + (long)b*NN;
  const uint4* kbase = (const uint4*)(wsb + KKB) + (long)b*NN*8;
  f32x4 racc[8];
  #pragma unroll
  for (int f=0;f<8;f++) racc[f] = (f32x4){0.f,0.f,0.f,0.f};
  float ksacc = 0.f;
  float bi_l[8], bo_l[8];
  #pragma unroll
  for (int f=0;f<8;f++){ bi_l[f] = bi[f*16+c]; bo_l[f] = bo[f*16+c]; }
  const int krr = tid>>3, kcc = tid&7;
  const int srow = tid>>2, sq3 = tid&3;
  const int rswz = ((w*16 + c) >> 3) & 7;
  uint4 hv0,hv1,hv2,hv3, krA,krB; float rmA,rmB;
  {
    const long r0 = (long)blockIdx.x*64;
    long gr = r0 + srow;
    hv0=(uint4){0,0,0,0}; hv1=hv0; hv2=hv0; hv3=hv0;
    if (gr < NN){
      const uint4* s = (const uint4*)(hsrc + ((long)b*NN + gr)*128 + sq3*32);
      hv0=s[0]; hv1=s[1]; hv2=s[2]; hv3=s[3];
    }
    krA=(uint4){0,0,0,0}; krB=krA; rmA=0.f; rmB=0.f;
    long gA = r0 + krr;      if (gA < NN){ krA = kbase[gA*8 + kcc]; rmA = rm[gA]; }
    long gB = r0 + krr + 32; if (gB < NN){ krB = kbase[gB*8 + kcc]; rmB = rm[gB]; }
  }
  int p = 0;
  #pragma unroll 1
  for (int tile = blockIdx.x; tile < NT; tile += nblk){
    const long r0 = (long)tile*64;
    // Phase A: write ht + ktl[p] from prefetched regs; issue next prefetch
    {
      uint4* d = (uint4*)&ht[srow][sq3*32];
      d[0]=hv0; d[1]=hv1; d[2]=hv2; d[3]=hv3;
    }
    {
      bool vA = (r0 + krr) < NN;
      bool vB = (r0 + krr + 32) < NN;
      float sA = __expf(rmA - gm), sB = __expf(rmB - gm);
      float ta[8], tb[8];
      up8(krA, ta); up8(krB, tb);
      #pragma unroll
      for (int i=0;i<8;i++){
        ta[i] = vA ? 0.125f*(ta[i]*sA + 1e-6f) : 0.f;
        tb[i] = vB ? 0.125f*(tb[i]*sB + 1e-6f) : 0.f;
      }
      const int pA = (((krr>>3) ^ kcc) << 3) | (krr & 7);
      const int pB = ((((krr>>3)+4) ^ kcc) << 3) | (krr & 7);
      #pragma unroll
      for (int i=0;i<8;i++){
        ktl[p][kcc*8+i][pA] = f2bf(ta[i]);
        ktl[p][kcc*8+i][pB] = f2bf(tb[i]);
      }
    }
    if (tile + nblk < NT){
      const long r1 = (long)(tile + nblk)*64;
      long gr = r1 + srow;
      hv0=(uint4){0,0,0,0}; hv1=hv0; hv2=hv0; hv3=hv0;
      if (gr < NN){
        const uint4* s = (const uint4*)(hsrc + ((long)b*NN + gr)*128 + sq3*32);
        hv0=s[0]; hv1=s[1]; hv2=s[2]; hv3=s[3];
      }
      krA=(uint4){0,0,0,0}; krB=krA; rmA=0.f; rmB=0.f;
      long gA = r1 + krr;      if (gA < NN){ krA = kbase[gA*8 + kcc]; rmA = rm[gA]; }
      long gB = r1 + krr + 32; if (gB < NN){ krB = kbase[gB*8 + kcc]; rmB = rm[gB]; }
    }
    __syncthreads();   // barrier A: ht/ktl[p] ready (also covers prior reduce)
    // Phase B: GLU MFMA (gacc[16], ILP-optimal), write htT, ksum
    f32x4 gacc[16];
    #pragma unroll
    for (int f=0;f<16;f++) gacc[f] = (f32x4){0.f,0.f,0.f,0.f};
    #pragma unroll
    for (int ks=0;ks<4;ks++){
      short8_t a = *(const short8_t*)&ht[w*16 + c][ks*32 + kg*8];
      #pragma unroll
      for (int f=0;f<16;f++){
        short8_t bb = *(const short8_t*)(wbf + (f*16 + c)*128 + ks*32 + kg*8);
        gacc[f] = __builtin_amdgcn_mfma_f32_16x16x32_bf16(a, bb, gacc[f], 0, 0, 0);
      }
    }
    #pragma unroll
    for (int f=0;f<8;f++)
      #pragma unroll
      for (int j=0;j<4;j++){
        float aa = gacc[f][j]   + bi_l[f];
        float cc2= gacc[f+8][j] + bo_l[f];
        float o  = cc2 / (1.0f + __expf(-aa));
        bool val = (r0 + w*16 + kg*4 + j) < NN;
        htT[f*16 + c][w*16 + kg*4 + j] = val ? f2bf(o) : (unsigned short)0;
      }
    if (ksout){
      int m = tid & 63, n0 = (tid>>6)*16;
      int sm = (m>>3)&7;
      #pragma unroll
      for (int n=0;n<16;n++){
        int nn = n0+n;
        ksacc += bf2f(ktl[p][m][(((nn>>3)^sm)<<3)|(nn&7)]);
      }
    }
    __syncthreads();   // barrier B: htT ready
    // Phase C: reduce MFMA (reads ktl[p] + htT only)
    #pragma unroll
    for (int ks=0;ks<2;ks++){
      short8_t a = *(const short8_t*)&ktl[p][w*16 + c][((ks*4 + kg) ^ rswz) << 3];
      #pragma unroll
      for (int f=0;f<8;f++){
        short8_t bb = *(const short8_t*)&htT[f*16 + c][ks*32 + kg*8];
        racc[f] = __builtin_amdgcn_mfma_f32_16x16x32_bf16(a, bb, racc[f], 0, 0, 0);
      }
    }
    p ^= 1;
    // no barrier: next Phase A writes ht (unread in C) and ktl[p^1] (unread in C)
  }
  float* v2x = v2x_out + (long)b*8192;
  #pragma unroll
  for (int f=0;f<8;f++)
    #pragma unroll
    for (int j=0;j<4;j++)
      atomicAdd(&v2x[(w*16 + kg*4 + j)*128 + f*16 + c], racc[f][j]);
  if (ksout){
    red[tid] = ksacc;
    __syncthreads();
    if (tid < 64)
      atomicAdd(ksout + b*64 + tid,
                red[tid]+red[64+tid]+red[128+tid]+red[192+tid]);
  }
}

// ---------- attn0 + residual(h0) + LN0 -> h1 (persistent) ------------------
__global__ __launch_bounds__(256) void k_attnln(
  char* __restrict__ wsb, const float* __restrict__ v2f_base,
  const float* __restrict__ g0, const float* __restrict__ bt0)
{
  __shared__ unsigned short ht[64][132];    // 16896 B
  __shared__ unsigned short v2s[144*72];    // 20736 B (persistent across tiles)
  const int b = blockIdx.y;
  const int tid = threadIdx.x;
  const int lane = tid & 63;
  const int w  = tid >> 6;
  const int c  = lane & 15;
  const int kg = lane >> 4;
  const int nblk = gridDim.x;
  const int rrow = tid>>2, rq3 = tid&3;
  const unsigned short* qb = (const unsigned short*)(wsb + QB) + (long)b*NN*64;
  const unsigned short* h0g = (const unsigned short*)(wsb + H0B) + (long)b*NN*128;
  unsigned short* h1g = (unsigned short*)(wsb + H1B) + (long)b*NN*128;
  // stage v2s directly from fp32 v2x + ksum (replaces k_v2cvt)
  {
    const float* v2f = v2f_base + (long)b*8192;
    const float* ks  = (const float*)(wsb + KSB) + b*64;
    for (int i = tid; i < 9216; i += 256){
      int n = i >> 6, m = i & 63;
      float v = (n < 128) ? v2f[m*128 + n] : ((n==128) ? ks[m] : 0.f);
      v2s[n*72 + m] = f2bf(v);
    }
  }
  short8_t aq0, aq1;
  uint4 rh0, rh1, rh2, rh3;
  {
    const long r0 = (long)blockIdx.x*64;
    if (r0 + w*16 + c < NN){
      const unsigned short* qrow = qb + (r0 + w*16 + c)*64 + kg*8;
      aq0 = *(const short8_t*)qrow; aq1 = *(const short8_t*)(qrow + 32);
    } else { aq0 = (short8_t){0,0,0,0,0,0,0,0}; aq1 = aq0; }
    rh0=(uint4){0,0,0,0}; rh1=rh0; rh2=rh0; rh3=rh0;
    if (r0 + rrow < NN){
      const uint4* hs = (const uint4*)(h0g + (r0 + rrow)*128 + rq3*32);
      rh0=hs[0]; rh1=hs[1]; rh2=hs[2]; rh3=hs[3];
    }
  }
  __syncthreads();   // v2s ready
  #pragma unroll 1
  for (int tile = blockIdx.x; tile < NT; tile += nblk){
    const long r0blk = (long)tile*64;
    const long rgr = r0blk + rrow;
    f32x4 acc[9];
    #pragma unroll
    for (int f=0;f<9;f++) acc[f] = (f32x4){0.f,0.f,0.f,0.f};
    #pragma unroll
    for (int f=0;f<9;f++){
      short8_t b0 = *(const short8_t*)&v2s[(f*16 + c)*72 + kg*8];
      acc[f] = __builtin_amdgcn_mfma_f32_16x16x32_bf16(aq0, b0, acc[f], 0, 0, 0);
      short8_t b1v = *(const short8_t*)&v2s[(f*16 + c)*72 + 32 + kg*8];
      acc[f] = __builtin_amdgcn_mfma_f32_16x16x32_bf16(aq1, b1v, acc[f], 0, 0, 0);
    }
    float inv[4];
    #pragma unroll
    for (int j=0;j<4;j++) inv[j] = 1.0f / __shfl(acc[8][j], (lane & 48));
    #pragma unroll
    for (int f=0;f<8;f++)
      #pragma unroll
      for (int j=0;j<4;j++)
        ht[w*16 + kg*4 + j][f*16 + c] = f2bf(acc[f][j]*inv[j]);
    __syncthreads();
    short8_t aq0n, aq1n;
    uint4 nh0, nh1, nh2, nh3;
    {
      aq0n = (short8_t){0,0,0,0,0,0,0,0}; aq1n = aq0n;
      nh0=(uint4){0,0,0,0}; nh1=nh0; nh2=nh0; nh3=nh0;
      if (tile + nblk < NT){
        const long r1 = (long)(tile + nblk)*64;
        if (r1 + w*16 + c < NN){
          const unsigned short* qrow = qb + (r1 + w*16 + c)*64 + kg*8;
          aq0n = *(const short8_t*)qrow; aq1n = *(const short8_t*)(qrow + 32);
        }
        if (r1 + rrow < NN){
          const uint4* hs = (const uint4*)(h0g + (r1 + rrow)*128 + rq3*32);
          nh0=hs[0]; nh1=hs[1]; nh2=hs[2]; nh3=hs[3];
        }
      }
    }
    {
      float tv[32];
      {
        const uint4* os = (const uint4*)&ht[rrow][rq3*32];
        uint4 o0=os[0],o1=os[1],o2=os[2],o3=os[3];
        up8(o0,tv); up8(o1,tv+8); up8(o2,tv+16); up8(o3,tv+24);
      }
      {
        float hv[32];
        up8(rh0,hv); up8(rh1,hv+8); up8(rh2,hv+16); up8(rh3,hv+24);
        #pragma unroll
        for (int i=0;i<32;i++) tv[i] += hv[i];
      }
      float s = 0.f;
      #pragma unroll
      for (int i=0;i<32;i++) s += tv[i];
      s += __shfl_xor(s, 1); s += __shfl_xor(s, 2);
      float mu = s * (1.0f/128.0f);
      float vv = 0.f;
      #pragma unroll
      for (int i=0;i<32;i++){ float e = tv[i]-mu; vv += e*e; }
      vv += __shfl_xor(vv, 1); vv += __shfl_xor(vv, 2);
      float rs = rsqrtf(vv * (1.0f/128.0f) + 1e-5f);
      const float4* gp = (const float4*)(g0 + rq3*32);
      const float4* bp = (const float4*)(bt0 + rq3*32);
      float h1v[32];
      #pragma unroll
      for (int i8=0;i8<8;i8++){
        float4 g4 = gp[i8], b4 = bp[i8];
        h1v[i8*4  ] = (tv[i8*4  ]-mu)*rs*g4.x + b4.x;
        h1v[i8*4+1] = (tv[i8*4+1]-mu)*rs*g4.y + b4.y;
        h1v[i8*4+2] = (tv[i8*4+2]-mu)*rs*g4.z + b4.z;
        h1v[i8*4+3] = (tv[i8*4+3]-mu)*rs*g4.w + b4.w;
      }
      if (rgr < NN){
        uint4 p0=pk8(h1v), p1=pk8(h1v+8), p2=pk8(h1v+16), p3=pk8(h1v+24);
        uint4* dst = (uint4*)(h1g + rgr*128 + rq3*32);
        dst[0]=p0; dst[1]=p1; dst[2]=p2; dst[3]=p3;
      }
    }
    __syncthreads();   // ht WAR for next tile
    aq0=aq0n; aq1=aq1n; rh0=nh0; rh1=nh1; rh2=nh2; rh3=nh3;
  }
}

// ---------- attn1 + residual(h1) + LN1 + MFMA head (persistent) ------------
__global__ __launch_bounds__(256) void k_attnhead(
  char* __restrict__ wsb, const float* __restrict__ v2f_base,
  const float* __restrict__ g1, const float* __restrict__ bt1,
  const float* __restrict__ b_reg, float* __restrict__ out)
{
  __shared__ unsigned short ht[64][132];    // 16896 B
  __shared__ unsigned short v2s[144*72];    // 20736 B (persistent)
  __shared__ unsigned short h0t[64][136];   // 17408 B
  const int b = blockIdx.y;
  const int tid = threadIdx.x;
  const int lane = tid & 63;
  const int w  = tid >> 6;
  const int c  = lane & 15;
  const int kg = lane >> 4;
  const int nblk = gridDim.x;
  const int rrow = tid>>2, rq3 = tid&3;
  const unsigned short* qb  = (const unsigned short*)(wsb + QB) + (long)b*NN*64;
  const unsigned short* h0g = (const unsigned short*)(wsb + H0B) + (long)b*NN*128;
  const unsigned short* h1g = (const unsigned short*)(wsb + H1B) + (long)b*NN*128;
  {
    const float* v2f = v2f_base + (long)b*8192;
    const float* ks  = (const float*)(wsb + KSB) + b*64;
    for (int i = tid; i < 9216; i += 256){
      int n = i >> 6, m = i & 63;
      float v = (n < 128) ? v2f[m*128 + n] : ((n==128) ? ks[m] : 0.f);
      v2s[n*72 + m] = f2bf(v);
    }
  }
  short8_t aq0, aq1;
  uint4 rh0, rh1, rh2, rh3, ah0, ah1, ah2, ah3;
  {
    const long r0 = (long)blockIdx.x*64;
    if (r0 + w*16 + c < NN){
      const unsigned short* qrow = qb + (r0 + w*16 + c)*64 + kg*8;
      aq0 = *(const short8_t*)qrow; aq1 = *(const short8_t*)(qrow + 32);
    } else { aq0 = (short8_t){0,0,0,0,0,0,0,0}; aq1 = aq0; }
    rh0=(uint4){0,0,0,0}; rh1=rh0; rh2=rh0; rh3=rh0;
    ah0=rh0; ah1=rh0; ah2=rh0; ah3=rh0;
    if (r0 + rrow < NN){
      const uint4* hs = (const uint4*)(h1g + (r0 + rrow)*128 + rq3*32);
      rh0=hs[0]; rh1=hs[1]; rh2=hs[2]; rh3=hs[3];
      const uint4* h0s = (const uint4*)(h0g + (r0 + rrow)*128 + rq3*32);
      ah0=h0s[0]; ah1=h0s[1]; ah2=h0s[2]; ah3=h0s[3];
    }
  }
  __syncthreads();   // v2s ready
  #pragma unroll 1
  for (int tile = blockIdx.x; tile < NT; tile += nblk){
    const long r0blk = (long)tile*64;
    const long r0w = r0blk + w*16;
    const long rgr = r0blk + rrow;
    f32x4 acc[9];
    #pragma unroll
    for (int f=0;f<9;f++) acc[f] = (f32x4){0.f,0.f,0.f,0.f};
    #pragma unroll
    for (int f=0;f<9;f++){
      short8_t b0 = *(const short8_t*)&v2s[(f*16 + c)*72 + kg*8];
      acc[f] = __builtin_amdgcn_mfma_f32_16x16x32_bf16(aq0, b0, acc[f], 0, 0, 0);
      short8_t b1v = *(const short8_t*)&v2s[(f*16 + c)*72 + 32 + kg*8];
      acc[f] = __builtin_amdgcn_mfma_f32_16x16x32_bf16(aq1, b1v, acc[f], 0, 0, 0);
    }
    float inv[4];
    #pragma unroll
    for (int j=0;j<4;j++) inv[j] = 1.0f / __shfl(acc[8][j], (lane & 48));
    #pragma unroll
    for (int f=0;f<8;f++)
      #pragma unroll
      for (int j=0;j<4;j++)
        ht[w*16 + kg*4 + j][f*16 + c] = f2bf(acc[f][j]*inv[j]);
    __syncthreads();
    short8_t aq0n, aq1n;
    uint4 nh0, nh1, nh2, nh3, na0, na1, na2, na3;
    {
      aq0n = (short8_t){0,0,0,0,0,0,0,0}; aq1n = aq0n;
      nh0=(uint4){0,0,0,0}; nh1=nh0; nh2=nh0; nh3=nh0;
      na0=nh0; na1=nh0; na2=nh0; na3=nh0;
      if (tile + nblk < NT){
        const long r1 = (long)(tile + nblk)*64;
        if (r1 + w*16 + c < NN){
          const unsigned short* qrow = qb + (r1 + w*16 + c)*64 + kg*8;
          aq0n = *(const short8_t*)qrow; aq1n = *(const short8_t*)(qrow + 32);
        }
        if (r1 + rrow < NN){
          const uint4* hs = (const uint4*)(h1g + (r1 + rrow)*128 + rq3*32);
          nh0=hs[0]; nh1=hs[1]; nh2=hs[2]; nh3=hs[3];
          const uint4* h0s = (const uint4*)(h0g + (r1 + rrow)*128 + rq3*32);
          na0=h0s[0]; na1=h0s[1]; na2=h0s[2]; na3=h0s[3];
        }
      }
    }
    {
      uint4* hd = (uint4*)&h0t[rrow][rq3*32];
      hd[0]=ah0; hd[1]=ah1; hd[2]=ah2; hd[3]=ah3;
      float tv[32];
      {
        const uint4* os = (const uint4*)&ht[rrow][rq3*32];
        uint4 o0=os[0],o1=os[1],o2=os[2],o3=os[3];
        up8(o0,tv); up8(o1,tv+8); up8(o2,tv+16); up8(o3,tv+24);
      }
      {
        float hv[32];
        up8(rh0,hv); up8(rh1,hv+8); up8(rh2,hv+16); up8(rh3,hv+24);
        #pragma unroll
        for (int i=0;i<32;i++) tv[i] += hv[i];
      }
      float s = 0.f;
      #pragma unroll
      for (int i=0;i<32;i++) s += tv[i];
      s += __shfl_xor(s, 1); s += __shfl_xor(s, 2);
      float mu = s * (1.0f/128.0f);
      float vv = 0.f;
      #pragma unroll
      for (int i=0;i<32;i++){ float e = tv[i]-mu; vv += e*e; }
      vv += __shfl_xor(vv, 1); vv += __shfl_xor(vv, 2);
      float rs = rsqrtf(vv * (1.0f/128.0f) + 1e-5f);
      const float4* gp = (const float4*)(g1 + rq3*32);
      const float4* bp = (const float4*)(bt1 + rq3*32);
      float h2v[32];
      #pragma unroll
      for (int i8=0;i8<8;i8++){
        float4 g4 = gp[i8], b4 = bp[i8];
        h2v[i8*4  ] = fmaxf((tv[i8*4  ]-mu)*rs*g4.x + b4.x, 0.f);
        h2v[i8*4+1] = fmaxf((tv[i8*4+1]-mu)*rs*g4.y + b4.y, 0.f);
        h2v[i8*4+2] = fmaxf((tv[i8*4+2]-mu)*rs*g4.z + b4.z, 0.f);
        h2v[i8*4+3] = fmaxf((tv[i8*4+3]-mu)*rs*g4.w + b4.w, 0.f);
      }
      uint4 p0=pk8(h2v), p1=pk8(h2v+8), p2=pk8(h2v+16), p3=pk8(h2v+24);
      uint4* d = (uint4*)&ht[rrow][rq3*32];
      d[0]=p0; d[1]=p1; d[2]=p2; d[3]=p3;
    }
    __syncthreads();
    const unsigned short* wregT = (const unsigned short*)(wsb + W12B) + 8192;
    f32x4 hacc = (f32x4){0.f,0.f,0.f,0.f};
    #pragma unroll
    for (int ks=0;ks<8;ks++){
      short8_t a;
      if (ks < 4)
        a = relu8(*(const short8_t*)&h0t[w*16 + c][ks*32 + kg*8]);
      else
        a = *(const short8_t*)&ht[w*16 + c][(ks-4)*32 + kg*8];
      short8_t bb = *(const short8_t*)(wregT + c*256 + ks*32 + kg*8);
      hacc = __builtin_amdgcn_mfma_f32_16x16x32_bf16(a, bb, hacc, 0, 0, 0);
    }
    if (c < 12){
      float br = b_reg[c];
      #pragma unroll
      for (int j=0;j<4;j++){
        long gr = r0w + kg*4 + j;
        if (gr < NN)
          out[((long)b*12 + c)*NN + gr] = hacc[j] + br;
      }
    }
    __syncthreads();   // ht/h0t WAR for next tile
    aq0=aq0n; aq1=aq1n;
    rh0=nh0; rh1=nh1; rh2=nh2; rh3=nh3;
    ah0=na0; ah1=na1; ah2=na2; ah3=na3;
  }
}

extern "C" void kernel_launch(void* const* d_in, const int* in_sizes, int n_in,
                              void* d_out, int out_size, void* d_ws, size_t ws_size,
                              hipStream_t stream)
{
  const float* x        = (const float*)d_in[0];
  const float* node_emb = (const float*)d_in[1];
  const float* time_emb = (const float*)d_in[2];
  const float* week_emb = (const float*)d_in[3];
  const float* W_in     = (const float*)d_in[4];
  const float* b_in     = (const float*)d_in[5];
  const float* W1       = (const float*)d_in[6];
  const float* b1       = (const float*)d_in[7];
  const float* W2       = (const float*)d_in[8];
  const float* b2       = (const float*)d_in[9];
  const float* W_reg    = (const float*)d_in[10];
  const float* b_reg    = (const float*)d_in[11];
  const float* proj     = (const float*)d_in[12];
  const float* fc_in0_w = (const float*)d_in[13];
  const float* fc_in0_b = (const float*)d_in[14];
  const float* fc_out0_w= (const float*)d_in[15];
  const float* fc_out0_b= (const float*)d_in[16];
  const float* ln0_g    = (const float*)d_in[17];
  const float* ln0_b    = (const float*)d_in[18];
  const float* fc_in1_w = (const float*)d_in[19];
  const float* fc_in1_b = (const float*)d_in[20];
  const float* fc_out1_w= (const float*)d_in[21];
  const float* fc_out1_b= (const float*)d_in[22];
  const float* ln1_g    = (const float*)d_in[23];
  const float* ln1_b    = (const float*)d_in[24];
  char* wsb  = (char*)d_ws;
  float* out = (float*)d_out;

  dim3 rowgrid((NN+255)/256, NB);     // (196, 4)
  dim3 pgrid(128, NB);                // persistent: 512 blocks, tile-stride

  k_init  <<<258, 256, 0, stream>>>(wsb);
  k_wcvt  <<<256, 256, 0, stream>>>(fc_in0_w, fc_out0_w, fc_in1_w, fc_out1_w, wsb);
  k_wcvt2 <<<48, 256, 0, stream>>>(W1, W2, proj, W_reg, wsb);
  k_pass1a<<<rowgrid, 256, 0, stream>>>(x, node_emb, time_emb, week_emb,
                                        W_in, b_in, wsb);
  k_pass1b<<<pgrid, 256, 0, stream>>>(b1, b2, wsb);
  k_glured<<<pgrid, 256, 0, stream>>>(wsb, (const unsigned short*)(wsb + H0B),
                                      (const unsigned short*)(wsb + WBFB),
                                      fc_in0_b, fc_out0_b,
                                      (float*)(wsb + V2F0B), (float*)(wsb + KSB));
  k_attnln<<<pgrid, 256, 0, stream>>>(wsb, (const float*)(wsb + V2F0B), ln0_g, ln0_b);
  k_glured<<<pgrid, 256, 0, stream>>>(wsb, (const unsigned short*)(wsb + H1B),
                                      (const unsigned short*)(wsb + WBFB) + 32768,
                                      fc_in1_b, fc_out1_b,
                                      (float*)(wsb + V2F1B), (float*)nullptr);
  k_attnhead<<<pgrid, 256, 0, stream>>>(wsb, (const float*)(wsb + V2F1B),
                                        ln1_g, ln1_b, b_reg, out);
}

// Round 21
// 369.219 us; speedup vs baseline: 1.2305x; 1.0676x over previous
//
#include <hip/hip_runtime.h>

#define NB 4
#define NN 50000
#define NT 784   // 64-row tiles per batch (784*64 = 50176 >= NN)

// ---- workspace byte offsets (total ~154.9 MB, < proven 205.9 MB) ----
#define H0B    0L
#define H1B    51200000L
#define QB     102400000L
#define KKB    128000000L    // k' (unfinalized, bf16)
#define RMB    153600000L    // fp32 rm [4*50000]
#define WBFB   154400000L    // bf16 GLU weights: layer0 [256][128], layer1 at +65536B
#define V2F0B  154531072L    // fp32 v2x layer0 [4][64][128]
#define V2F1B  154662144L    // fp32 v2x layer1
#define KSB    154793216L    // fp32 ksum [4][64]
#define GMB    154794240L    // 4 uints
#define W12B   154795264L    // bf16: W1 [32][96], W2 [32][96], proj [64][32], W_regT [16][256]
#define V2TB   154819840L    // bf16 v2x^T+ksum [4][144][64]
#define NZERO  65796         // words zeroed at V2F0B (v2x0+v2x1+ksum+gmax)

typedef short short8_t __attribute__((ext_vector_type(8)));
typedef float f32x4 __attribute__((ext_vector_type(4)));

__device__ __forceinline__ unsigned short f2bf(float f){
  unsigned u = __float_as_uint(f);
  return (unsigned short)((u + 0x7FFFu + ((u>>16)&1u)) >> 16);
}
__device__ __forceinline__ float bf2f(unsigned short s){
  return __uint_as_float(((unsigned)s)<<16);
}
__device__ __forceinline__ unsigned pk2(float a, float b){
  return (unsigned)f2bf(a) | ((unsigned)f2bf(b)<<16);
}
__device__ __forceinline__ uint4 pk8(const float* f){
  uint4 o; o.x=pk2(f[0],f[1]); o.y=pk2(f[2],f[3]);
  o.z=pk2(f[4],f[5]); o.w=pk2(f[6],f[7]); return o;
}
__device__ __forceinline__ void up8(uint4 v, float* f){
  f[0]=bf2f((unsigned short)(v.x&0xFFFFu)); f[1]=bf2f((unsigned short)(v.x>>16));
  f[2]=bf2f((unsigned short)(v.y&0xFFFFu)); f[3]=bf2f((unsigned short)(v.y>>16));
  f[4]=bf2f((unsigned short)(v.z&0xFFFFu)); f[5]=bf2f((unsigned short)(v.z>>16));
  f[6]=bf2f((unsigned short)(v.w&0xFFFFu)); f[7]=bf2f((unsigned short)(v.w>>16));
}
__device__ __forceinline__ short8_t relu8(short8_t s){
  short8_t r;
  #pragma unroll
  for (int i=0;i<8;i++){ short v = s[i]; r[i] = (v & (short)0x8000) ? (short)0 : v; }
  return r;
}
__device__ __forceinline__ unsigned encOrd(float f){
  unsigned u = __float_as_uint(f);
  return (u & 0x80000000u) ? ~u : (u | 0x80000000u);
}
__device__ __forceinline__ float decOrd(unsigned u){
  return (u & 0x80000000u) ? __uint_as_float(u & 0x7fffffffu)
                           : __uint_as_float(~u);
}

// ---- zero v2x0+v2x1+ksum+gmax ----
__global__ void k_init(char* __restrict__ wsb){
  int i = blockIdx.x*256 + threadIdx.x;
  if (i < NZERO) ((unsigned*)(wsb + V2F0B))[i] = 0u;
}
// ---- GLU weights -> bf16 [n][k] ----
__global__ void k_wcvt(const float* __restrict__ wi0, const float* __restrict__ wo0,
                       const float* __restrict__ wi1, const float* __restrict__ wo1,
                       char* __restrict__ wsb){
  int idx = blockIdx.x*256 + threadIdx.x;
  if (idx >= 65536) return;
  int l = idx >> 15, r = (idx >> 7) & 255, c = idx & 127;
  const float* src = (l==0) ? ((r<128)? wi0 : wo0) : ((r<128)? wi1 : wo1);
  float v = src[(r&127)*128 + c];
  ((unsigned short*)(wsb + WBFB))[l*32768 + r*128 + c] = f2bf(v);
}
// ---- W1,W2 [32][96], proj [64][32], W_regT [16][256] -> bf16 --------------
__global__ void k_wcvt2(const float* __restrict__ W1, const float* __restrict__ W2,
                        const float* __restrict__ proj, const float* __restrict__ W_reg,
                        char* __restrict__ wsb){
  int i = blockIdx.x*256 + threadIdx.x;          // 12288 total
  if (i >= 12288) return;
  unsigned short* dst = (unsigned short*)(wsb + W12B);
  float v;
  if (i < 3072) v = W1[i];
  else if (i < 6144) v = W2[i-3072];
  else if (i < 8192) v = proj[i-6144];
  else {
    int r = (i-8192) >> 8, c = (i-8192) & 255;
    v = (r < 12) ? W_reg[r*256 + c] : 0.f;
  }
  dst[i] = f2bf(v);
}

// ---------- pass1a: h0 (W_in matmul + embeddings) --------------------------
__global__ __launch_bounds__(256) void k_pass1a(
  const float* __restrict__ x, const float* __restrict__ node_emb,
  const float* __restrict__ time_emb, const float* __restrict__ week_emb,
  const float* __restrict__ W_in, const float* __restrict__ b_in,
  char* __restrict__ wsb)
{
  const int b = blockIdx.y;
  const int n = blockIdx.x*256 + threadIdx.x;
  if (n >= NN) return;
  const long row = (long)b*NN + n;
  float xr[36];
  {
    const float4* xp = (const float4*)(x + row*36);
    #pragma unroll
    for (int i=0;i<9;i++){ float4 t=xp[i]; xr[4*i]=t.x; xr[4*i+1]=t.y; xr[4*i+2]=t.z; xr[4*i+3]=t.w; }
  }
  int tidx = (int)(xr[34]*288.0f); tidx = tidx<0?0:(tidx>287?287:tidx);
  int widx = (int)(xr[35]);        widx = widx<0?0:(widx>6?6:widx);
  uint4* h0q = (uint4*)(wsb + H0B) + row*16;
  float hh[32];
  #pragma unroll 1
  for (int jj=0;jj<8;jj++){
    #pragma unroll
    for (int jl=0;jl<4;jl++){
      const int j = jj*4+jl;
      const float* w = W_in + j*36;
      float a0=0.f,a1=0.f,a2=0.f,a3=0.f;
      #pragma unroll
      for (int i=0;i<36;i+=4){ a0+=xr[i]*w[i]; a1+=xr[i+1]*w[i+1]; a2+=xr[i+2]*w[i+2]; a3+=xr[i+3]*w[i+3]; }
      hh[j] = b_in[j] + ((a0+a1)+(a2+a3));
    }
  }
  #pragma unroll
  for (int c=0;c<4;c++) h0q[c] = pk8(hh + 8*c);
  float xg[96];
  {
    const float4* p0 = (const float4*)(node_emb + (long)n*32);
    const float4* p1 = (const float4*)(time_emb + (long)tidx*32);
    const float4* p2 = (const float4*)(week_emb + (long)widx*32);
    #pragma unroll
    for (int i=0;i<8;i++){ float4 t=p0[i]; xg[4*i]=t.x; xg[4*i+1]=t.y; xg[4*i+2]=t.z; xg[4*i+3]=t.w; }
    #pragma unroll
    for (int i=0;i<8;i++){ float4 t=p1[i]; xg[32+4*i]=t.x; xg[32+4*i+1]=t.y; xg[32+4*i+2]=t.z; xg[32+4*i+3]=t.w; }
    #pragma unroll
    for (int i=0;i<8;i++){ float4 t=p2[i]; xg[64+4*i]=t.x; xg[64+4*i+1]=t.y; xg[64+4*i+2]=t.z; xg[64+4*i+3]=t.w; }
  }
  #pragma unroll
  for (int c=0;c<12;c++) h0q[4+c] = pk8(xg + 8*c);
}

// ---------- pass1b (MFMA, persistent): q, k', rm, global key max -----------
__global__ __launch_bounds__(256) void k_pass1b(
  const float* __restrict__ b1, const float* __restrict__ b2,
  char* __restrict__ wsb)
{
  __shared__ unsigned short xgt[64][104];
  __shared__ unsigned short dt[2][64][40];
  __shared__ unsigned short ot[64][72];
  __shared__ float wred[4];
  const int b   = blockIdx.y;
  const int tid = threadIdx.x;
  const int lane= tid & 63;
  const int w   = tid >> 6;
  const int c   = lane & 15;
  const int kg  = lane >> 4;
  const int nblk = gridDim.x;
  const int srow = tid >> 2, sq3 = tid & 3;
  const unsigned short* w1bf = (const unsigned short*)(wsb + W12B);
  const unsigned short* w2bf = w1bf + 3072;
  const unsigned short* pjbf = w1bf + 6144;
  uint4 xv0, xv1, xv2;
  {
    const long r0 = (long)blockIdx.x*64;
    long gr = r0 + srow;
    xv0=(uint4){0,0,0,0}; xv1=xv0; xv2=xv0;
    if (gr < NN){
      const uint4* src = (const uint4*)(wsb + H0B + ((long)b*NN + gr)*256 + 64 + sq3*48);
      xv0=src[0]; xv1=src[1]; xv2=src[2];
    }
  }
  #pragma unroll 1
  for (int tile = blockIdx.x; tile < NT; tile += nblk){
    const long r0blk = (long)tile*64;
    {
      uint4* d = (uint4*)&xgt[srow][sq3*24];
      d[0]=xv0; d[1]=xv1; d[2]=xv2;
    }
    if (tile + nblk < NT){
      const long r1 = (long)(tile + nblk)*64;
      long gr = r1 + srow;
      xv0=(uint4){0,0,0,0}; xv1=xv0; xv2=xv0;
      if (gr < NN){
        const uint4* src = (const uint4*)(wsb + H0B + ((long)b*NN + gr)*256 + 64 + sq3*48);
        xv0=src[0]; xv1=src[1]; xv2=src[2];
      }
    }
    __syncthreads();
    f32x4 accd[2][2];
    #pragma unroll
    for (int s=0;s<2;s++)
      #pragma unroll
      for (int f=0;f<2;f++) accd[s][f] = (f32x4){0.f,0.f,0.f,0.f};
    #pragma unroll
    for (int ks=0;ks<3;ks++){
      short8_t a = *(const short8_t*)&xgt[w*16 + c][ks*32 + kg*8];
      #pragma unroll
      for (int f=0;f<2;f++){
        short8_t bw1 = *(const short8_t*)(w1bf + (f*16+c)*96 + ks*32 + kg*8);
        accd[0][f] = __builtin_amdgcn_mfma_f32_16x16x32_bf16(a, bw1, accd[0][f], 0,0,0);
        short8_t bw2 = *(const short8_t*)(w2bf + (f*16+c)*96 + ks*32 + kg*8);
        accd[1][f] = __builtin_amdgcn_mfma_f32_16x16x32_bf16(a, bw2, accd[1][f], 0,0,0);
      }
    }
    const float DSC = 0.42044820762685725f;   // 32^-0.25
    float dv[2][2][4];
    #pragma unroll
    for (int f=0;f<2;f++){
      float bb1 = b1[f*16+c], bb2 = b2[f*16+c];
      #pragma unroll
      for (int jj=0;jj<4;jj++){
        dv[0][f][jj] = (accd[0][f][jj] + bb1) * DSC;
        dv[1][f][jj] = (accd[1][f][jj] + bb2) * DSC;
      }
    }
    float dg[2][4];
    #pragma unroll
    for (int s=0;s<2;s++)
      #pragma unroll
      for (int jj=0;jj<4;jj++){
        float t = dv[s][0][jj]*dv[s][0][jj] + dv[s][1][jj]*dv[s][1][jj];
        #pragma unroll
        for (int off=1; off<16; off<<=1) t += __shfl_xor(t, off);
        dg[s][jj] = 0.5f * t;
      }
    #pragma unroll
    for (int s=0;s<2;s++)
      #pragma unroll
      for (int f=0;f<2;f++)
        #pragma unroll
        for (int jj=0;jj<4;jj++)
          dt[s][w*16 + kg*4 + jj][f*16 + c] = f2bf(dv[s][f][jj]);
    __syncthreads();
    f32x4 acc2[2][4];
    #pragma unroll
    for (int s=0;s<2;s++){
      short8_t ad = *(const short8_t*)&dt[s][w*16 + c][kg*8];
      #pragma unroll
      for (int f=0;f<4;f++){
        short8_t bp = *(const short8_t*)(pjbf + (f*16+c)*32 + kg*8);
        acc2[s][f] = __builtin_amdgcn_mfma_f32_16x16x32_bf16(ad, bp, (f32x4){0.f,0.f,0.f,0.f}, 0,0,0);
      }
    }
    float mx[2][4];
    #pragma unroll
    for (int s=0;s<2;s++)
      #pragma unroll
      for (int jj=0;jj<4;jj++){
        float t = fmaxf(fmaxf(acc2[s][0][jj],acc2[s][1][jj]),
                        fmaxf(acc2[s][2][jj],acc2[s][3][jj]));
        #pragma unroll
        for (int off=1; off<16; off<<=1) t = fmaxf(t, __shfl_xor(t, off));
        mx[s][jj] = t;
      }
    #pragma unroll
    for (int f=0;f<4;f++)
      #pragma unroll
      for (int jj=0;jj<4;jj++){
        float qv = 0.125f*(__expf(acc2[0][f][jj] - dg[0][jj] - mx[0][jj]) + 1e-6f);
        ot[w*16 + kg*4 + jj][f*16 + c] = f2bf(qv);
      }
    __syncthreads();
    {
      long gr = r0blk + srow;
      if (gr < NN){
        const uint4* s = (const uint4*)&ot[srow][sq3*16];
        uint4* dst = (uint4*)((unsigned short*)(wsb + QB) + ((long)b*NN + gr)*64 + sq3*16);
        dst[0] = s[0]; dst[1] = s[1];
      }
    }
    __syncthreads();
    float bmax = -3.0e38f;
    #pragma unroll
    for (int f=0;f<4;f++)
      #pragma unroll
      for (int jj=0;jj<4;jj++){
        float kv = __expf(acc2[1][f][jj] - mx[1][jj]);
        ot[w*16 + kg*4 + jj][f*16 + c] = f2bf(kv);
      }
    #pragma unroll
    for (int jj=0;jj<4;jj++){
      long gr = r0blk + w*16 + kg*4 + jj;
      bool val = (gr < NN);
      if (val && c==0)
        ((float*)(wsb + RMB))[(long)b*NN + gr] = mx[1][jj] - dg[1][jj];
      if (val) bmax = fmaxf(bmax, mx[1][jj]);
    }
    #pragma unroll
    for (int off=32; off>0; off>>=1) bmax = fmaxf(bmax, __shfl_xor(bmax, off));
    if (lane==0) wred[w] = bmax;
    __syncthreads();
    {
      long gr = r0blk + srow;
      if (gr < NN){
        const uint4* s = (const uint4*)&ot[srow][sq3*16];
        uint4* dst = (uint4*)((unsigned short*)(wsb + KKB) + ((long)b*NN + gr)*64 + sq3*16);
        dst[0] = s[0]; dst[1] = s[1];
      }
    }
    if (tid==0){
      float m2 = fmaxf(fmaxf(wred[0],wred[1]), fmaxf(wred[2],wred[3]));
      atomicMax((unsigned*)(wsb + GMB) + b, encOrd(m2));
    }
    __syncthreads();   // ot/wred WAR before next tile
  }
}

// ---------- fused GLU + k-finalize (+ksum) + MFMA reduce -------------------
// persistent tile-stride; gacc[16]; GLU weights staged in dynamic LDS
__global__ __launch_bounds__(256) void k_glured(
  char* __restrict__ wsb, const unsigned short* __restrict__ hsrc,
  const unsigned short* __restrict__ wbf,
  const float* __restrict__ bi, const float* __restrict__ bo,
  float* __restrict__ v2x_out, float* __restrict__ ksout)
{
  __shared__ unsigned short ht[64][132];       // 16896 B
  __shared__ unsigned short htT[128][72];      // 18432 B
  __shared__ unsigned short ktl[2][64][72];    // 2 x 9216 B
  __shared__ float red[256];
  extern __shared__ unsigned short wl[];       // dynamic: 65536 B, swizzled weights
  const int b = blockIdx.y;
  const int tid = threadIdx.x;
  const int lane = tid & 63;
  const int w = tid >> 6;
  const int c = lane & 15;
  const int kg = lane >> 4;
  const int nblk = gridDim.x;
  const float gm = decOrd(((const unsigned*)(wsb + GMB))[b]);
  const float* rm = (const float*)(wsb + RMB) + (long)b*NN;
  const uint4* kbase = (const uint4*)(wsb + KKB) + (long)b*NN*8;
  // stage weights once: wl[row][blk ^ (row&7)] = wbf[row][blk]   (16B blocks)
  {
    uint4* wl4 = (uint4*)wl;
    const uint4* src = (const uint4*)wbf;
    #pragma unroll
    for (int e=0;e<16;e++){
      int i = tid + 256*e;           // 4096 uint4 total
      int row = i >> 4, blk = i & 15;
      wl4[row*16 + (blk ^ (row & 7))] = src[i];
    }
  }
  f32x4 racc[8];
  #pragma unroll
  for (int f=0;f<8;f++) racc[f] = (f32x4){0.f,0.f,0.f,0.f};
  float ksacc = 0.f;
  float bi_l[8], bo_l[8];
  #pragma unroll
  for (int f=0;f<8;f++){ bi_l[f] = bi[f*16+c]; bo_l[f] = bo[f*16+c]; }
  const int krr = tid>>3, kcc = tid&7;
  const int srow = tid>>2, sq3 = tid&3;
  const int rswz = ((w*16 + c) >> 3) & 7;
  const int wswz = c & 7;                      // weight-read swizzle (row&7 = c&7)
  uint4 hv0,hv1,hv2,hv3, krA,krB; float rmA,rmB;
  {
    const long r0 = (long)blockIdx.x*64;
    long gr = r0 + srow;
    hv0=(uint4){0,0,0,0}; hv1=hv0; hv2=hv0; hv3=hv0;
    if (gr < NN){
      const uint4* s = (const uint4*)(hsrc + ((long)b*NN + gr)*128 + sq3*32);
      hv0=s[0]; hv1=s[1]; hv2=s[2]; hv3=s[3];
    }
    krA=(uint4){0,0,0,0}; krB=krA; rmA=0.f; rmB=0.f;
    long gA = r0 + krr;      if (gA < NN){ krA = kbase[gA*8 + kcc]; rmA = rm[gA]; }
    long gB = r0 + krr + 32; if (gB < NN){ krB = kbase[gB*8 + kcc]; rmB = rm[gB]; }
  }
  int p = 0;
  #pragma unroll 1
  for (int tile = blockIdx.x; tile < NT; tile += nblk){
    const long r0 = (long)tile*64;
    // Phase A: write ht + ktl[p] from prefetched regs; issue next prefetch
    {
      uint4* d = (uint4*)&ht[srow][sq3*32];
      d[0]=hv0; d[1]=hv1; d[2]=hv2; d[3]=hv3;
    }
    {
      bool vA = (r0 + krr) < NN;
      bool vB = (r0 + krr + 32) < NN;
      float sA = __expf(rmA - gm), sB = __expf(rmB - gm);
      float ta[8], tb[8];
      up8(krA, ta); up8(krB, tb);
      #pragma unroll
      for (int i=0;i<8;i++){
        ta[i] = vA ? 0.125f*(ta[i]*sA + 1e-6f) : 0.f;
        tb[i] = vB ? 0.125f*(tb[i]*sB + 1e-6f) : 0.f;
      }
      const int pA = (((krr>>3) ^ kcc) << 3) | (krr & 7);
      const int pB = ((((krr>>3)+4) ^ kcc) << 3) | (krr & 7);
      #pragma unroll
      for (int i=0;i<8;i++){
        ktl[p][kcc*8+i][pA] = f2bf(ta[i]);
        ktl[p][kcc*8+i][pB] = f2bf(tb[i]);
      }
    }
    if (tile + nblk < NT){
      const long r1 = (long)(tile + nblk)*64;
      long gr = r1 + srow;
      hv0=(uint4){0,0,0,0}; hv1=hv0; hv2=hv0; hv3=hv0;
      if (gr < NN){
        const uint4* s = (const uint4*)(hsrc + ((long)b*NN + gr)*128 + sq3*32);
        hv0=s[0]; hv1=s[1]; hv2=s[2]; hv3=s[3];
      }
      krA=(uint4){0,0,0,0}; krB=krA; rmA=0.f; rmB=0.f;
      long gA = r1 + krr;      if (gA < NN){ krA = kbase[gA*8 + kcc]; rmA = rm[gA]; }
      long gB = r1 + krr + 32; if (gB < NN){ krB = kbase[gB*8 + kcc]; rmB = rm[gB]; }
    }
    __syncthreads();   // barrier A: ht/ktl[p] (and, on tile 0, wl) ready
    // Phase B: GLU MFMA (gacc[16], weights from LDS), write htT, ksum
    f32x4 gacc[16];
    #pragma unroll
    for (int f=0;f<16;f++) gacc[f] = (f32x4){0.f,0.f,0.f,0.f};
    #pragma unroll
    for (int ks=0;ks<4;ks++){
      short8_t a = *(const short8_t*)&ht[w*16 + c][ks*32 + kg*8];
      #pragma unroll
      for (int f=0;f<16;f++){
        short8_t bb = *(const short8_t*)(wl + (((f*16 + c)*16 + ((ks*4 + kg) ^ wswz)) << 3));
        gacc[f] = __builtin_amdgcn_mfma_f32_16x16x32_bf16(a, bb, gacc[f], 0, 0, 0);
      }
    }
    #pragma unroll
    for (int f=0;f<8;f++)
      #pragma unroll
      for (int j=0;j<4;j++){
        float aa = gacc[f][j]   + bi_l[f];
        float cc2= gacc[f+8][j] + bo_l[f];
        float o  = cc2 / (1.0f + __expf(-aa));
        bool val = (r0 + w*16 + kg*4 + j) < NN;
        htT[f*16 + c][w*16 + kg*4 + j] = val ? f2bf(o) : (unsigned short)0;
      }
    if (ksout){
      int m = tid & 63, n0 = (tid>>6)*16;
      int sm = (m>>3)&7;
      #pragma unroll
      for (int n=0;n<16;n++){
        int nn = n0+n;
        ksacc += bf2f(ktl[p][m][(((nn>>3)^sm)<<3)|(nn&7)]);
      }
    }
    __syncthreads();   // barrier B: htT ready
    // Phase C: reduce MFMA (reads ktl[p] + htT only)
    #pragma unroll
    for (int ks=0;ks<2;ks++){
      short8_t a = *(const short8_t*)&ktl[p][w*16 + c][((ks*4 + kg) ^ rswz) << 3];
      #pragma unroll
      for (int f=0;f<8;f++){
        short8_t bb = *(const short8_t*)&htT[f*16 + c][ks*32 + kg*8];
        racc[f] = __builtin_amdgcn_mfma_f32_16x16x32_bf16(a, bb, racc[f], 0, 0, 0);
      }
    }
    p ^= 1;
    // no barrier: next Phase A writes ht (unread in C) and ktl[p^1] (unread in C)
  }
  float* v2x = v2x_out + (long)b*8192;
  #pragma unroll
  for (int f=0;f<8;f++)
    #pragma unroll
    for (int j=0;j<4;j++)
      atomicAdd(&v2x[(w*16 + kg*4 + j)*128 + f*16 + c], racc[f][j]);
  if (ksout){
    red[tid] = ksacc;
    __syncthreads();
    if (tid < 64)
      atomicAdd(ksout + b*64 + tid,
                red[tid]+red[64+tid]+red[128+tid]+red[192+tid]);
  }
}

// ---------- v2t[b][n][m]: n<128: v2x[m][n]; n=128: ksum[m]; n>128: 0 -------
__global__ void k_v2cvt(char* __restrict__ wsb, const float* __restrict__ v2f){
  int idx = blockIdx.x*256 + threadIdx.x;          // 36864
  if (idx >= 36864) return;
  int b = idx / 9216, rem = idx % 9216;
  int n = rem / 64, m = rem % 64;
  const float* ks = (const float*)(wsb + KSB);
  float v = (n < 128) ? v2f[b*8192 + m*128 + n] : ((n==128) ? ks[b*64+m] : 0.f);
  ((unsigned short*)(wsb + V2TB))[b*9216 + n*64 + m] = f2bf(v);
}

// ---------- attn0 + residual(h0) + LN0 -> h1 (persistent) ------------------
__global__ __launch_bounds__(256) void k_attnln(
  char* __restrict__ wsb, const float* __restrict__ g0,
  const float* __restrict__ bt0)
{
  __shared__ unsigned short ht[64][132];    // 16896 B
  __shared__ unsigned short v2s[144*72];    // 20736 B (persistent across tiles)
  const int b = blockIdx.y;
  const int tid = threadIdx.x;
  const int lane = tid & 63;
  const int w  = tid >> 6;
  const int c  = lane & 15;
  const int kg = lane >> 4;
  const int nblk = gridDim.x;
  const int rrow = tid>>2, rq3 = tid&3;
  const unsigned short* qb = (const unsigned short*)(wsb + QB) + (long)b*NN*64;
  const unsigned short* h0g = (const unsigned short*)(wsb + H0B) + (long)b*NN*128;
  unsigned short* h1g = (unsigned short*)(wsb + H1B) + (long)b*NN*128;
  {
    const uint4* v2g = (const uint4*)((const unsigned short*)(wsb + V2TB) + b*9216);
    #pragma unroll
    for (int e=0;e<5;e++){
      int j = tid + 256*e;
      if (j < 1152){
        int row = j >> 3, cc = j & 7;
        *(uint4*)&v2s[row*72 + cc*8] = v2g[j];
      }
    }
  }
  short8_t aq0, aq1;
  uint4 rh0, rh1, rh2, rh3;
  {
    const long r0 = (long)blockIdx.x*64;
    if (r0 + w*16 + c < NN){
      const unsigned short* qrow = qb + (r0 + w*16 + c)*64 + kg*8;
      aq0 = *(const short8_t*)qrow; aq1 = *(const short8_t*)(qrow + 32);
    } else { aq0 = (short8_t){0,0,0,0,0,0,0,0}; aq1 = aq0; }
    rh0=(uint4){0,0,0,0}; rh1=rh0; rh2=rh0; rh3=rh0;
    if (r0 + rrow < NN){
      const uint4* hs = (const uint4*)(h0g + (r0 + rrow)*128 + rq3*32);
      rh0=hs[0]; rh1=hs[1]; rh2=hs[2]; rh3=hs[3];
    }
  }
  __syncthreads();   // v2s ready
  #pragma unroll 1
  for (int tile = blockIdx.x; tile < NT; tile += nblk){
    const long r0blk = (long)tile*64;
    const long rgr = r0blk + rrow;
    f32x4 acc[9];
    #pragma unroll
    for (int f=0;f<9;f++) acc[f] = (f32x4){0.f,0.f,0.f,0.f};
    #pragma unroll
    for (int f=0;f<9;f++){
      short8_t b0 = *(const short8_t*)&v2s[(f*16 + c)*72 + kg*8];
      acc[f] = __builtin_amdgcn_mfma_f32_16x16x32_bf16(aq0, b0, acc[f], 0, 0, 0);
      short8_t b1v = *(const short8_t*)&v2s[(f*16 + c)*72 + 32 + kg*8];
      acc[f] = __builtin_amdgcn_mfma_f32_16x16x32_bf16(aq1, b1v, acc[f], 0, 0, 0);
    }
    float inv[4];
    #pragma unroll
    for (int j=0;j<4;j++) inv[j] = 1.0f / __shfl(acc[8][j], (lane & 48));
    #pragma unroll
    for (int f=0;f<8;f++)
      #pragma unroll
      for (int j=0;j<4;j++)
        ht[w*16 + kg*4 + j][f*16 + c] = f2bf(acc[f][j]*inv[j]);
    __syncthreads();
    short8_t aq0n, aq1n;
    uint4 nh0, nh1, nh2, nh3;
    {
      aq0n = (short8_t){0,0,0,0,0,0,0,0}; aq1n = aq0n;
      nh0=(uint4){0,0,0,0}; nh1=nh0; nh2=nh0; nh3=nh0;
      if (tile + nblk < NT){
        const long r1 = (long)(tile + nblk)*64;
        if (r1 + w*16 + c < NN){
          const unsigned short* qrow = qb + (r1 + w*16 + c)*64 + kg*8;
          aq0n = *(const short8_t*)qrow; aq1n = *(const short8_t*)(qrow + 32);
        }
        if (r1 + rrow < NN){
          const uint4* hs = (const uint4*)(h0g + (r1 + rrow)*128 + rq3*32);
          nh0=hs[0]; nh1=hs[1]; nh2=hs[2]; nh3=hs[3];
        }
      }
    }
    {
      float tv[32];
      {
        const uint4* os = (const uint4*)&ht[rrow][rq3*32];
        uint4 o0=os[0],o1=os[1],o2=os[2],o3=os[3];
        up8(o0,tv); up8(o1,tv+8); up8(o2,tv+16); up8(o3,tv+24);
      }
      {
        float hv[32];
        up8(rh0,hv); up8(rh1,hv+8); up8(rh2,hv+16); up8(rh3,hv+24);
        #pragma unroll
        for (int i=0;i<32;i++) tv[i] += hv[i];
      }
      float s = 0.f;
      #pragma unroll
      for (int i=0;i<32;i++) s += tv[i];
      s += __shfl_xor(s, 1); s += __shfl_xor(s, 2);
      float mu = s * (1.0f/128.0f);
      float vv = 0.f;
      #pragma unroll
      for (int i=0;i<32;i++){ float e = tv[i]-mu; vv += e*e; }
      vv += __shfl_xor(vv, 1); vv += __shfl_xor(vv, 2);
      float rs = rsqrtf(vv * (1.0f/128.0f) + 1e-5f);
      const float4* gp = (const float4*)(g0 + rq3*32);
      const float4* bp = (const float4*)(bt0 + rq3*32);
      float h1v[32];
      #pragma unroll
      for (int i8=0;i8<8;i8++){
        float4 g4 = gp[i8], b4 = bp[i8];
        h1v[i8*4  ] = (tv[i8*4  ]-mu)*rs*g4.x + b4.x;
        h1v[i8*4+1] = (tv[i8*4+1]-mu)*rs*g4.y + b4.y;
        h1v[i8*4+2] = (tv[i8*4+2]-mu)*rs*g4.z + b4.z;
        h1v[i8*4+3] = (tv[i8*4+3]-mu)*rs*g4.w + b4.w;
      }
      if (rgr < NN){
        uint4 p0=pk8(h1v), p1=pk8(h1v+8), p2=pk8(h1v+16), p3=pk8(h1v+24);
        uint4* dst = (uint4*)(h1g + rgr*128 + rq3*32);
        dst[0]=p0; dst[1]=p1; dst[2]=p2; dst[3]=p3;
      }
    }
    __syncthreads();   // ht WAR for next tile
    aq0=aq0n; aq1=aq1n; rh0=nh0; rh1=nh1; rh2=nh2; rh3=nh3;
  }
}

// ---------- attn1 + residual(h1) + LN1 + MFMA head (persistent) ------------
__global__ __launch_bounds__(256) void k_attnhead(
  char* __restrict__ wsb, const float* __restrict__ g1,
  const float* __restrict__ bt1, const float* __restrict__ b_reg,
  float* __restrict__ out)
{
  __shared__ unsigned short ht[64][132];    // 16896 B
  __shared__ unsigned short v2s[144*72];    // 20736 B (persistent)
  __shared__ unsigned short h0t[64][136];   // 17408 B
  const int b = blockIdx.y;
  const int tid = threadIdx.x;
  const int lane = tid & 63;
  const int w  = tid >> 6;
  const int c  = lane & 15;
  const int kg = lane >> 4;
  const int nblk = gridDim.x;
  const int rrow = tid>>2, rq3 = tid&3;
  const unsigned short* qb  = (const unsigned short*)(wsb + QB) + (long)b*NN*64;
  const unsigned short* h0g = (const unsigned short*)(wsb + H0B) + (long)b*NN*128;
  const unsigned short* h1g = (const unsigned short*)(wsb + H1B) + (long)b*NN*128;
  {
    const uint4* v2g = (const uint4*)((const unsigned short*)(wsb + V2TB) + b*9216);
    #pragma unroll
    for (int e=0;e<5;e++){
      int j = tid + 256*e;
      if (j < 1152){
        int row = j >> 3, cc = j & 7;
        *(uint4*)&v2s[row*72 + cc*8] = v2g[j];
      }
    }
  }
  short8_t aq0, aq1;
  uint4 rh0, rh1, rh2, rh3, ah0, ah1, ah2, ah3;
  {
    const long r0 = (long)blockIdx.x*64;
    if (r0 + w*16 + c < NN){
      const unsigned short* qrow = qb + (r0 + w*16 + c)*64 + kg*8;
      aq0 = *(const short8_t*)qrow; aq1 = *(const short8_t*)(qrow + 32);
    } else { aq0 = (short8_t){0,0,0,0,0,0,0,0}; aq1 = aq0; }
    rh0=(uint4){0,0,0,0}; rh1=rh0; rh2=rh0; rh3=rh0;
    ah0=rh0; ah1=rh0; ah2=rh0; ah3=rh0;
    if (r0 + rrow < NN){
      const uint4* hs = (const uint4*)(h1g + (r0 + rrow)*128 + rq3*32);
      rh0=hs[0]; rh1=hs[1]; rh2=hs[2]; rh3=hs[3];
      const uint4* h0s = (const uint4*)(h0g + (r0 + rrow)*128 + rq3*32);
      ah0=h0s[0]; ah1=h0s[1]; ah2=h0s[2]; ah3=h0s[3];
    }
  }
  __syncthreads();   // v2s ready
  #pragma unroll 1
  for (int tile = blockIdx.x; tile < NT; tile += nblk){
    const long r0blk = (long)tile*64;
    const long r0w = r0blk + w*16;
    const long rgr = r0blk + rrow;
    f32x4 acc[9];
    #pragma unroll
    for (int f=0;f<9;f++) acc[f] = (f32x4){0.f,0.f,0.f,0.f};
    #pragma unroll
    for (int f=0;f<9;f++){
      short8_t b0 = *(const short8_t*)&v2s[(f*16 + c)*72 + kg*8];
      acc[f] = __builtin_amdgcn_mfma_f32_16x16x32_bf16(aq0, b0, acc[f], 0, 0, 0);
      short8_t b1v = *(const short8_t*)&v2s[(f*16 + c)*72 + 32 + kg*8];
      acc[f] = __builtin_amdgcn_mfma_f32_16x16x32_bf16(aq1, b1v, acc[f], 0, 0, 0);
    }
    float inv[4];
    #pragma unroll
    for (int j=0;j<4;j++) inv[j] = 1.0f / __shfl(acc[8][j], (lane & 48));
    #pragma unroll
    for (int f=0;f<8;f++)
      #pragma unroll
      for (int j=0;j<4;j++)
        ht[w*16 + kg*4 + j][f*16 + c] = f2bf(acc[f][j]*inv[j]);
    __syncthreads();
    short8_t aq0n, aq1n;
    uint4 nh0, nh1, nh2, nh3, na0, na1, na2, na3;
    {
      aq0n = (short8_t){0,0,0,0,0,0,0,0}; aq1n = aq0n;
      nh0=(uint4){0,0,0,0}; nh1=nh0; nh2=nh0; nh3=nh0;
      na0=nh0; na1=nh0; na2=nh0; na3=nh0;
      if (tile + nblk < NT){
        const long r1 = (long)(tile + nblk)*64;
        if (r1 + w*16 + c < NN){
          const unsigned short* qrow = qb + (r1 + w*16 + c)*64 + kg*8;
          aq0n = *(const short8_t*)qrow; aq1n = *(const short8_t*)(qrow + 32);
        }
        if (r1 + rrow < NN){
          const uint4* hs = (const uint4*)(h1g + (r1 + rrow)*128 + rq3*32);
          nh0=hs[0]; nh1=hs[1]; nh2=hs[2]; nh3=hs[3];
          const uint4* h0s = (const uint4*)(h0g + (r1 + rrow)*128 + rq3*32);
          na0=h0s[0]; na1=h0s[1]; na2=h0s[2]; na3=h0s[3];
        }
      }
    }
    {
      uint4* hd = (uint4*)&h0t[rrow][rq3*32];
      hd[0]=ah0; hd[1]=ah1; hd[2]=ah2; hd[3]=ah3;
      float tv[32];
      {
        const uint4* os = (const uint4*)&ht[rrow][rq3*32];
        uint4 o0=os[0],o1=os[1],o2=os[2],o3=os[3];
        up8(o0,tv); up8(o1,tv+8); up8(o2,tv+16); up8(o3,tv+24);
      }
      {
        float hv[32];
        up8(rh0,hv); up8(rh1,hv+8); up8(rh2,hv+16); up8(rh3,hv+24);
        #pragma unroll
        for (int i=0;i<32;i++) tv[i] += hv[i];
      }
      float s = 0.f;
      #pragma unroll
      for (int i=0;i<32;i++) s += tv[i];
      s += __shfl_xor(s, 1); s += __shfl_xor(s, 2);
      float mu = s * (1.0f/128.0f);
      float vv = 0.f;
      #pragma unroll
      for (int i=0;i<32;i++){ float e = tv[i]-mu; vv += e*e; }
      vv += __shfl_xor(vv, 1); vv += __shfl_xor(vv, 2);
      float rs = rsqrtf(vv * (1.0f/128.0f) + 1e-5f);
      const float4* gp = (const float4*)(g1 + rq3*32);
      const float4* bp = (const float4*)(bt1 + rq3*32);
      float h2v[32];
      #pragma unroll
      for (int i8=0;i8<8;i8++){
        float4 g4 = gp[i8], b4 = bp[i8];
        h2v[i8*4  ] = fmaxf((tv[i8*4  ]-mu)*rs*g4.x + b4.x, 0.f);
        h2v[i8*4+1] = fmaxf((tv[i8*4+1]-mu)*rs*g4.y + b4.y, 0.f);
        h2v[i8*4+2] = fmaxf((tv[i8*4+2]-mu)*rs*g4.z + b4.z, 0.f);
        h2v[i8*4+3] = fmaxf((tv[i8*4+3]-mu)*rs*g4.w + b4.w, 0.f);
      }
      uint4 p0=pk8(h2v), p1=pk8(h2v+8), p2=pk8(h2v+16), p3=pk8(h2v+24);
      uint4* d = (uint4*)&ht[rrow][rq3*32];
      d[0]=p0; d[1]=p1; d[2]=p2; d[3]=p3;
    }
    __syncthreads();
    const unsigned short* wregT = (const unsigned short*)(wsb + W12B) + 8192;
    f32x4 hacc = (f32x4){0.f,0.f,0.f,0.f};
    #pragma unroll
    for (int ks=0;ks<8;ks++){
      short8_t a;
      if (ks < 4)
        a = relu8(*(const short8_t*)&h0t[w*16 + c][ks*32 + kg*8]);
      else
        a = *(const short8_t*)&ht[w*16 + c][(ks-4)*32 + kg*8];
      short8_t bb = *(const short8_t*)(wregT + c*256 + ks*32 + kg*8);
      hacc = __builtin_amdgcn_mfma_f32_16x16x32_bf16(a, bb, hacc, 0, 0, 0);
    }
    if (c < 12){
      float br = b_reg[c];
      #pragma unroll
      for (int j=0;j<4;j++){
        long gr = r0w + kg*4 + j;
        if (gr < NN)
          out[((long)b*12 + c)*NN + gr] = hacc[j] + br;
      }
    }
    __syncthreads();   // ht/h0t WAR for next tile
    aq0=aq0n; aq1=aq1n;
    rh0=nh0; rh1=nh1; rh2=nh2; rh3=nh3;
    ah0=na0; ah1=na1; ah2=na2; ah3=na3;
  }
}

extern "C" void kernel_launch(void* const* d_in, const int* in_sizes, int n_in,
                              void* d_out, int out_size, void* d_ws, size_t ws_size,
                              hipStream_t stream)
{
  const float* x        = (const float*)d_in[0];
  const float* node_emb = (const float*)d_in[1];
  const float* time_emb = (const float*)d_in[2];
  const float* week_emb = (const float*)d_in[3];
  const float* W_in     = (const float*)d_in[4];
  const float* b_in     = (const float*)d_in[5];
  const float* W1       = (const float*)d_in[6];
  const float* b1       = (const float*)d_in[7];
  const float* W2       = (const float*)d_in[8];
  const float* b2       = (const float*)d_in[9];
  const float* W_reg    = (const float*)d_in[10];
  const float* b_reg    = (const float*)d_in[11];
  const float* proj     = (const float*)d_in[12];
  const float* fc_in0_w = (const float*)d_in[13];
  const float* fc_in0_b = (const float*)d_in[14];
  const float* fc_out0_w= (const float*)d_in[15];
  const float* fc_out0_b= (const float*)d_in[16];
  const float* ln0_g    = (const float*)d_in[17];
  const float* ln0_b    = (const float*)d_in[18];
  const float* fc_in1_w = (const float*)d_in[19];
  const float* fc_in1_b = (const float*)d_in[20];
  const float* fc_out1_w= (const float*)d_in[21];
  const float* fc_out1_b= (const float*)d_in[22];
  const float* ln1_g    = (const float*)d_in[23];
  const float* ln1_b    = (const float*)d_in[24];
  char* wsb  = (char*)d_ws;
  float* out = (float*)d_out;

  dim3 rowgrid((NN+255)/256, NB);     // (196, 4)
  dim3 pgrid(128, NB);                // persistent: 512 blocks, tile-stride
  dim3 cvtgrid(144);

  hipFuncSetAttribute((const void*)k_glured,
                      hipFuncAttributeMaxDynamicSharedMemorySize, 65536);

  k_init  <<<258, 256, 0, stream>>>(wsb);
  k_wcvt  <<<256, 256, 0, stream>>>(fc_in0_w, fc_out0_w, fc_in1_w, fc_out1_w, wsb);
  k_wcvt2 <<<48, 256, 0, stream>>>(W1, W2, proj, W_reg, wsb);
  k_pass1a<<<rowgrid, 256, 0, stream>>>(x, node_emb, time_emb, week_emb,
                                        W_in, b_in, wsb);
  k_pass1b<<<pgrid, 256, 0, stream>>>(b1, b2, wsb);
  k_glured<<<pgrid, 256, 65536, stream>>>(wsb, (const unsigned short*)(wsb + H0B),
                                          (const unsigned short*)(wsb + WBFB),
                                          fc_in0_b, fc_out0_b,
                                          (float*)(wsb + V2F0B), (float*)(wsb + KSB));
  k_v2cvt <<<cvtgrid, 256, 0, stream>>>(wsb, (const float*)(wsb + V2F0B));
  k_attnln<<<pgrid, 256, 0, stream>>>(wsb, ln0_g, ln0_b);
  k_glured<<<pgrid, 256, 65536, stream>>>(wsb, (const unsigned short*)(wsb + H1B),
                                          (const unsigned short*)(wsb + WBFB) + 32768,
                                          fc_in1_b, fc_out1_b,
                                          (float*)(wsb + V2F1B), (float*)nullptr);
  k_v2cvt <<<cvtgrid, 256, 0, stream>>>(wsb, (const float*)(wsb + V2F1B));
  k_attnhead<<<pgrid, 256, 0, stream>>>(wsb, ln1_g, ln1_b, b_reg, out);
}

// Round 22
// 363.645 us; speedup vs baseline: 1.2494x; 1.0153x over previous
//
#include <hip/hip_runtime.h>

#define NB 4
#define NN 50000
#define NT 784   // 64-row tiles per batch (784*64 = 50176 >= NN)

// ---- workspace byte offsets (total ~154.9 MB, < proven 205.9 MB) ----
#define H0B    0L
#define H1B    51200000L
#define QB     102400000L
#define KKB    128000000L    // k' (unfinalized, bf16)
#define RMB    153600000L    // fp32 rm [4*50000]
#define WBFB   154400000L    // bf16 GLU weights: layer0 [256][128], layer1 at +65536B
#define V2F0B  154531072L    // fp32 v2x layer0 [4][64][128]
#define V2F1B  154662144L    // fp32 v2x layer1
#define KSB    154793216L    // fp32 ksum [4][64]
#define GMB    154794240L    // 4 uints
#define W12B   154795264L    // bf16: W1 [32][96], W2 [32][96], proj [64][32], W_regT [16][256]
#define V2TB   154819840L    // bf16 v2x^T+ksum [4][144][64]
#define NZERO  65796         // words zeroed at V2F0B (v2x0+v2x1+ksum+gmax)

typedef short short8_t __attribute__((ext_vector_type(8)));
typedef float f32x4 __attribute__((ext_vector_type(4)));

__device__ __forceinline__ unsigned short f2bf(float f){
  unsigned u = __float_as_uint(f);
  return (unsigned short)((u + 0x7FFFu + ((u>>16)&1u)) >> 16);
}
__device__ __forceinline__ float bf2f(unsigned short s){
  return __uint_as_float(((unsigned)s)<<16);
}
__device__ __forceinline__ unsigned pk2(float a, float b){
  return (unsigned)f2bf(a) | ((unsigned)f2bf(b)<<16);
}
__device__ __forceinline__ uint4 pk8(const float* f){
  uint4 o; o.x=pk2(f[0],f[1]); o.y=pk2(f[2],f[3]);
  o.z=pk2(f[4],f[5]); o.w=pk2(f[6],f[7]); return o;
}
__device__ __forceinline__ void up8(uint4 v, float* f){
  f[0]=bf2f((unsigned short)(v.x&0xFFFFu)); f[1]=bf2f((unsigned short)(v.x>>16));
  f[2]=bf2f((unsigned short)(v.y&0xFFFFu)); f[3]=bf2f((unsigned short)(v.y>>16));
  f[4]=bf2f((unsigned short)(v.z&0xFFFFu)); f[5]=bf2f((unsigned short)(v.z>>16));
  f[6]=bf2f((unsigned short)(v.w&0xFFFFu)); f[7]=bf2f((unsigned short)(v.w>>16));
}
__device__ __forceinline__ short8_t relu8(short8_t s){
  short8_t r;
  #pragma unroll
  for (int i=0;i<8;i++){ short v = s[i]; r[i] = (v & (short)0x8000) ? (short)0 : v; }
  return r;
}
__device__ __forceinline__ unsigned encOrd(float f){
  unsigned u = __float_as_uint(f);
  return (u & 0x80000000u) ? ~u : (u | 0x80000000u);
}
__device__ __forceinline__ float decOrd(unsigned u){
  return (u & 0x80000000u) ? __uint_as_float(u & 0x7fffffffu)
                           : __uint_as_float(~u);
}

// ---- zero v2x0+v2x1+ksum+gmax ----
__global__ void k_init(char* __restrict__ wsb){
  int i = blockIdx.x*256 + threadIdx.x;
  if (i < NZERO) ((unsigned*)(wsb + V2F0B))[i] = 0u;
}
// ---- GLU weights -> bf16 [n][k] ----
__global__ void k_wcvt(const float* __restrict__ wi0, const float* __restrict__ wo0,
                       const float* __restrict__ wi1, const float* __restrict__ wo1,
                       char* __restrict__ wsb){
  int idx = blockIdx.x*256 + threadIdx.x;
  if (idx >= 65536) return;
  int l = idx >> 15, r = (idx >> 7) & 255, c = idx & 127;
  const float* src = (l==0) ? ((r<128)? wi0 : wo0) : ((r<128)? wi1 : wo1);
  float v = src[(r&127)*128 + c];
  ((unsigned short*)(wsb + WBFB))[l*32768 + r*128 + c] = f2bf(v);
}
// ---- W1,W2 [32][96], proj [64][32], W_regT [16][256] -> bf16 --------------
__global__ void k_wcvt2(const float* __restrict__ W1, const float* __restrict__ W2,
                        const float* __restrict__ proj, const float* __restrict__ W_reg,
                        char* __restrict__ wsb){
  int i = blockIdx.x*256 + threadIdx.x;          // 12288 total
  if (i >= 12288) return;
  unsigned short* dst = (unsigned short*)(wsb + W12B);
  float v;
  if (i < 3072) v = W1[i];
  else if (i < 6144) v = W2[i-3072];
  else if (i < 8192) v = proj[i-6144];
  else {
    int r = (i-8192) >> 8, c = (i-8192) & 255;
    v = (r < 12) ? W_reg[r*256 + c] : 0.f;
  }
  dst[i] = f2bf(v);
}

// ---------- pass1a: h0 (W_in matmul + embeddings) --------------------------
__global__ __launch_bounds__(256) void k_pass1a(
  const float* __restrict__ x, const float* __restrict__ node_emb,
  const float* __restrict__ time_emb, const float* __restrict__ week_emb,
  const float* __restrict__ W_in, const float* __restrict__ b_in,
  char* __restrict__ wsb)
{
  const int b = blockIdx.y;
  const int n = blockIdx.x*256 + threadIdx.x;
  if (n >= NN) return;
  const long row = (long)b*NN + n;
  float xr[36];
  {
    const float4* xp = (const float4*)(x + row*36);
    #pragma unroll
    for (int i=0;i<9;i++){ float4 t=xp[i]; xr[4*i]=t.x; xr[4*i+1]=t.y; xr[4*i+2]=t.z; xr[4*i+3]=t.w; }
  }
  int tidx = (int)(xr[34]*288.0f); tidx = tidx<0?0:(tidx>287?287:tidx);
  int widx = (int)(xr[35]);        widx = widx<0?0:(widx>6?6:widx);
  uint4* h0q = (uint4*)(wsb + H0B) + row*16;
  float hh[32];
  #pragma unroll 1
  for (int jj=0;jj<8;jj++){
    #pragma unroll
    for (int jl=0;jl<4;jl++){
      const int j = jj*4+jl;
      const float* w = W_in + j*36;
      float a0=0.f,a1=0.f,a2=0.f,a3=0.f;
      #pragma unroll
      for (int i=0;i<36;i+=4){ a0+=xr[i]*w[i]; a1+=xr[i+1]*w[i+1]; a2+=xr[i+2]*w[i+2]; a3+=xr[i+3]*w[i+3]; }
      hh[j] = b_in[j] + ((a0+a1)+(a2+a3));
    }
  }
  #pragma unroll
  for (int c=0;c<4;c++) h0q[c] = pk8(hh + 8*c);
  float xg[96];
  {
    const float4* p0 = (const float4*)(node_emb + (long)n*32);
    const float4* p1 = (const float4*)(time_emb + (long)tidx*32);
    const float4* p2 = (const float4*)(week_emb + (long)widx*32);
    #pragma unroll
    for (int i=0;i<8;i++){ float4 t=p0[i]; xg[4*i]=t.x; xg[4*i+1]=t.y; xg[4*i+2]=t.z; xg[4*i+3]=t.w; }
    #pragma unroll
    for (int i=0;i<8;i++){ float4 t=p1[i]; xg[32+4*i]=t.x; xg[32+4*i+1]=t.y; xg[32+4*i+2]=t.z; xg[32+4*i+3]=t.w; }
    #pragma unroll
    for (int i=0;i<8;i++){ float4 t=p2[i]; xg[64+4*i]=t.x; xg[64+4*i+1]=t.y; xg[64+4*i+2]=t.z; xg[64+4*i+3]=t.w; }
  }
  #pragma unroll
  for (int c=0;c<12;c++) h0q[4+c] = pk8(xg + 8*c);
}

// ---------- pass1b (MFMA, persistent): q, k', rm, global key max -----------
// W1/W2/proj staged in LDS (padded strides, 2-way reads)
__global__ __launch_bounds__(256) void k_pass1b(
  const float* __restrict__ b1, const float* __restrict__ b2,
  char* __restrict__ wsb)
{
  __shared__ unsigned short xgt[64][104];
  __shared__ unsigned short dt[2][64][40];
  __shared__ unsigned short ot[64][72];
  __shared__ unsigned short w1l[32][104];
  __shared__ unsigned short w2l[32][104];
  __shared__ unsigned short pjl[64][40];
  __shared__ float wred[4];
  const int b   = blockIdx.y;
  const int tid = threadIdx.x;
  const int lane= tid & 63;
  const int w   = tid >> 6;
  const int c   = lane & 15;
  const int kg  = lane >> 4;
  const int nblk = gridDim.x;
  const int srow = tid >> 2, sq3 = tid & 3;
  // stage weights once per block
  {
    const unsigned short* w1bf = (const unsigned short*)(wsb + W12B);
    const unsigned short* w2bf = w1bf + 3072;
    const unsigned short* pjbf = w1bf + 6144;
    for (int i = tid; i < 3072; i += 256){ w1l[i/96][i%96] = w1bf[i]; w2l[i/96][i%96] = w2bf[i]; }
    for (int i = tid; i < 2048; i += 256){ pjl[i/32][i%32] = pjbf[i]; }
  }
  uint4 xv0, xv1, xv2;
  {
    const long r0 = (long)blockIdx.x*64;
    long gr = r0 + srow;
    xv0=(uint4){0,0,0,0}; xv1=xv0; xv2=xv0;
    if (gr < NN){
      const uint4* src = (const uint4*)(wsb + H0B + ((long)b*NN + gr)*256 + 64 + sq3*48);
      xv0=src[0]; xv1=src[1]; xv2=src[2];
    }
  }
  #pragma unroll 1
  for (int tile = blockIdx.x; tile < NT; tile += nblk){
    const long r0blk = (long)tile*64;
    {
      uint4* d = (uint4*)&xgt[srow][sq3*24];
      d[0]=xv0; d[1]=xv1; d[2]=xv2;
    }
    if (tile + nblk < NT){
      const long r1 = (long)(tile + nblk)*64;
      long gr = r1 + srow;
      xv0=(uint4){0,0,0,0}; xv1=xv0; xv2=xv0;
      if (gr < NN){
        const uint4* src = (const uint4*)(wsb + H0B + ((long)b*NN + gr)*256 + 64 + sq3*48);
        xv0=src[0]; xv1=src[1]; xv2=src[2];
      }
    }
    __syncthreads();   // xgt (and on first tile: weights) ready
    f32x4 accd[2][2];
    #pragma unroll
    for (int s=0;s<2;s++)
      #pragma unroll
      for (int f=0;f<2;f++) accd[s][f] = (f32x4){0.f,0.f,0.f,0.f};
    #pragma unroll
    for (int ks=0;ks<3;ks++){
      short8_t a = *(const short8_t*)&xgt[w*16 + c][ks*32 + kg*8];
      #pragma unroll
      for (int f=0;f<2;f++){
        short8_t bw1 = *(const short8_t*)&w1l[f*16+c][ks*32 + kg*8];
        accd[0][f] = __builtin_amdgcn_mfma_f32_16x16x32_bf16(a, bw1, accd[0][f], 0,0,0);
        short8_t bw2 = *(const short8_t*)&w2l[f*16+c][ks*32 + kg*8];
        accd[1][f] = __builtin_amdgcn_mfma_f32_16x16x32_bf16(a, bw2, accd[1][f], 0,0,0);
      }
    }
    const float DSC = 0.42044820762685725f;   // 32^-0.25
    float dv[2][2][4];
    #pragma unroll
    for (int f=0;f<2;f++){
      float bb1 = b1[f*16+c], bb2 = b2[f*16+c];
      #pragma unroll
      for (int jj=0;jj<4;jj++){
        dv[0][f][jj] = (accd[0][f][jj] + bb1) * DSC;
        dv[1][f][jj] = (accd[1][f][jj] + bb2) * DSC;
      }
    }
    float dg[2][4];
    #pragma unroll
    for (int s=0;s<2;s++)
      #pragma unroll
      for (int jj=0;jj<4;jj++){
        float t = dv[s][0][jj]*dv[s][0][jj] + dv[s][1][jj]*dv[s][1][jj];
        #pragma unroll
        for (int off=1; off<16; off<<=1) t += __shfl_xor(t, off);
        dg[s][jj] = 0.5f * t;
      }
    #pragma unroll
    for (int s=0;s<2;s++)
      #pragma unroll
      for (int f=0;f<2;f++)
        #pragma unroll
        for (int jj=0;jj<4;jj++)
          dt[s][w*16 + kg*4 + jj][f*16 + c] = f2bf(dv[s][f][jj]);
    __syncthreads();
    f32x4 acc2[2][4];
    #pragma unroll
    for (int s=0;s<2;s++){
      short8_t ad = *(const short8_t*)&dt[s][w*16 + c][kg*8];
      #pragma unroll
      for (int f=0;f<4;f++){
        short8_t bp = *(const short8_t*)&pjl[f*16+c][kg*8];
        acc2[s][f] = __builtin_amdgcn_mfma_f32_16x16x32_bf16(ad, bp, (f32x4){0.f,0.f,0.f,0.f}, 0,0,0);
      }
    }
    float mx[2][4];
    #pragma unroll
    for (int s=0;s<2;s++)
      #pragma unroll
      for (int jj=0;jj<4;jj++){
        float t = fmaxf(fmaxf(acc2[s][0][jj],acc2[s][1][jj]),
                        fmaxf(acc2[s][2][jj],acc2[s][3][jj]));
        #pragma unroll
        for (int off=1; off<16; off<<=1) t = fmaxf(t, __shfl_xor(t, off));
        mx[s][jj] = t;
      }
    #pragma unroll
    for (int f=0;f<4;f++)
      #pragma unroll
      for (int jj=0;jj<4;jj++){
        float qv = 0.125f*(__expf(acc2[0][f][jj] - dg[0][jj] - mx[0][jj]) + 1e-6f);
        ot[w*16 + kg*4 + jj][f*16 + c] = f2bf(qv);
      }
    __syncthreads();
    {
      long gr = r0blk + srow;
      if (gr < NN){
        const uint4* s = (const uint4*)&ot[srow][sq3*16];
        uint4* dst = (uint4*)((unsigned short*)(wsb + QB) + ((long)b*NN + gr)*64 + sq3*16);
        dst[0] = s[0]; dst[1] = s[1];
      }
    }
    __syncthreads();
    float bmax = -3.0e38f;
    #pragma unroll
    for (int f=0;f<4;f++)
      #pragma unroll
      for (int jj=0;jj<4;jj++){
        float kv = __expf(acc2[1][f][jj] - mx[1][jj]);
        ot[w*16 + kg*4 + jj][f*16 + c] = f2bf(kv);
      }
    #pragma unroll
    for (int jj=0;jj<4;jj++){
      long gr = r0blk + w*16 + kg*4 + jj;
      bool val = (gr < NN);
      if (val && c==0)
        ((float*)(wsb + RMB))[(long)b*NN + gr] = mx[1][jj] - dg[1][jj];
      if (val) bmax = fmaxf(bmax, mx[1][jj]);
    }
    #pragma unroll
    for (int off=32; off>0; off>>=1) bmax = fmaxf(bmax, __shfl_xor(bmax, off));
    if (lane==0) wred[w] = bmax;
    __syncthreads();
    {
      long gr = r0blk + srow;
      if (gr < NN){
        const uint4* s = (const uint4*)&ot[srow][sq3*16];
        uint4* dst = (uint4*)((unsigned short*)(wsb + KKB) + ((long)b*NN + gr)*64 + sq3*16);
        dst[0] = s[0]; dst[1] = s[1];
      }
    }
    if (tid==0){
      float m2 = fmaxf(fmaxf(wred[0],wred[1]), fmaxf(wred[2],wred[3]));
      atomicMax((unsigned*)(wsb + GMB) + b, encOrd(m2));
    }
    __syncthreads();   // ot/wred WAR before next tile
  }
}

// ---------- fused GLU + k-finalize (+ksum) + MFMA reduce -------------------
// persistent tile-stride; gacc[16]; GLU weights staged in dynamic LDS
__global__ __launch_bounds__(256) void k_glured(
  char* __restrict__ wsb, const unsigned short* __restrict__ hsrc,
  const unsigned short* __restrict__ wbf,
  const float* __restrict__ bi, const float* __restrict__ bo,
  float* __restrict__ v2x_out, float* __restrict__ ksout)
{
  __shared__ unsigned short ht[64][132];       // 16896 B
  __shared__ unsigned short htT[128][72];      // 18432 B
  __shared__ unsigned short ktl[2][64][72];    // 2 x 9216 B
  __shared__ float red[256];
  extern __shared__ unsigned short wl[];       // dynamic: 65536 B, swizzled weights
  const int b = blockIdx.y;
  const int tid = threadIdx.x;
  const int lane = tid & 63;
  const int w = tid >> 6;
  const int c = lane & 15;
  const int kg = lane >> 4;
  const int nblk = gridDim.x;
  const float gm = decOrd(((const unsigned*)(wsb + GMB))[b]);
  const float* rm = (const float*)(wsb + RMB) + (long)b*NN;
  const uint4* kbase = (const uint4*)(wsb + KKB) + (long)b*NN*8;
  // stage weights once: wl[row][blk ^ (row&7)] = wbf[row][blk]   (16B blocks)
  {
    uint4* wl4 = (uint4*)wl;
    const uint4* src = (const uint4*)wbf;
    #pragma unroll
    for (int e=0;e<16;e++){
      int i = tid + 256*e;           // 4096 uint4 total
      int row = i >> 4, blk = i & 15;
      wl4[row*16 + (blk ^ (row & 7))] = src[i];
    }
  }
  f32x4 racc[8];
  #pragma unroll
  for (int f=0;f<8;f++) racc[f] = (f32x4){0.f,0.f,0.f,0.f};
  float ksacc = 0.f;
  float bi_l[8], bo_l[8];
  #pragma unroll
  for (int f=0;f<8;f++){ bi_l[f] = bi[f*16+c]; bo_l[f] = bo[f*16+c]; }
  const int krr = tid>>3, kcc = tid&7;
  const int srow = tid>>2, sq3 = tid&3;
  const int rswz = ((w*16 + c) >> 3) & 7;
  const int wswz = c & 7;                      // weight-read swizzle (row&7 = c&7)
  uint4 hv0,hv1,hv2,hv3, krA,krB; float rmA,rmB;
  {
    const long r0 = (long)blockIdx.x*64;
    long gr = r0 + srow;
    hv0=(uint4){0,0,0,0}; hv1=hv0; hv2=hv0; hv3=hv0;
    if (gr < NN){
      const uint4* s = (const uint4*)(hsrc + ((long)b*NN + gr)*128 + sq3*32);
      hv0=s[0]; hv1=s[1]; hv2=s[2]; hv3=s[3];
    }
    krA=(uint4){0,0,0,0}; krB=krA; rmA=0.f; rmB=0.f;
    long gA = r0 + krr;      if (gA < NN){ krA = kbase[gA*8 + kcc]; rmA = rm[gA]; }
    long gB = r0 + krr + 32; if (gB < NN){ krB = kbase[gB*8 + kcc]; rmB = rm[gB]; }
  }
  int p = 0;
  #pragma unroll 1
  for (int tile = blockIdx.x; tile < NT; tile += nblk){
    const long r0 = (long)tile*64;
    // Phase A: write ht + ktl[p] from prefetched regs; issue next prefetch
    {
      uint4* d = (uint4*)&ht[srow][sq3*32];
      d[0]=hv0; d[1]=hv1; d[2]=hv2; d[3]=hv3;
    }
    {
      bool vA = (r0 + krr) < NN;
      bool vB = (r0 + krr + 32) < NN;
      float sA = __expf(rmA - gm), sB = __expf(rmB - gm);
      float ta[8], tb[8];
      up8(krA, ta); up8(krB, tb);
      #pragma unroll
      for (int i=0;i<8;i++){
        ta[i] = vA ? 0.125f*(ta[i]*sA + 1e-6f) : 0.f;
        tb[i] = vB ? 0.125f*(tb[i]*sB + 1e-6f) : 0.f;
      }
      const int pA = (((krr>>3) ^ kcc) << 3) | (krr & 7);
      const int pB = ((((krr>>3)+4) ^ kcc) << 3) | (krr & 7);
      #pragma unroll
      for (int i=0;i<8;i++){
        ktl[p][kcc*8+i][pA] = f2bf(ta[i]);
        ktl[p][kcc*8+i][pB] = f2bf(tb[i]);
      }
    }
    if (tile + nblk < NT){
      const long r1 = (long)(tile + nblk)*64;
      long gr = r1 + srow;
      hv0=(uint4){0,0,0,0}; hv1=hv0; hv2=hv0; hv3=hv0;
      if (gr < NN){
        const uint4* s = (const uint4*)(hsrc + ((long)b*NN + gr)*128 + sq3*32);
        hv0=s[0]; hv1=s[1]; hv2=s[2]; hv3=s[3];
      }
      krA=(uint4){0,0,0,0}; krB=krA; rmA=0.f; rmB=0.f;
      long gA = r1 + krr;      if (gA < NN){ krA = kbase[gA*8 + kcc]; rmA = rm[gA]; }
      long gB = r1 + krr + 32; if (gB < NN){ krB = kbase[gB*8 + kcc]; rmB = rm[gB]; }
    }
    __syncthreads();   // barrier A: ht/ktl[p] (and, on tile 0, wl) ready
    // Phase B: GLU MFMA (gacc[16], weights from LDS), write htT, ksum
    f32x4 gacc[16];
    #pragma unroll
    for (int f=0;f<16;f++) gacc[f] = (f32x4){0.f,0.f,0.f,0.f};
    #pragma unroll
    for (int ks=0;ks<4;ks++){
      short8_t a = *(const short8_t*)&ht[w*16 + c][ks*32 + kg*8];
      #pragma unroll
      for (int f=0;f<16;f++){
        short8_t bb = *(const short8_t*)(wl + (((f*16 + c)*16 + ((ks*4 + kg) ^ wswz)) << 3));
        gacc[f] = __builtin_amdgcn_mfma_f32_16x16x32_bf16(a, bb, gacc[f], 0, 0, 0);
      }
    }
    #pragma unroll
    for (int f=0;f<8;f++)
      #pragma unroll
      for (int j=0;j<4;j++){
        float aa = gacc[f][j]   + bi_l[f];
        float cc2= gacc[f+8][j] + bo_l[f];
        float o  = cc2 / (1.0f + __expf(-aa));
        bool val = (r0 + w*16 + kg*4 + j) < NN;
        htT[f*16 + c][w*16 + kg*4 + j] = val ? f2bf(o) : (unsigned short)0;
      }
    if (ksout){
      int m = tid & 63, n0 = (tid>>6)*16;
      int sm = (m>>3)&7;
      #pragma unroll
      for (int n=0;n<16;n++){
        int nn = n0+n;
        ksacc += bf2f(ktl[p][m][(((nn>>3)^sm)<<3)|(nn&7)]);
      }
    }
    __syncthreads();   // barrier B: htT ready
    // Phase C: reduce MFMA (reads ktl[p] + htT only)
    #pragma unroll
    for (int ks=0;ks<2;ks++){
      short8_t a = *(const short8_t*)&ktl[p][w*16 + c][((ks*4 + kg) ^ rswz) << 3];
      #pragma unroll
      for (int f=0;f<8;f++){
        short8_t bb = *(const short8_t*)&htT[f*16 + c][ks*32 + kg*8];
        racc[f] = __builtin_amdgcn_mfma_f32_16x16x32_bf16(a, bb, racc[f], 0, 0, 0);
      }
    }
    p ^= 1;
    // no barrier: next Phase A writes ht (unread in C) and ktl[p^1] (unread in C)
  }
  float* v2x = v2x_out + (long)b*8192;
  #pragma unroll
  for (int f=0;f<8;f++)
    #pragma unroll
    for (int j=0;j<4;j++)
      atomicAdd(&v2x[(w*16 + kg*4 + j)*128 + f*16 + c], racc[f][j]);
  if (ksout){
    red[tid] = ksacc;
    __syncthreads();
    if (tid < 64)
      atomicAdd(ksout + b*64 + tid,
                red[tid]+red[64+tid]+red[128+tid]+red[192+tid]);
  }
}

// ---------- v2t[b][n][m]: n<128: v2x[m][n]; n=128: ksum[m]; n>128: 0 -------
__global__ void k_v2cvt(char* __restrict__ wsb, const float* __restrict__ v2f){
  int idx = blockIdx.x*256 + threadIdx.x;          // 36864
  if (idx >= 36864) return;
  int b = idx / 9216, rem = idx % 9216;
  int n = rem / 64, m = rem % 64;
  const float* ks = (const float*)(wsb + KSB);
  float v = (n < 128) ? v2f[b*8192 + m*128 + n] : ((n==128) ? ks[b*64+m] : 0.f);
  ((unsigned short*)(wsb + V2TB))[b*9216 + n*64 + m] = f2bf(v);
}

// ---------- attn0 + residual(h0) + LN0 -> h1 (persistent) ------------------
__global__ __launch_bounds__(256) void k_attnln(
  char* __restrict__ wsb, const float* __restrict__ g0,
  const float* __restrict__ bt0)
{
  __shared__ unsigned short ht[64][132];    // 16896 B
  __shared__ unsigned short v2s[144*72];    // 20736 B (persistent across tiles)
  const int b = blockIdx.y;
  const int tid = threadIdx.x;
  const int lane = tid & 63;
  const int w  = tid >> 6;
  const int c  = lane & 15;
  const int kg = lane >> 4;
  const int nblk = gridDim.x;
  const int rrow = tid>>2, rq3 = tid&3;
  const unsigned short* qb = (const unsigned short*)(wsb + QB) + (long)b*NN*64;
  const unsigned short* h0g = (const unsigned short*)(wsb + H0B) + (long)b*NN*128;
  unsigned short* h1g = (unsigned short*)(wsb + H1B) + (long)b*NN*128;
  {
    const uint4* v2g = (const uint4*)((const unsigned short*)(wsb + V2TB) + b*9216);
    #pragma unroll
    for (int e=0;e<5;e++){
      int j = tid + 256*e;
      if (j < 1152){
        int row = j >> 3, cc = j & 7;
        *(uint4*)&v2s[row*72 + cc*8] = v2g[j];
      }
    }
  }
  short8_t aq0, aq1;
  uint4 rh0, rh1, rh2, rh3;
  {
    const long r0 = (long)blockIdx.x*64;
    if (r0 + w*16 + c < NN){
      const unsigned short* qrow = qb + (r0 + w*16 + c)*64 + kg*8;
      aq0 = *(const short8_t*)qrow; aq1 = *(const short8_t*)(qrow + 32);
    } else { aq0 = (short8_t){0,0,0,0,0,0,0,0}; aq1 = aq0; }
    rh0=(uint4){0,0,0,0}; rh1=rh0; rh2=rh0; rh3=rh0;
    if (r0 + rrow < NN){
      const uint4* hs = (const uint4*)(h0g + (r0 + rrow)*128 + rq3*32);
      rh0=hs[0]; rh1=hs[1]; rh2=hs[2]; rh3=hs[3];
    }
  }
  __syncthreads();   // v2s ready
  #pragma unroll 1
  for (int tile = blockIdx.x; tile < NT; tile += nblk){
    const long r0blk = (long)tile*64;
    const long rgr = r0blk + rrow;
    f32x4 acc[9];
    #pragma unroll
    for (int f=0;f<9;f++) acc[f] = (f32x4){0.f,0.f,0.f,0.f};
    #pragma unroll
    for (int f=0;f<9;f++){
      short8_t b0 = *(const short8_t*)&v2s[(f*16 + c)*72 + kg*8];
      acc[f] = __builtin_amdgcn_mfma_f32_16x16x32_bf16(aq0, b0, acc[f], 0, 0, 0);
      short8_t b1v = *(const short8_t*)&v2s[(f*16 + c)*72 + 32 + kg*8];
      acc[f] = __builtin_amdgcn_mfma_f32_16x16x32_bf16(aq1, b1v, acc[f], 0, 0, 0);
    }
    float inv[4];
    #pragma unroll
    for (int j=0;j<4;j++) inv[j] = 1.0f / __shfl(acc[8][j], (lane & 48));
    #pragma unroll
    for (int f=0;f<8;f++)
      #pragma unroll
      for (int j=0;j<4;j++)
        ht[w*16 + kg*4 + j][f*16 + c] = f2bf(acc[f][j]*inv[j]);
    __syncthreads();
    short8_t aq0n, aq1n;
    uint4 nh0, nh1, nh2, nh3;
    {
      aq0n = (short8_t){0,0,0,0,0,0,0,0}; aq1n = aq0n;
      nh0=(uint4){0,0,0,0}; nh1=nh0; nh2=nh0; nh3=nh0;
      if (tile + nblk < NT){
        const long r1 = (long)(tile + nblk)*64;
        if (r1 + w*16 + c < NN){
          const unsigned short* qrow = qb + (r1 + w*16 + c)*64 + kg*8;
          aq0n = *(const short8_t*)qrow; aq1n = *(const short8_t*)(qrow + 32);
        }
        if (r1 + rrow < NN){
          const uint4* hs = (const uint4*)(h0g + (r1 + rrow)*128 + rq3*32);
          nh0=hs[0]; nh1=hs[1]; nh2=hs[2]; nh3=hs[3];
        }
      }
    }
    {
      float tv[32];
      {
        const uint4* os = (const uint4*)&ht[rrow][rq3*32];
        uint4 o0=os[0],o1=os[1],o2=os[2],o3=os[3];
        up8(o0,tv); up8(o1,tv+8); up8(o2,tv+16); up8(o3,tv+24);
      }
      {
        float hv[32];
        up8(rh0,hv); up8(rh1,hv+8); up8(rh2,hv+16); up8(rh3,hv+24);
        #pragma unroll
        for (int i=0;i<32;i++) tv[i] += hv[i];
      }
      float s = 0.f;
      #pragma unroll
      for (int i=0;i<32;i++) s += tv[i];
      s += __shfl_xor(s, 1); s += __shfl_xor(s, 2);
      float mu = s * (1.0f/128.0f);
      float vv = 0.f;
      #pragma unroll
      for (int i=0;i<32;i++){ float e = tv[i]-mu; vv += e*e; }
      vv += __shfl_xor(vv, 1); vv += __shfl_xor(vv, 2);
      float rs = rsqrtf(vv * (1.0f/128.0f) + 1e-5f);
      const float4* gp = (const float4*)(g0 + rq3*32);
      const float4* bp = (const float4*)(bt0 + rq3*32);
      float h1v[32];
      #pragma unroll
      for (int i8=0;i8<8;i8++){
        float4 g4 = gp[i8], b4 = bp[i8];
        h1v[i8*4  ] = (tv[i8*4  ]-mu)*rs*g4.x + b4.x;
        h1v[i8*4+1] = (tv[i8*4+1]-mu)*rs*g4.y + b4.y;
        h1v[i8*4+2] = (tv[i8*4+2]-mu)*rs*g4.z + b4.z;
        h1v[i8*4+3] = (tv[i8*4+3]-mu)*rs*g4.w + b4.w;
      }
      if (rgr < NN){
        uint4 p0=pk8(h1v), p1=pk8(h1v+8), p2=pk8(h1v+16), p3=pk8(h1v+24);
        uint4* dst = (uint4*)(h1g + rgr*128 + rq3*32);
        dst[0]=p0; dst[1]=p1; dst[2]=p2; dst[3]=p3;
      }
    }
    __syncthreads();   // ht WAR for next tile
    aq0=aq0n; aq1=aq1n; rh0=nh0; rh1=nh1; rh2=nh2; rh3=nh3;
  }
}

// ---------- attn1 + residual(h1) + LN1 + MFMA head (persistent) ------------
// W_regT staged in LDS with padded stride (was a 16-way global pattern)
__global__ __launch_bounds__(256) void k_attnhead(
  char* __restrict__ wsb, const float* __restrict__ g1,
  const float* __restrict__ bt1, const float* __restrict__ b_reg,
  float* __restrict__ out)
{
  __shared__ unsigned short ht[64][132];    // 16896 B
  __shared__ unsigned short v2s[144*72];    // 20736 B (persistent)
  __shared__ unsigned short h0t[64][136];   // 17408 B
  __shared__ unsigned short wrl[16][264];   // 8448 B  (total 63488 B)
  const int b = blockIdx.y;
  const int tid = threadIdx.x;
  const int lane = tid & 63;
  const int w  = tid >> 6;
  const int c  = lane & 15;
  const int kg = lane >> 4;
  const int nblk = gridDim.x;
  const int rrow = tid>>2, rq3 = tid&3;
  const unsigned short* qb  = (const unsigned short*)(wsb + QB) + (long)b*NN*64;
  const unsigned short* h0g = (const unsigned short*)(wsb + H0B) + (long)b*NN*128;
  const unsigned short* h1g = (const unsigned short*)(wsb + H1B) + (long)b*NN*128;
  {
    const uint4* v2g = (const uint4*)((const unsigned short*)(wsb + V2TB) + b*9216);
    #pragma unroll
    for (int e=0;e<5;e++){
      int j = tid + 256*e;
      if (j < 1152){
        int row = j >> 3, cc = j & 7;
        *(uint4*)&v2s[row*72 + cc*8] = v2g[j];
      }
    }
    const unsigned short* wregT = (const unsigned short*)(wsb + W12B) + 8192;
    for (int i = tid; i < 4096; i += 256)
      wrl[i>>8][i&255] = wregT[i];
  }
  short8_t aq0, aq1;
  uint4 rh0, rh1, rh2, rh3, ah0, ah1, ah2, ah3;
  {
    const long r0 = (long)blockIdx.x*64;
    if (r0 + w*16 + c < NN){
      const unsigned short* qrow = qb + (r0 + w*16 + c)*64 + kg*8;
      aq0 = *(const short8_t*)qrow; aq1 = *(const short8_t*)(qrow + 32);
    } else { aq0 = (short8_t){0,0,0,0,0,0,0,0}; aq1 = aq0; }
    rh0=(uint4){0,0,0,0}; rh1=rh0; rh2=rh0; rh3=rh0;
    ah0=rh0; ah1=rh0; ah2=rh0; ah3=rh0;
    if (r0 + rrow < NN){
      const uint4* hs = (const uint4*)(h1g + (r0 + rrow)*128 + rq3*32);
      rh0=hs[0]; rh1=hs[1]; rh2=hs[2]; rh3=hs[3];
      const uint4* h0s = (const uint4*)(h0g + (r0 + rrow)*128 + rq3*32);
      ah0=h0s[0]; ah1=h0s[1]; ah2=h0s[2]; ah3=h0s[3];
    }
  }
  __syncthreads();   // v2s + wrl ready
  #pragma unroll 1
  for (int tile = blockIdx.x; tile < NT; tile += nblk){
    const long r0blk = (long)tile*64;
    const long r0w = r0blk + w*16;
    const long rgr = r0blk + rrow;
    f32x4 acc[9];
    #pragma unroll
    for (int f=0;f<9;f++) acc[f] = (f32x4){0.f,0.f,0.f,0.f};
    #pragma unroll
    for (int f=0;f<9;f++){
      short8_t b0 = *(const short8_t*)&v2s[(f*16 + c)*72 + kg*8];
      acc[f] = __builtin_amdgcn_mfma_f32_16x16x32_bf16(aq0, b0, acc[f], 0, 0, 0);
      short8_t b1v = *(const short8_t*)&v2s[(f*16 + c)*72 + 32 + kg*8];
      acc[f] = __builtin_amdgcn_mfma_f32_16x16x32_bf16(aq1, b1v, acc[f], 0, 0, 0);
    }
    float inv[4];
    #pragma unroll
    for (int j=0;j<4;j++) inv[j] = 1.0f / __shfl(acc[8][j], (lane & 48));
    #pragma unroll
    for (int f=0;f<8;f++)
      #pragma unroll
      for (int j=0;j<4;j++)
        ht[w*16 + kg*4 + j][f*16 + c] = f2bf(acc[f][j]*inv[j]);
    __syncthreads();
    short8_t aq0n, aq1n;
    uint4 nh0, nh1, nh2, nh3, na0, na1, na2, na3;
    {
      aq0n = (short8_t){0,0,0,0,0,0,0,0}; aq1n = aq0n;
      nh0=(uint4){0,0,0,0}; nh1=nh0; nh2=nh0; nh3=nh0;
      na0=nh0; na1=nh0; na2=nh0; na3=nh0;
      if (tile + nblk < NT){
        const long r1 = (long)(tile + nblk)*64;
        if (r1 + w*16 + c < NN){
          const unsigned short* qrow = qb + (r1 + w*16 + c)*64 + kg*8;
          aq0n = *(const short8_t*)qrow; aq1n = *(const short8_t*)(qrow + 32);
        }
        if (r1 + rrow < NN){
          const uint4* hs = (const uint4*)(h1g + (r1 + rrow)*128 + rq3*32);
          nh0=hs[0]; nh1=hs[1]; nh2=hs[2]; nh3=hs[3];
          const uint4* h0s = (const uint4*)(h0g + (r1 + rrow)*128 + rq3*32);
          na0=h0s[0]; na1=h0s[1]; na2=h0s[2]; na3=h0s[3];
        }
      }
    }
    {
      uint4* hd = (uint4*)&h0t[rrow][rq3*32];
      hd[0]=ah0; hd[1]=ah1; hd[2]=ah2; hd[3]=ah3;
      float tv[32];
      {
        const uint4* os = (const uint4*)&ht[rrow][rq3*32];
        uint4 o0=os[0],o1=os[1],o2=os[2],o3=os[3];
        up8(o0,tv); up8(o1,tv+8); up8(o2,tv+16); up8(o3,tv+24);
      }
      {
        float hv[32];
        up8(rh0,hv); up8(rh1,hv+8); up8(rh2,hv+16); up8(rh3,hv+24);
        #pragma unroll
        for (int i=0;i<32;i++) tv[i] += hv[i];
      }
      float s = 0.f;
      #pragma unroll
      for (int i=0;i<32;i++) s += tv[i];
      s += __shfl_xor(s, 1); s += __shfl_xor(s, 2);
      float mu = s * (1.0f/128.0f);
      float vv = 0.f;
      #pragma unroll
      for (int i=0;i<32;i++){ float e = tv[i]-mu; vv += e*e; }
      vv += __shfl_xor(vv, 1); vv += __shfl_xor(vv, 2);
      float rs = rsqrtf(vv * (1.0f/128.0f) + 1e-5f);
      const float4* gp = (const float4*)(g1 + rq3*32);
      const float4* bp = (const float4*)(bt1 + rq3*32);
      float h2v[32];
      #pragma unroll
      for (int i8=0;i8<8;i8++){
        float4 g4 = gp[i8], b4 = bp[i8];
        h2v[i8*4  ] = fmaxf((tv[i8*4  ]-mu)*rs*g4.x + b4.x, 0.f);
        h2v[i8*4+1] = fmaxf((tv[i8*4+1]-mu)*rs*g4.y + b4.y, 0.f);
        h2v[i8*4+2] = fmaxf((tv[i8*4+2]-mu)*rs*g4.z + b4.z, 0.f);
        h2v[i8*4+3] = fmaxf((tv[i8*4+3]-mu)*rs*g4.w + b4.w, 0.f);
      }
      uint4 p0=pk8(h2v), p1=pk8(h2v+8), p2=pk8(h2v+16), p3=pk8(h2v+24);
      uint4* d = (uint4*)&ht[rrow][rq3*32];
      d[0]=p0; d[1]=p1; d[2]=p2; d[3]=p3;
    }
    __syncthreads();
    f32x4 hacc = (f32x4){0.f,0.f,0.f,0.f};
    #pragma unroll
    for (int ks=0;ks<8;ks++){
      short8_t a;
      if (ks < 4)
        a = relu8(*(const short8_t*)&h0t[w*16 + c][ks*32 + kg*8]);
      else
        a = *(const short8_t*)&ht[w*16 + c][(ks-4)*32 + kg*8];
      short8_t bb = *(const short8_t*)&wrl[c][ks*32 + kg*8];
      hacc = __builtin_amdgcn_mfma_f32_16x16x32_bf16(a, bb, hacc, 0, 0, 0);
    }
    if (c < 12){
      float br = b_reg[c];
      #pragma unroll
      for (int j=0;j<4;j++){
        long gr = r0w + kg*4 + j;
        if (gr < NN)
          out[((long)b*12 + c)*NN + gr] = hacc[j] + br;
      }
    }
    __syncthreads();   // ht/h0t WAR for next tile
    aq0=aq0n; aq1=aq1n;
    rh0=nh0; rh1=nh1; rh2=nh2; rh3=nh3;
    ah0=na0; ah1=na1; ah2=na2; ah3=na3;
  }
}

extern "C" void kernel_launch(void* const* d_in, const int* in_sizes, int n_in,
                              void* d_out, int out_size, void* d_ws, size_t ws_size,
                              hipStream_t stream)
{
  const float* x        = (const float*)d_in[0];
  const float* node_emb = (const float*)d_in[1];
  const float* time_emb = (const float*)d_in[2];
  const float* week_emb = (const float*)d_in[3];
  const float* W_in     = (const float*)d_in[4];
  const float* b_in     = (const float*)d_in[5];
  const float* W1       = (const float*)d_in[6];
  const float* b1       = (const float*)d_in[7];
  const float* W2       = (const float*)d_in[8];
  const float* b2       = (const float*)d_in[9];
  const float* W_reg    = (const float*)d_in[10];
  const float* b_reg    = (const float*)d_in[11];
  const float* proj     = (const float*)d_in[12];
  const float* fc_in0_w = (const float*)d_in[13];
  const float* fc_in0_b = (const float*)d_in[14];
  const float* fc_out0_w= (const float*)d_in[15];
  const float* fc_out0_b= (const float*)d_in[16];
  const float* ln0_g    = (const float*)d_in[17];
  const float* ln0_b    = (const float*)d_in[18];
  const float* fc_in1_w = (const float*)d_in[19];
  const float* fc_in1_b = (const float*)d_in[20];
  const float* fc_out1_w= (const float*)d_in[21];
  const float* fc_out1_b= (const float*)d_in[22];
  const float* ln1_g    = (const float*)d_in[23];
  const float* ln1_b    = (const float*)d_in[24];
  char* wsb  = (char*)d_ws;
  float* out = (float*)d_out;

  dim3 rowgrid((NN+255)/256, NB);     // (196, 4)
  dim3 pgrid(128, NB);                // persistent: 512 blocks, tile-stride
  dim3 cvtgrid(144);

  hipFuncSetAttribute((const void*)k_glured,
                      hipFuncAttributeMaxDynamicSharedMemorySize, 65536);

  k_init  <<<258, 256, 0, stream>>>(wsb);
  k_wcvt  <<<256, 256, 0, stream>>>(fc_in0_w, fc_out0_w, fc_in1_w, fc_out1_w, wsb);
  k_wcvt2 <<<48, 256, 0, stream>>>(W1, W2, proj, W_reg, wsb);
  k_pass1a<<<rowgrid, 256, 0, stream>>>(x, node_emb, time_emb, week_emb,
                                        W_in, b_in, wsb);
  k_pass1b<<<pgrid, 256, 0, stream>>>(b1, b2, wsb);
  k_glured<<<pgrid, 256, 65536, stream>>>(wsb, (const unsigned short*)(wsb + H0B),
                                          (const unsigned short*)(wsb + WBFB),
                                          fc_in0_b, fc_out0_b,
                                          (float*)(wsb + V2F0B), (float*)(wsb + KSB));
  k_v2cvt <<<cvtgrid, 256, 0, stream>>>(wsb, (const float*)(wsb + V2F0B));
  k_attnln<<<pgrid, 256, 0, stream>>>(wsb, ln0_g, ln0_b);
  k_glured<<<pgrid, 256, 65536, stream>>>(wsb, (const unsigned short*)(wsb + H1B),
                                          (const unsigned short*)(wsb + WBFB) + 32768,
                                          fc_in1_b, fc_out1_b,
                                          (float*)(wsb + V2F1B), (float*)nullptr);
  k_v2cvt <<<cvtgrid, 256, 0, stream>>>(wsb, (const float*)(wsb + V2F1B));
  k_attnhead<<<pgrid, 256, 0, stream>>>(wsb, ln1_g, ln1_b, b_reg, out);
}

// Round 23
// 320.472 us; speedup vs baseline: 1.4177x; 1.1347x over previous
//
#include <hip/hip_runtime.h>

#define NB 4
#define NN 50000
#define NT 784   // 64-row tiles per batch (784*64 = 50176 >= NN)

// ---- workspace byte offsets (total ~154.9 MB, < proven 205.9 MB) ----
#define H0B    0L
#define H1B    51200000L
#define QB     102400000L
#define KKB    128000000L    // k' (unfinalized, bf16)
#define RMB    153600000L    // fp32 rm [4*50000]
#define WBFB   154400000L    // bf16 GLU weights: layer0 [256][128], layer1 at +65536B
#define V2F0B  154531072L    // fp32 v2x layer0 [4][64][128]
#define V2F1B  154662144L    // fp32 v2x layer1
#define KSB    154793216L    // fp32 ksum [4][64]
#define GMB    154794240L    // 4 uints
#define W12B   154795264L    // bf16: W1 [32][96], W2 [32][96], proj [64][32], W_regT [16][256]
#define V2TB   154819840L    // bf16 v2x^T+ksum [4][144][64]
#define NZERO  65796         // words zeroed at V2F0B (v2x0+v2x1+ksum+gmax)

typedef short short8_t __attribute__((ext_vector_type(8)));
typedef float f32x4 __attribute__((ext_vector_type(4)));

__device__ __forceinline__ unsigned short f2bf(float f){
  unsigned u = __float_as_uint(f);
  return (unsigned short)((u + 0x7FFFu + ((u>>16)&1u)) >> 16);
}
__device__ __forceinline__ float bf2f(unsigned short s){
  return __uint_as_float(((unsigned)s)<<16);
}
__device__ __forceinline__ unsigned pk2(float a, float b){
  return (unsigned)f2bf(a) | ((unsigned)f2bf(b)<<16);
}
__device__ __forceinline__ uint4 pk8(const float* f){
  uint4 o; o.x=pk2(f[0],f[1]); o.y=pk2(f[2],f[3]);
  o.z=pk2(f[4],f[5]); o.w=pk2(f[6],f[7]); return o;
}
__device__ __forceinline__ void up8(uint4 v, float* f){
  f[0]=bf2f((unsigned short)(v.x&0xFFFFu)); f[1]=bf2f((unsigned short)(v.x>>16));
  f[2]=bf2f((unsigned short)(v.y&0xFFFFu)); f[3]=bf2f((unsigned short)(v.y>>16));
  f[4]=bf2f((unsigned short)(v.z&0xFFFFu)); f[5]=bf2f((unsigned short)(v.z>>16));
  f[6]=bf2f((unsigned short)(v.w&0xFFFFu)); f[7]=bf2f((unsigned short)(v.w>>16));
}
__device__ __forceinline__ short8_t relu8(short8_t s){
  short8_t r;
  #pragma unroll
  for (int i=0;i<8;i++){ short v = s[i]; r[i] = (v & (short)0x8000) ? (short)0 : v; }
  return r;
}
__device__ __forceinline__ unsigned encOrd(float f){
  unsigned u = __float_as_uint(f);
  return (u & 0x80000000u) ? ~u : (u | 0x80000000u);
}
__device__ __forceinline__ float decOrd(unsigned u){
  return (u & 0x80000000u) ? __uint_as_float(u & 0x7fffffffu)
                           : __uint_as_float(~u);
}

// ---- zero v2x0+v2x1+ksum+gmax ----
__global__ void k_init(char* __restrict__ wsb){
  int i = blockIdx.x*256 + threadIdx.x;
  if (i < NZERO) ((unsigned*)(wsb + V2F0B))[i] = 0u;
}
// ---- GLU weights -> bf16 [n][k] ----
__global__ void k_wcvt(const float* __restrict__ wi0, const float* __restrict__ wo0,
                       const float* __restrict__ wi1, const float* __restrict__ wo1,
                       char* __restrict__ wsb){
  int idx = blockIdx.x*256 + threadIdx.x;
  if (idx >= 65536) return;
  int l = idx >> 15, r = (idx >> 7) & 255, c = idx & 127;
  const float* src = (l==0) ? ((r<128)? wi0 : wo0) : ((r<128)? wi1 : wo1);
  float v = src[(r&127)*128 + c];
  ((unsigned short*)(wsb + WBFB))[l*32768 + r*128 + c] = f2bf(v);
}
// ---- W1,W2 [32][96], proj [64][32], W_regT [16][256] -> bf16 --------------
__global__ void k_wcvt2(const float* __restrict__ W1, const float* __restrict__ W2,
                        const float* __restrict__ proj, const float* __restrict__ W_reg,
                        char* __restrict__ wsb){
  int i = blockIdx.x*256 + threadIdx.x;          // 12288 total
  if (i >= 12288) return;
  unsigned short* dst = (unsigned short*)(wsb + W12B);
  float v;
  if (i < 3072) v = W1[i];
  else if (i < 6144) v = W2[i-3072];
  else if (i < 8192) v = proj[i-6144];
  else {
    int r = (i-8192) >> 8, c = (i-8192) & 255;
    v = (r < 12) ? W_reg[r*256 + c] : 0.f;
  }
  dst[i] = f2bf(v);
}

// ---------- pass1a: h0 (W_in matmul + embeddings) --------------------------
__global__ __launch_bounds__(256) void k_pass1a(
  const float* __restrict__ x, const float* __restrict__ node_emb,
  const float* __restrict__ time_emb, const float* __restrict__ week_emb,
  const float* __restrict__ W_in, const float* __restrict__ b_in,
  char* __restrict__ wsb)
{
  const int b = blockIdx.y;
  const int n = blockIdx.x*256 + threadIdx.x;
  if (n >= NN) return;
  const long row = (long)b*NN + n;
  float xr[36];
  {
    const float4* xp = (const float4*)(x + row*36);
    #pragma unroll
    for (int i=0;i<9;i++){ float4 t=xp[i]; xr[4*i]=t.x; xr[4*i+1]=t.y; xr[4*i+2]=t.z; xr[4*i+3]=t.w; }
  }
  int tidx = (int)(xr[34]*288.0f); tidx = tidx<0?0:(tidx>287?287:tidx);
  int widx = (int)(xr[35]);        widx = widx<0?0:(widx>6?6:widx);
  uint4* h0q = (uint4*)(wsb + H0B) + row*16;
  float hh[32];
  #pragma unroll 1
  for (int jj=0;jj<8;jj++){
    #pragma unroll
    for (int jl=0;jl<4;jl++){
      const int j = jj*4+jl;
      const float* w = W_in + j*36;
      float a0=0.f,a1=0.f,a2=0.f,a3=0.f;
      #pragma unroll
      for (int i=0;i<36;i+=4){ a0+=xr[i]*w[i]; a1+=xr[i+1]*w[i+1]; a2+=xr[i+2]*w[i+2]; a3+=xr[i+3]*w[i+3]; }
      hh[j] = b_in[j] + ((a0+a1)+(a2+a3));
    }
  }
  #pragma unroll
  for (int c=0;c<4;c++) h0q[c] = pk8(hh + 8*c);
  float xg[96];
  {
    const float4* p0 = (const float4*)(node_emb + (long)n*32);
    const float4* p1 = (const float4*)(time_emb + (long)tidx*32);
    const float4* p2 = (const float4*)(week_emb + (long)widx*32);
    #pragma unroll
    for (int i=0;i<8;i++){ float4 t=p0[i]; xg[4*i]=t.x; xg[4*i+1]=t.y; xg[4*i+2]=t.z; xg[4*i+3]=t.w; }
    #pragma unroll
    for (int i=0;i<8;i++){ float4 t=p1[i]; xg[32+4*i]=t.x; xg[32+4*i+1]=t.y; xg[32+4*i+2]=t.z; xg[32+4*i+3]=t.w; }
    #pragma unroll
    for (int i=0;i<8;i++){ float4 t=p2[i]; xg[64+4*i]=t.x; xg[64+4*i+1]=t.y; xg[64+4*i+2]=t.z; xg[64+4*i+3]=t.w; }
  }
  #pragma unroll
  for (int c=0;c<12;c++) h0q[4+c] = pk8(xg + 8*c);
}

// ---------- pass1b (MFMA, persistent): q, k', rm, global key max -----------
// W1/W2/proj staged in LDS (padded strides, 2-way reads)
__global__ __launch_bounds__(256) void k_pass1b(
  const float* __restrict__ b1, const float* __restrict__ b2,
  char* __restrict__ wsb)
{
  __shared__ unsigned short xgt[64][104];
  __shared__ unsigned short dt[2][64][40];
  __shared__ unsigned short ot[64][72];
  __shared__ unsigned short w1l[32][104];
  __shared__ unsigned short w2l[32][104];
  __shared__ unsigned short pjl[64][40];
  __shared__ float wred[4];
  const int b   = blockIdx.y;
  const int tid = threadIdx.x;
  const int lane= tid & 63;
  const int w   = tid >> 6;
  const int c   = lane & 15;
  const int kg  = lane >> 4;
  const int nblk = gridDim.x;
  const int srow = tid >> 2, sq3 = tid & 3;
  // stage weights once per block
  {
    const unsigned short* w1bf = (const unsigned short*)(wsb + W12B);
    const unsigned short* w2bf = w1bf + 3072;
    const unsigned short* pjbf = w1bf + 6144;
    for (int i = tid; i < 3072; i += 256){ w1l[i/96][i%96] = w1bf[i]; w2l[i/96][i%96] = w2bf[i]; }
    for (int i = tid; i < 2048; i += 256){ pjl[i/32][i%32] = pjbf[i]; }
  }
  uint4 xv0, xv1, xv2;
  {
    const long r0 = (long)blockIdx.x*64;
    long gr = r0 + srow;
    xv0=(uint4){0,0,0,0}; xv1=xv0; xv2=xv0;
    if (gr < NN){
      const uint4* src = (const uint4*)(wsb + H0B + ((long)b*NN + gr)*256 + 64 + sq3*48);
      xv0=src[0]; xv1=src[1]; xv2=src[2];
    }
  }
  #pragma unroll 1
  for (int tile = blockIdx.x; tile < NT; tile += nblk){
    const long r0blk = (long)tile*64;
    {
      uint4* d = (uint4*)&xgt[srow][sq3*24];
      d[0]=xv0; d[1]=xv1; d[2]=xv2;
    }
    if (tile + nblk < NT){
      const long r1 = (long)(tile + nblk)*64;
      long gr = r1 + srow;
      xv0=(uint4){0,0,0,0}; xv1=xv0; xv2=xv0;
      if (gr < NN){
        const uint4* src = (const uint4*)(wsb + H0B + ((long)b*NN + gr)*256 + 64 + sq3*48);
        xv0=src[0]; xv1=src[1]; xv2=src[2];
      }
    }
    __syncthreads();   // xgt (and on first tile: weights) ready
    f32x4 accd[2][2];
    #pragma unroll
    for (int s=0;s<2;s++)
      #pragma unroll
      for (int f=0;f<2;f++) accd[s][f] = (f32x4){0.f,0.f,0.f,0.f};
    #pragma unroll
    for (int ks=0;ks<3;ks++){
      short8_t a = *(const short8_t*)&xgt[w*16 + c][ks*32 + kg*8];
      #pragma unroll
      for (int f=0;f<2;f++){
        short8_t bw1 = *(const short8_t*)&w1l[f*16+c][ks*32 + kg*8];
        accd[0][f] = __builtin_amdgcn_mfma_f32_16x16x32_bf16(a, bw1, accd[0][f], 0,0,0);
        short8_t bw2 = *(const short8_t*)&w2l[f*16+c][ks*32 + kg*8];
        accd[1][f] = __builtin_amdgcn_mfma_f32_16x16x32_bf16(a, bw2, accd[1][f], 0,0,0);
      }
    }
    const float DSC = 0.42044820762685725f;   // 32^-0.25
    float dv[2][2][4];
    #pragma unroll
    for (int f=0;f<2;f++){
      float bb1 = b1[f*16+c], bb2 = b2[f*16+c];
      #pragma unroll
      for (int jj=0;jj<4;jj++){
        dv[0][f][jj] = (accd[0][f][jj] + bb1) * DSC;
        dv[1][f][jj] = (accd[1][f][jj] + bb2) * DSC;
      }
    }
    float dg[2][4];
    #pragma unroll
    for (int s=0;s<2;s++)
      #pragma unroll
      for (int jj=0;jj<4;jj++){
        float t = dv[s][0][jj]*dv[s][0][jj] + dv[s][1][jj]*dv[s][1][jj];
        #pragma unroll
        for (int off=1; off<16; off<<=1) t += __shfl_xor(t, off);
        dg[s][jj] = 0.5f * t;
      }
    #pragma unroll
    for (int s=0;s<2;s++)
      #pragma unroll
      for (int f=0;f<2;f++)
        #pragma unroll
        for (int jj=0;jj<4;jj++)
          dt[s][w*16 + kg*4 + jj][f*16 + c] = f2bf(dv[s][f][jj]);
    __syncthreads();
    f32x4 acc2[2][4];
    #pragma unroll
    for (int s=0;s<2;s++){
      short8_t ad = *(const short8_t*)&dt[s][w*16 + c][kg*8];
      #pragma unroll
      for (int f=0;f<4;f++){
        short8_t bp = *(const short8_t*)&pjl[f*16+c][kg*8];
        acc2[s][f] = __builtin_amdgcn_mfma_f32_16x16x32_bf16(ad, bp, (f32x4){0.f,0.f,0.f,0.f}, 0,0,0);
      }
    }
    float mx[2][4];
    #pragma unroll
    for (int s=0;s<2;s++)
      #pragma unroll
      for (int jj=0;jj<4;jj++){
        float t = fmaxf(fmaxf(acc2[s][0][jj],acc2[s][1][jj]),
                        fmaxf(acc2[s][2][jj],acc2[s][3][jj]));
        #pragma unroll
        for (int off=1; off<16; off<<=1) t = fmaxf(t, __shfl_xor(t, off));
        mx[s][jj] = t;
      }
    #pragma unroll
    for (int f=0;f<4;f++)
      #pragma unroll
      for (int jj=0;jj<4;jj++){
        float qv = 0.125f*(__expf(acc2[0][f][jj] - dg[0][jj] - mx[0][jj]) + 1e-6f);
        ot[w*16 + kg*4 + jj][f*16 + c] = f2bf(qv);
      }
    __syncthreads();
    {
      long gr = r0blk + srow;
      if (gr < NN){
        const uint4* s = (const uint4*)&ot[srow][sq3*16];
        uint4* dst = (uint4*)((unsigned short*)(wsb + QB) + ((long)b*NN + gr)*64 + sq3*16);
        dst[0] = s[0]; dst[1] = s[1];
      }
    }
    __syncthreads();
    float bmax = -3.0e38f;
    #pragma unroll
    for (int f=0;f<4;f++)
      #pragma unroll
      for (int jj=0;jj<4;jj++){
        float kv = __expf(acc2[1][f][jj] - mx[1][jj]);
        ot[w*16 + kg*4 + jj][f*16 + c] = f2bf(kv);
      }
    #pragma unroll
    for (int jj=0;jj<4;jj++){
      long gr = r0blk + w*16 + kg*4 + jj;
      bool val = (gr < NN);
      if (val && c==0)
        ((float*)(wsb + RMB))[(long)b*NN + gr] = mx[1][jj] - dg[1][jj];
      if (val) bmax = fmaxf(bmax, mx[1][jj]);
    }
    #pragma unroll
    for (int off=32; off>0; off>>=1) bmax = fmaxf(bmax, __shfl_xor(bmax, off));
    if (lane==0) wred[w] = bmax;
    __syncthreads();
    {
      long gr = r0blk + srow;
      if (gr < NN){
        const uint4* s = (const uint4*)&ot[srow][sq3*16];
        uint4* dst = (uint4*)((unsigned short*)(wsb + KKB) + ((long)b*NN + gr)*64 + sq3*16);
        dst[0] = s[0]; dst[1] = s[1];
      }
    }
    if (tid==0){
      float m2 = fmaxf(fmaxf(wred[0],wred[1]), fmaxf(wred[2],wred[3]));
      atomicMax((unsigned*)(wsb + GMB) + b, encOrd(m2));
    }
    __syncthreads();   // ot/wred WAR before next tile
  }
}

// ---------- fused GLU + k-finalize (+ksum) + MFMA reduce -------------------
// 512 threads / 8 waves (2 waves/SIMD at 1 block/CU); waves = 4 row-groups x
// 2 feature-halves; weights in dynamic LDS; 2 barriers/tile
__global__ __launch_bounds__(512) void k_glured(
  char* __restrict__ wsb, const unsigned short* __restrict__ hsrc,
  const unsigned short* __restrict__ wbf,
  const float* __restrict__ bi, const float* __restrict__ bo,
  float* __restrict__ v2x_out, float* __restrict__ ksout)
{
  __shared__ unsigned short ht[64][132];       // 16896 B
  __shared__ unsigned short htT[128][72];      // 18432 B
  __shared__ unsigned short ktl[2][64][72];    // 2 x 9216 B
  __shared__ float red[512];                   // 2048 B
  extern __shared__ unsigned short wl[];       // dynamic: 65536 B, swizzled weights
  const int b = blockIdx.y;
  const int tid = threadIdx.x;
  const int lane = tid & 63;
  const int w  = tid >> 6;        // 0..7
  const int wr = w & 3;           // row group (16 rows)
  const int wh = w >> 2;          // feature half
  const int c  = lane & 15;
  const int kg = lane >> 4;
  const int nblk = gridDim.x;
  const float gm = decOrd(((const unsigned*)(wsb + GMB))[b]);
  const float* rm = (const float*)(wsb + RMB) + (long)b*NN;
  const uint4* kbase = (const uint4*)(wsb + KKB) + (long)b*NN*8;
  // stage weights once: wl[row][blk ^ (row&7)] = wbf[row][blk]   (16B blocks)
  {
    uint4* wl4 = (uint4*)wl;
    const uint4* src = (const uint4*)wbf;
    #pragma unroll
    for (int e=0;e<8;e++){
      int i = tid + 512*e;           // 4096 uint4 total
      int row = i >> 4, blk = i & 15;
      wl4[row*16 + (blk ^ (row & 7))] = src[i];
    }
  }
  f32x4 racc[4];
  #pragma unroll
  for (int f=0;f<4;f++) racc[f] = (f32x4){0.f,0.f,0.f,0.f};
  float ksacc = 0.f;
  float bi_l[4], bo_l[4];
  #pragma unroll
  for (int ff=0;ff<4;ff++){
    bi_l[ff] = bi[(wh*4+ff)*16 + c];
    bo_l[ff] = bo[(wh*4+ff)*16 + c];
  }
  const int krr = tid>>3, kcc = tid&7;        // krr in [0,64)
  const int srow = tid>>3, sq = tid&7;        // ht staging: 8 threads/row, 16 shorts each
  const int rswz = ((wr*16 + c) >> 3) & 7;
  const int wswz = c & 7;                      // weight-read swizzle (row&7 = c&7)
  uint4 hv0,hv1, krA; float rmA;
  {
    const long r0 = (long)blockIdx.x*64;
    long gr = r0 + srow;
    hv0=(uint4){0,0,0,0}; hv1=hv0;
    if (gr < NN){
      const uint4* s = (const uint4*)(hsrc + ((long)b*NN + gr)*128 + sq*16);
      hv0=s[0]; hv1=s[1];
    }
    krA=(uint4){0,0,0,0}; rmA=0.f;
    long gA = r0 + krr;
    if (gA < NN){ krA = kbase[gA*8 + kcc]; rmA = rm[gA]; }
  }
  int p = 0;
  #pragma unroll 1
  for (int tile = blockIdx.x; tile < NT; tile += nblk){
    const long r0 = (long)tile*64;
    // Phase A: write ht + ktl[p] from prefetched regs; issue next prefetch
    {
      uint4* d = (uint4*)&ht[srow][sq*16];
      d[0]=hv0; d[1]=hv1;
    }
    {
      bool vA = (r0 + krr) < NN;
      float sA = __expf(rmA - gm);
      float ta[8];
      up8(krA, ta);
      #pragma unroll
      for (int i=0;i<8;i++)
        ta[i] = vA ? 0.125f*(ta[i]*sA + 1e-6f) : 0.f;
      const int pA = (((krr>>3) ^ kcc) << 3) | (krr & 7);
      #pragma unroll
      for (int i=0;i<8;i++)
        ktl[p][kcc*8+i][pA] = f2bf(ta[i]);
    }
    if (tile + nblk < NT){
      const long r1 = (long)(tile + nblk)*64;
      long gr = r1 + srow;
      hv0=(uint4){0,0,0,0}; hv1=hv0;
      if (gr < NN){
        const uint4* s = (const uint4*)(hsrc + ((long)b*NN + gr)*128 + sq*16);
        hv0=s[0]; hv1=s[1];
      }
      krA=(uint4){0,0,0,0}; rmA=0.f;
      long gA = r1 + krr;
      if (gA < NN){ krA = kbase[gA*8 + kcc]; rmA = rm[gA]; }
    }
    __syncthreads();   // barrier A: ht/ktl[p] (and, on tile 0, wl) ready
    // Phase B: GLU MFMA — wave handles rows wr*16.., features half wh
    {
      const f32x4 z4 = (f32x4){0.f,0.f,0.f,0.f};
      f32x4 gi[4], go[4];
      #pragma unroll
      for (int ff=0;ff<4;ff++){ gi[ff]=z4; go[ff]=z4; }
      #pragma unroll
      for (int ks=0;ks<4;ks++){
        short8_t a = *(const short8_t*)&ht[wr*16 + c][ks*32 + kg*8];
        #pragma unroll
        for (int ff=0;ff<4;ff++){
          const int fi = wh*4 + ff;
          short8_t bwi = *(const short8_t*)(wl + (((fi*16 + c)*16 + ((ks*4 + kg) ^ wswz)) << 3));
          gi[ff] = __builtin_amdgcn_mfma_f32_16x16x32_bf16(a, bwi, gi[ff], 0, 0, 0);
          short8_t bwo = *(const short8_t*)(wl + ((((fi+8)*16 + c)*16 + ((ks*4 + kg) ^ wswz)) << 3));
          go[ff] = __builtin_amdgcn_mfma_f32_16x16x32_bf16(a, bwo, go[ff], 0, 0, 0);
        }
      }
      #pragma unroll
      for (int ff=0;ff<4;ff++){
        const int fi = wh*4 + ff;
        #pragma unroll
        for (int j=0;j<4;j++){
          float aa = gi[ff][j] + bi_l[ff];
          float cc2= go[ff][j] + bo_l[ff];
          float o  = cc2 / (1.0f + __expf(-aa));
          bool val = (r0 + wr*16 + kg*4 + j) < NN;
          htT[fi*16 + c][wr*16 + kg*4 + j] = val ? f2bf(o) : (unsigned short)0;
        }
      }
    }
    if (ksout){
      int m = tid & 63, n0 = (tid>>6)*8;
      int sm = (m>>3)&7;
      #pragma unroll
      for (int n=0;n<8;n++){
        int nn = n0+n;
        ksacc += bf2f(ktl[p][m][(((nn>>3)^sm)<<3)|(nn&7)]);
      }
    }
    __syncthreads();   // barrier B: htT ready
    // Phase C: reduce MFMA (reads ktl[p] + htT only)
    #pragma unroll
    for (int ks=0;ks<2;ks++){
      short8_t a = *(const short8_t*)&ktl[p][wr*16 + c][((ks*4 + kg) ^ rswz) << 3];
      #pragma unroll
      for (int ff=0;ff<4;ff++){
        const int fi = wh*4 + ff;
        short8_t bb = *(const short8_t*)&htT[fi*16 + c][ks*32 + kg*8];
        racc[ff] = __builtin_amdgcn_mfma_f32_16x16x32_bf16(a, bb, racc[ff], 0, 0, 0);
      }
    }
    p ^= 1;
    // no barrier: next Phase A writes ht (unread in C) and ktl[p^1] (unread in C)
  }
  float* v2x = v2x_out + (long)b*8192;
  #pragma unroll
  for (int ff=0;ff<4;ff++)
    #pragma unroll
    for (int j=0;j<4;j++)
      atomicAdd(&v2x[(wr*16 + kg*4 + j)*128 + (wh*4+ff)*16 + c], racc[ff][j]);
  if (ksout){
    red[tid] = ksacc;
    __syncthreads();
    if (tid < 64){
      float s = 0.f;
      #pragma unroll
      for (int q=0;q<8;q++) s += red[q*64 + tid];
      atomicAdd(ksout + b*64 + tid, s);
    }
  }
}

// ---------- v2t[b][n][m]: n<128: v2x[m][n]; n=128: ksum[m]; n>128: 0 -------
__global__ void k_v2cvt(char* __restrict__ wsb, const float* __restrict__ v2f){
  int idx = blockIdx.x*256 + threadIdx.x;          // 36864
  if (idx >= 36864) return;
  int b = idx / 9216, rem = idx % 9216;
  int n = rem / 64, m = rem % 64;
  const float* ks = (const float*)(wsb + KSB);
  float v = (n < 128) ? v2f[b*8192 + m*128 + n] : ((n==128) ? ks[b*64+m] : 0.f);
  ((unsigned short*)(wsb + V2TB))[b*9216 + n*64 + m] = f2bf(v);
}

// ---------- attn0 + residual(h0) + LN0 -> h1 (persistent) ------------------
__global__ __launch_bounds__(256) void k_attnln(
  char* __restrict__ wsb, const float* __restrict__ g0,
  const float* __restrict__ bt0)
{
  __shared__ unsigned short ht[64][132];    // 16896 B
  __shared__ unsigned short v2s[144*72];    // 20736 B (persistent across tiles)
  const int b = blockIdx.y;
  const int tid = threadIdx.x;
  const int lane = tid & 63;
  const int w  = tid >> 6;
  const int c  = lane & 15;
  const int kg = lane >> 4;
  const int nblk = gridDim.x;
  const int rrow = tid>>2, rq3 = tid&3;
  const unsigned short* qb = (const unsigned short*)(wsb + QB) + (long)b*NN*64;
  const unsigned short* h0g = (const unsigned short*)(wsb + H0B) + (long)b*NN*128;
  unsigned short* h1g = (unsigned short*)(wsb + H1B) + (long)b*NN*128;
  {
    const uint4* v2g = (const uint4*)((const unsigned short*)(wsb + V2TB) + b*9216);
    #pragma unroll
    for (int e=0;e<5;e++){
      int j = tid + 256*e;
      if (j < 1152){
        int row = j >> 3, cc = j & 7;
        *(uint4*)&v2s[row*72 + cc*8] = v2g[j];
      }
    }
  }
  short8_t aq0, aq1;
  uint4 rh0, rh1, rh2, rh3;
  {
    const long r0 = (long)blockIdx.x*64;
    if (r0 + w*16 + c < NN){
      const unsigned short* qrow = qb + (r0 + w*16 + c)*64 + kg*8;
      aq0 = *(const short8_t*)qrow; aq1 = *(const short8_t*)(qrow + 32);
    } else { aq0 = (short8_t){0,0,0,0,0,0,0,0}; aq1 = aq0; }
    rh0=(uint4){0,0,0,0}; rh1=rh0; rh2=rh0; rh3=rh0;
    if (r0 + rrow < NN){
      const uint4* hs = (const uint4*)(h0g + (r0 + rrow)*128 + rq3*32);
      rh0=hs[0]; rh1=hs[1]; rh2=hs[2]; rh3=hs[3];
    }
  }
  __syncthreads();   // v2s ready
  #pragma unroll 1
  for (int tile = blockIdx.x; tile < NT; tile += nblk){
    const long r0blk = (long)tile*64;
    const long rgr = r0blk + rrow;
    f32x4 acc[9];
    #pragma unroll
    for (int f=0;f<9;f++) acc[f] = (f32x4){0.f,0.f,0.f,0.f};
    #pragma unroll
    for (int f=0;f<9;f++){
      short8_t b0 = *(const short8_t*)&v2s[(f*16 + c)*72 + kg*8];
      acc[f] = __builtin_amdgcn_mfma_f32_16x16x32_bf16(aq0, b0, acc[f], 0, 0, 0);
      short8_t b1v = *(const short8_t*)&v2s[(f*16 + c)*72 + 32 + kg*8];
      acc[f] = __builtin_amdgcn_mfma_f32_16x16x32_bf16(aq1, b1v, acc[f], 0, 0, 0);
    }
    float inv[4];
    #pragma unroll
    for (int j=0;j<4;j++) inv[j] = 1.0f / __shfl(acc[8][j], (lane & 48));
    #pragma unroll
    for (int f=0;f<8;f++)
      #pragma unroll
      for (int j=0;j<4;j++)
        ht[w*16 + kg*4 + j][f*16 + c] = f2bf(acc[f][j]*inv[j]);
    __syncthreads();
    short8_t aq0n, aq1n;
    uint4 nh0, nh1, nh2, nh3;
    {
      aq0n = (short8_t){0,0,0,0,0,0,0,0}; aq1n = aq0n;
      nh0=(uint4){0,0,0,0}; nh1=nh0; nh2=nh0; nh3=nh0;
      if (tile + nblk < NT){
        const long r1 = (long)(tile + nblk)*64;
        if (r1 + w*16 + c < NN){
          const unsigned short* qrow = qb + (r1 + w*16 + c)*64 + kg*8;
          aq0n = *(const short8_t*)qrow; aq1n = *(const short8_t*)(qrow + 32);
        }
        if (r1 + rrow < NN){
          const uint4* hs = (const uint4*)(h0g + (r1 + rrow)*128 + rq3*32);
          nh0=hs[0]; nh1=hs[1]; nh2=hs[2]; nh3=hs[3];
        }
      }
    }
    {
      float tv[32];
      {
        const uint4* os = (const uint4*)&ht[rrow][rq3*32];
        uint4 o0=os[0],o1=os[1],o2=os[2],o3=os[3];
        up8(o0,tv); up8(o1,tv+8); up8(o2,tv+16); up8(o3,tv+24);
      }
      {
        float hv[32];
        up8(rh0,hv); up8(rh1,hv+8); up8(rh2,hv+16); up8(rh3,hv+24);
        #pragma unroll
        for (int i=0;i<32;i++) tv[i] += hv[i];
      }
      float s = 0.f;
      #pragma unroll
      for (int i=0;i<32;i++) s += tv[i];
      s += __shfl_xor(s, 1); s += __shfl_xor(s, 2);
      float mu = s * (1.0f/128.0f);
      float vv = 0.f;
      #pragma unroll
      for (int i=0;i<32;i++){ float e = tv[i]-mu; vv += e*e; }
      vv += __shfl_xor(vv, 1); vv += __shfl_xor(vv, 2);
      float rs = rsqrtf(vv * (1.0f/128.0f) + 1e-5f);
      const float4* gp = (const float4*)(g0 + rq3*32);
      const float4* bp = (const float4*)(bt0 + rq3*32);
      float h1v[32];
      #pragma unroll
      for (int i8=0;i8<8;i8++){
        float4 g4 = gp[i8], b4 = bp[i8];
        h1v[i8*4  ] = (tv[i8*4  ]-mu)*rs*g4.x + b4.x;
        h1v[i8*4+1] = (tv[i8*4+1]-mu)*rs*g4.y + b4.y;
        h1v[i8*4+2] = (tv[i8*4+2]-mu)*rs*g4.z + b4.z;
        h1v[i8*4+3] = (tv[i8*4+3]-mu)*rs*g4.w + b4.w;
      }
      if (rgr < NN){
        uint4 p0=pk8(h1v), p1=pk8(h1v+8), p2=pk8(h1v+16), p3=pk8(h1v+24);
        uint4* dst = (uint4*)(h1g + rgr*128 + rq3*32);
        dst[0]=p0; dst[1]=p1; dst[2]=p2; dst[3]=p3;
      }
    }
    __syncthreads();   // ht WAR for next tile
    aq0=aq0n; aq1=aq1n; rh0=nh0; rh1=nh1; rh2=nh2; rh3=nh3;
  }
}

// ---------- attn1 + residual(h1) + LN1 + MFMA head (persistent) ------------
// W_regT staged in LDS with padded stride (was a 16-way global pattern)
__global__ __launch_bounds__(256) void k_attnhead(
  char* __restrict__ wsb, const float* __restrict__ g1,
  const float* __restrict__ bt1, const float* __restrict__ b_reg,
  float* __restrict__ out)
{
  __shared__ unsigned short ht[64][132];    // 16896 B
  __shared__ unsigned short v2s[144*72];    // 20736 B (persistent)
  __shared__ unsigned short h0t[64][136];   // 17408 B
  __shared__ unsigned short wrl[16][264];   // 8448 B  (total 63488 B)
  const int b = blockIdx.y;
  const int tid = threadIdx.x;
  const int lane = tid & 63;
  const int w  = tid >> 6;
  const int c  = lane & 15;
  const int kg = lane >> 4;
  const int nblk = gridDim.x;
  const int rrow = tid>>2, rq3 = tid&3;
  const unsigned short* qb  = (const unsigned short*)(wsb + QB) + (long)b*NN*64;
  const unsigned short* h0g = (const unsigned short*)(wsb + H0B) + (long)b*NN*128;
  const unsigned short* h1g = (const unsigned short*)(wsb + H1B) + (long)b*NN*128;
  {
    const uint4* v2g = (const uint4*)((const unsigned short*)(wsb + V2TB) + b*9216);
    #pragma unroll
    for (int e=0;e<5;e++){
      int j = tid + 256*e;
      if (j < 1152){
        int row = j >> 3, cc = j & 7;
        *(uint4*)&v2s[row*72 + cc*8] = v2g[j];
      }
    }
    const unsigned short* wregT = (const unsigned short*)(wsb + W12B) + 8192;
    for (int i = tid; i < 4096; i += 256)
      wrl[i>>8][i&255] = wregT[i];
  }
  short8_t aq0, aq1;
  uint4 rh0, rh1, rh2, rh3, ah0, ah1, ah2, ah3;
  {
    const long r0 = (long)blockIdx.x*64;
    if (r0 + w*16 + c < NN){
      const unsigned short* qrow = qb + (r0 + w*16 + c)*64 + kg*8;
      aq0 = *(const short8_t*)qrow; aq1 = *(const short8_t*)(qrow + 32);
    } else { aq0 = (short8_t){0,0,0,0,0,0,0,0}; aq1 = aq0; }
    rh0=(uint4){0,0,0,0}; rh1=rh0; rh2=rh0; rh3=rh0;
    ah0=rh0; ah1=rh0; ah2=rh0; ah3=rh0;
    if (r0 + rrow < NN){
      const uint4* hs = (const uint4*)(h1g + (r0 + rrow)*128 + rq3*32);
      rh0=hs[0]; rh1=hs[1]; rh2=hs[2]; rh3=hs[3];
      const uint4* h0s = (const uint4*)(h0g + (r0 + rrow)*128 + rq3*32);
      ah0=h0s[0]; ah1=h0s[1]; ah2=h0s[2]; ah3=h0s[3];
    }
  }
  __syncthreads();   // v2s + wrl ready
  #pragma unroll 1
  for (int tile = blockIdx.x; tile < NT; tile += nblk){
    const long r0blk = (long)tile*64;
    const long r0w = r0blk + w*16;
    const long rgr = r0blk + rrow;
    f32x4 acc[9];
    #pragma unroll
    for (int f=0;f<9;f++) acc[f] = (f32x4){0.f,0.f,0.f,0.f};
    #pragma unroll
    for (int f=0;f<9;f++){
      short8_t b0 = *(const short8_t*)&v2s[(f*16 + c)*72 + kg*8];
      acc[f] = __builtin_amdgcn_mfma_f32_16x16x32_bf16(aq0, b0, acc[f], 0, 0, 0);
      short8_t b1v = *(const short8_t*)&v2s[(f*16 + c)*72 + 32 + kg*8];
      acc[f] = __builtin_amdgcn_mfma_f32_16x16x32_bf16(aq1, b1v, acc[f], 0, 0, 0);
    }
    float inv[4];
    #pragma unroll
    for (int j=0;j<4;j++) inv[j] = 1.0f / __shfl(acc[8][j], (lane & 48));
    #pragma unroll
    for (int f=0;f<8;f++)
      #pragma unroll
      for (int j=0;j<4;j++)
        ht[w*16 + kg*4 + j][f*16 + c] = f2bf(acc[f][j]*inv[j]);
    __syncthreads();
    short8_t aq0n, aq1n;
    uint4 nh0, nh1, nh2, nh3, na0, na1, na2, na3;
    {
      aq0n = (short8_t){0,0,0,0,0,0,0,0}; aq1n = aq0n;
      nh0=(uint4){0,0,0,0}; nh1=nh0; nh2=nh0; nh3=nh0;
      na0=nh0; na1=nh0; na2=nh0; na3=nh0;
      if (tile + nblk < NT){
        const long r1 = (long)(tile + nblk)*64;
        if (r1 + w*16 + c < NN){
          const unsigned short* qrow = qb + (r1 + w*16 + c)*64 + kg*8;
          aq0n = *(const short8_t*)qrow; aq1n = *(const short8_t*)(qrow + 32);
        }
        if (r1 + rrow < NN){
          const uint4* hs = (const uint4*)(h1g + (r1 + rrow)*128 + rq3*32);
          nh0=hs[0]; nh1=hs[1]; nh2=hs[2]; nh3=hs[3];
          const uint4* h0s = (const uint4*)(h0g + (r1 + rrow)*128 + rq3*32);
          na0=h0s[0]; na1=h0s[1]; na2=h0s[2]; na3=h0s[3];
        }
      }
    }
    {
      uint4* hd = (uint4*)&h0t[rrow][rq3*32];
      hd[0]=ah0; hd[1]=ah1; hd[2]=ah2; hd[3]=ah3;
      float tv[32];
      {
        const uint4* os = (const uint4*)&ht[rrow][rq3*32];
        uint4 o0=os[0],o1=os[1],o2=os[2],o3=os[3];
        up8(o0,tv); up8(o1,tv+8); up8(o2,tv+16); up8(o3,tv+24);
      }
      {
        float hv[32];
        up8(rh0,hv); up8(rh1,hv+8); up8(rh2,hv+16); up8(rh3,hv+24);
        #pragma unroll
        for (int i=0;i<32;i++) tv[i] += hv[i];
      }
      float s = 0.f;
      #pragma unroll
      for (int i=0;i<32;i++) s += tv[i];
      s += __shfl_xor(s, 1); s += __shfl_xor(s, 2);
      float mu = s * (1.0f/128.0f);
      float vv = 0.f;
      #pragma unroll
      for (int i=0;i<32;i++){ float e = tv[i]-mu; vv += e*e; }
      vv += __shfl_xor(vv, 1); vv += __shfl_xor(vv, 2);
      float rs = rsqrtf(vv * (1.0f/128.0f) + 1e-5f);
      const float4* gp = (const float4*)(g1 + rq3*32);
      const float4* bp = (const float4*)(bt1 + rq3*32);
      float h2v[32];
      #pragma unroll
      for (int i8=0;i8<8;i8++){
        float4 g4 = gp[i8], b4 = bp[i8];
        h2v[i8*4  ] = fmaxf((tv[i8*4  ]-mu)*rs*g4.x + b4.x, 0.f);
        h2v[i8*4+1] = fmaxf((tv[i8*4+1]-mu)*rs*g4.y + b4.y, 0.f);
        h2v[i8*4+2] = fmaxf((tv[i8*4+2]-mu)*rs*g4.z + b4.z, 0.f);
        h2v[i8*4+3] = fmaxf((tv[i8*4+3]-mu)*rs*g4.w + b4.w, 0.f);
      }
      uint4 p0=pk8(h2v), p1=pk8(h2v+8), p2=pk8(h2v+16), p3=pk8(h2v+24);
      uint4* d = (uint4*)&ht[rrow][rq3*32];
      d[0]=p0; d[1]=p1; d[2]=p2; d[3]=p3;
    }
    __syncthreads();
    f32x4 hacc = (f32x4){0.f,0.f,0.f,0.f};
    #pragma unroll
    for (int ks=0;ks<8;ks++){
      short8_t a;
      if (ks < 4)
        a = relu8(*(const short8_t*)&h0t[w*16 + c][ks*32 + kg*8]);
      else
        a = *(const short8_t*)&ht[w*16 + c][(ks-4)*32 + kg*8];
      short8_t bb = *(const short8_t*)&wrl[c][ks*32 + kg*8];
      hacc = __builtin_amdgcn_mfma_f32_16x16x32_bf16(a, bb, hacc, 0, 0, 0);
    }
    if (c < 12){
      float br = b_reg[c];
      #pragma unroll
      for (int j=0;j<4;j++){
        long gr = r0w + kg*4 + j;
        if (gr < NN)
          out[((long)b*12 + c)*NN + gr] = hacc[j] + br;
      }
    }
    __syncthreads();   // ht/h0t WAR for next tile
    aq0=aq0n; aq1=aq1n;
    rh0=nh0; rh1=nh1; rh2=nh2; rh3=nh3;
    ah0=na0; ah1=na1; ah2=na2; ah3=na3;
  }
}

extern "C" void kernel_launch(void* const* d_in, const int* in_sizes, int n_in,
                              void* d_out, int out_size, void* d_ws, size_t ws_size,
                              hipStream_t stream)
{
  const float* x        = (const float*)d_in[0];
  const float* node_emb = (const float*)d_in[1];
  const float* time_emb = (const float*)d_in[2];
  const float* week_emb = (const float*)d_in[3];
  const float* W_in     = (const float*)d_in[4];
  const float* b_in     = (const float*)d_in[5];
  const float* W1       = (const float*)d_in[6];
  const float* b1       = (const float*)d_in[7];
  const float* W2       = (const float*)d_in[8];
  const float* b2       = (const float*)d_in[9];
  const float* W_reg    = (const float*)d_in[10];
  const float* b_reg    = (const float*)d_in[11];
  const float* proj     = (const float*)d_in[12];
  const float* fc_in0_w = (const float*)d_in[13];
  const float* fc_in0_b = (const float*)d_in[14];
  const float* fc_out0_w= (const float*)d_in[15];
  const float* fc_out0_b= (const float*)d_in[16];
  const float* ln0_g    = (const float*)d_in[17];
  const float* ln0_b    = (const float*)d_in[18];
  const float* fc_in1_w = (const float*)d_in[19];
  const float* fc_in1_b = (const float*)d_in[20];
  const float* fc_out1_w= (const float*)d_in[21];
  const float* fc_out1_b= (const float*)d_in[22];
  const float* ln1_g    = (const float*)d_in[23];
  const float* ln1_b    = (const float*)d_in[24];
  char* wsb  = (char*)d_ws;
  float* out = (float*)d_out;

  dim3 rowgrid((NN+255)/256, NB);     // (196, 4)
  dim3 pgrid(128, NB);                // persistent 256-thread kernels
  dim3 ggrid(64, NB);                 // glured: 256 blocks x 512 threads (1/CU, 8 waves)
  dim3 cvtgrid(144);

  hipFuncSetAttribute((const void*)k_glured,
                      hipFuncAttributeMaxDynamicSharedMemorySize, 65536);

  k_init  <<<258, 256, 0, stream>>>(wsb);
  k_wcvt  <<<256, 256, 0, stream>>>(fc_in0_w, fc_out0_w, fc_in1_w, fc_out1_w, wsb);
  k_wcvt2 <<<48, 256, 0, stream>>>(W1, W2, proj, W_reg, wsb);
  k_pass1a<<<rowgrid, 256, 0, stream>>>(x, node_emb, time_emb, week_emb,
                                        W_in, b_in, wsb);
  k_pass1b<<<pgrid, 256, 0, stream>>>(b1, b2, wsb);
  k_glured<<<ggrid, 512, 65536, stream>>>(wsb, (const unsigned short*)(wsb + H0B),
                                          (const unsigned short*)(wsb + WBFB),
                                          fc_in0_b, fc_out0_b,
                                          (float*)(wsb + V2F0B), (float*)(wsb + KSB));
  k_v2cvt <<<cvtgrid, 256, 0, stream>>>(wsb, (const float*)(wsb + V2F0B));
  k_attnln<<<pgrid, 256, 0, stream>>>(wsb, ln0_g, ln0_b);
  k_glured<<<ggrid, 512, 65536, stream>>>(wsb, (const unsigned short*)(wsb + H1B),
                                          (const unsigned short*)(wsb + WBFB) + 32768,
                                          fc_in1_b, fc_out1_b,
                                          (float*)(wsb + V2F1B), (float*)nullptr);
  k_v2cvt <<<cvtgrid, 256, 0, stream>>>(wsb, (const float*)(wsb + V2F1B));
  k_attnhead<<<pgrid, 256, 0, stream>>>(wsb, ln1_g, ln1_b, b_reg, out);
}